// Round 1
// baseline (543.030 us; speedup 1.0000x reference)
//
#include <hip/hip_runtime.h>

typedef unsigned int uint;
typedef unsigned short ushort;
typedef __attribute__((ext_vector_type(8))) short bf16x8;
typedef __attribute__((ext_vector_type(4))) float f32x4;

#define EPSF 1e-7f
#define ONE_M_EPS 0.99999988079071044921875f /* f32 nearest to 1-1e-7 */
#define ATANH_1ME 8.4056213f                 /* atanh(1-1e-7), f64-accurate */
#define Y2_CLIP 0.99999982f                  /* (1-1e-7)^2 */

__device__ __forceinline__ float bflo(uint u){ union{uint u;float f;}x; x.u = u<<16; return x.f; }
__device__ __forceinline__ float bfhi(uint u){ union{uint u;float f;}x; x.u = u & 0xffff0000u; return x.f; }
__device__ __forceinline__ ushort f2bf(float f){
  union{float f;uint u;}x; x.f=f; uint u=x.u;
  return (ushort)((u + 0x7fffu + ((u>>16)&1u)) >> 16);
}
__device__ __forceinline__ float atanh_c(float a){
  a = fminf(a, ONE_M_EPS);
  return 0.5f*__logf((1.f+a)/(1.f-a));
}
__device__ __forceinline__ float gelu_t(float v){
  return 0.5f*v*(1.f + tanhf(0.7978845608f*(v + 0.044715f*v*v*v)));
}

// expmap0 scalar factor: result = factor * v  (v has squared norm n2); r2 = ||result||^2
__device__ __forceinline__ float expmap_factor(float n2, float sc, float& r2){
  float n = sqrtf(n2);
  if (n < EPSF) { r2 = 0.f; return 0.f; }
  float mag = tanhf(sc*n)/sc;
  float f = mag/n;
  if (mag >= 1.f) { f *= ONE_M_EPS/mag; r2 = Y2_CLIP; }
  else r2 = mag*mag;
  return f;
}
// logmap0(project(expmap0(t,c)),c) = factor * t ; t has squared norm tn2
__device__ __forceinline__ float roundtrip_factor(float tn2, float sc){
  float tn = sqrtf(tn2);
  if (tn < EPSF) return 0.f;
  float mag = tanhf(sc*tn)/sc;
  if (mag >= 1.f) {
    return ATANH_1ME / (sc * tn);   // mag cancels: (mag/tn)*((1-e)/mag)*(ATANH/(sc*(1-e)))
  } else {
    if (mag < EPSF) return 0.f;
    return (mag/tn) * (atanh_c(mag) / (sc * mag));
  }
}

// ---------------- block reductions (256 threads) ----------------
__device__ __forceinline__ float blkSum(float v, float* tmp){
  #pragma unroll
  for (int o=32;o>0;o>>=1) v += __shfl_xor(v, o, 64);
  int w = threadIdx.x >> 6;
  if ((threadIdx.x & 63) == 0) tmp[w] = v;
  __syncthreads();
  v = tmp[0]+tmp[1]+tmp[2]+tmp[3];
  __syncthreads();
  return v;
}
__device__ __forceinline__ float2 blkSum2(float a, float b, float* tmp){
  #pragma unroll
  for (int o=32;o>0;o>>=1){ a += __shfl_xor(a, o, 64); b += __shfl_xor(b, o, 64); }
  int w = threadIdx.x >> 6;
  if ((threadIdx.x & 63) == 0){ tmp[w] = a; tmp[4+w] = b; }
  __syncthreads();
  float2 r; r.x = tmp[0]+tmp[1]+tmp[2]+tmp[3]; r.y = tmp[4]+tmp[5]+tmp[6]+tmp[7];
  __syncthreads();
  return r;
}

// ---------------- transpose + f32->bf16 : W[K][N] -> WT[N][K] ----------------
__global__ void k_tcvt(const float* __restrict__ W, ushort* __restrict__ WT, int K, int N){
  __shared__ float s[32][33];
  int n0 = blockIdx.x*32, k0 = blockIdx.y*32;
  int tx = threadIdx.x, ty = threadIdx.y; // (32,8)
  #pragma unroll
  for (int i=0;i<4;i++)
    s[ty+8*i][tx] = W[(size_t)(k0+ty+8*i)*N + n0+tx];
  __syncthreads();
  #pragma unroll
  for (int i=0;i<4;i++)
    WT[(size_t)(n0+ty+8*i)*K + k0+tx] = f2bf(s[tx][ty+8*i]);
}

// ---------------- prep: x -> x_tan (bf16) ----------------
__global__ __launch_bounds__(256) void k_prep(const float* __restrict__ x,
    const float* __restrict__ cg, const float* __restrict__ lns, const float* __restrict__ lnb,
    ushort* __restrict__ xtan){
  __shared__ float tmp[8];
  int r = blockIdx.x, t = threadIdx.x;
  float c = cg[0];
  float sc = fmaxf(sqrtf(c), EPSF);
  float4 xv = ((const float4*)(x + (size_t)r*1024))[t];
  float n2 = blkSum(xv.x*xv.x + xv.y*xv.y + xv.z*xv.z + xv.w*xv.w, tmp);
  float n = sqrtf(n2);
  float f1 = (n < EPSF) ? 0.f : (atanh_c(n) / sc / n);
  float ux = xv.x*f1, uy = xv.y*f1, uz = xv.z*f1, uw = xv.w*f1;
  float2 s12 = blkSum2(ux+uy+uz+uw, ux*ux+uy*uy+uz*uz+uw*uw, tmp);
  float mu = s12.x*(1.f/1024.f);
  float var = s12.y*(1.f/1024.f) - mu*mu;
  float inv = rsqrtf(var + 1e-6f);
  float4 sv = ((const float4*)lns)[t];
  float4 bv = ((const float4*)lnb)[t];
  float ta = (ux-mu)*inv*sv.x + bv.x;
  float tb = (uy-mu)*inv*sv.y + bv.y;
  float tc = (uz-mu)*inv*sv.z + bv.z;
  float td = (uw-mu)*inv*sv.w + bv.w;
  float tn2 = blkSum(ta*ta+tb*tb+tc*tc+td*td, tmp);
  float f = roundtrip_factor(tn2, sc);
  ushort4 o; o.x=f2bf(ta*f); o.y=f2bf(tb*f); o.z=f2bf(tc*f); o.w=f2bf(td*f);
  ((ushort4*)(xtan + (size_t)r*1024))[t] = o;
}

// ---------------- GEMM: C[M][N] = A[M][K](bf16) * Bt[N][K](bf16)^T + bias ----------------
// EPI: 0 = f32 out, 1 = bf16 out, 2 = gelu + bf16 out
template<int EPI>
__global__ __launch_bounds__(256) void k_gemm(const ushort* __restrict__ A,
    const ushort* __restrict__ Bt, const float* __restrict__ bias,
    void* __restrict__ C, int M, int N, int K){
  __shared__ ushort As[128][72];
  __shared__ ushort Bs[128][72];
  const int tid = threadIdx.x;
  const int lane = tid & 63;
  const int wid = tid >> 6;
  const int ro = (wid >> 1) * 64, co = (wid & 1) * 64;
  const int l15 = lane & 15, hi = lane >> 4;
  const int m0 = blockIdx.y * 128, n0 = blockIdx.x * 128;
  const int srow = tid >> 3, scol = (tid & 7) * 8;
  const ushort* Ag = A + (size_t)(m0 + srow) * K + scol;
  const ushort* Bg = Bt + (size_t)(n0 + srow) * K + scol;
  f32x4 acc[4][4];
  #pragma unroll
  for (int i=0;i<4;i++)
    #pragma unroll
    for (int j=0;j<4;j++) acc[i][j] = (f32x4){0.f,0.f,0.f,0.f};
  for (int kt = 0; kt < K; kt += 64){
    uint4 ar[4], br[4];
    #pragma unroll
    for (int i=0;i<4;i++){
      ar[i] = *(const uint4*)(Ag + (size_t)(32*i)*K + kt);
      br[i] = *(const uint4*)(Bg + (size_t)(32*i)*K + kt);
    }
    __syncthreads();
    #pragma unroll
    for (int i=0;i<4;i++){
      *(uint4*)&As[srow + 32*i][scol] = ar[i];
      *(uint4*)&Bs[srow + 32*i][scol] = br[i];
    }
    __syncthreads();
    #pragma unroll
    for (int ks=0;ks<2;ks++){
      bf16x8 af[4], bfv[4];
      #pragma unroll
      for (int m=0;m<4;m++) af[m] = *(const bf16x8*)&As[ro + m*16 + l15][ks*32 + hi*8];
      #pragma unroll
      for (int n=0;n<4;n++) bfv[n] = *(const bf16x8*)&Bs[co + n*16 + l15][ks*32 + hi*8];
      #pragma unroll
      for (int m=0;m<4;m++)
        #pragma unroll
        for (int n=0;n<4;n++)
          acc[m][n] = __builtin_amdgcn_mfma_f32_16x16x32_bf16(af[m], bfv[n], acc[m][n], 0, 0, 0);
    }
  }
  #pragma unroll
  for (int m=0;m<4;m++){
    #pragma unroll
    for (int n=0;n<4;n++){
      int gc = n0 + co + n*16 + l15;
      float bb = bias[gc];
      #pragma unroll
      for (int i=0;i<4;i++){
        int gr = m0 + ro + m*16 + hi*4 + i;
        float v = acc[m][n][i] + bb;
        if (EPI == 2) v = gelu_t(v);
        if (EPI == 0) ((float*)C)[(size_t)gr*N + gc] = v;
        else ((ushort*)C)[(size_t)gr*N + gc] = f2bf(v);
      }
    }
  }
}

// ---------------- fused hyperbolic attention ----------------
// grid (H=16, Be=8, 2), 64 threads; thread t handles q-row qh*64+t; stages K/V rows t, t+64
__global__ __launch_bounds__(64) void k_attn(const float* __restrict__ qkv,
    const float* __restrict__ c_logits, const float* __restrict__ geo,
    ushort* __restrict__ ao){
  __shared__ float Ks[128*64];   // chunk-rotated float4 layout
  __shared__ float k2s[128];
  __shared__ ushort Vs[128*64];  // chunk-rotated uint4 layout
  const int h = blockIdx.x, be = blockIdx.y, qh = blockIdx.z;
  const int t = threadIdx.x;
  const float cl = c_logits[h];
  const float ch = (cl > 20.f) ? cl : log1pf(__expf(cl));
  const float sc = fmaxf(sqrtf(ch), EPSF);
  const float gs = geo[h];
  float4* Ks4 = (float4*)Ks;
  uint4*  Vs4 = (uint4*)Vs;

  #pragma unroll
  for (int rr=0; rr<2; rr++){
    int row = t + rr*64;
    const float* base = qkv + (size_t)(be*128 + row)*3072 + h*64;
    float v[64];
    #pragma unroll
    for (int e=0;e<64;e++) v[e] = base[1024 + e];
    #pragma unroll
    for (int i=0;i<32;i++){
      float fr = __expf(-(float)i * 0.28782313662f); // ln(10000)/32
      float sn, cn; sincosf((float)row * fr, &sn, &cn);
      float a = v[i], b = v[i+32];
      v[i] = a*cn - b*sn;
      v[i+32] = a*sn + b*cn;
    }
    float n2 = 0.f;
    #pragma unroll
    for (int e=0;e<64;e++) n2 += v[e]*v[e];
    float r2; float f = expmap_factor(n2, sc, r2);
    #pragma unroll
    for (int c=0;c<16;c++){
      float4 val; val.x=v[4*c]*f; val.y=v[4*c+1]*f; val.z=v[4*c+2]*f; val.w=v[4*c+3]*f;
      Ks4[row*16 + ((c + row) & 15)] = val;
    }
    k2s[row] = r2;
    #pragma unroll
    for (int c=0;c<8;c++){
      uint4 pv;
      pv.x = (uint)f2bf(base[2048+8*c+0]) | ((uint)f2bf(base[2048+8*c+1])<<16);
      pv.y = (uint)f2bf(base[2048+8*c+2]) | ((uint)f2bf(base[2048+8*c+3])<<16);
      pv.z = (uint)f2bf(base[2048+8*c+4]) | ((uint)f2bf(base[2048+8*c+5])<<16);
      pv.w = (uint)f2bf(base[2048+8*c+6]) | ((uint)f2bf(base[2048+8*c+7])<<16);
      Vs4[row*8 + ((c + row) & 7)] = pv;
    }
  }

  const int qrow = qh*64 + t;
  float q[64];
  {
    const float* base = qkv + (size_t)(be*128 + qrow)*3072 + h*64;
    #pragma unroll
    for (int e=0;e<64;e++) q[e] = base[e];
    #pragma unroll
    for (int i=0;i<32;i++){
      float fr = __expf(-(float)i * 0.28782313662f);
      float sn, cn; sincosf((float)qrow * fr, &sn, &cn);
      float a = q[i], b = q[i+32];
      q[i] = a*cn - b*sn;
      q[i+32] = a*sn + b*cn;
    }
  }
  float qn2 = 0.f;
  #pragma unroll
  for (int e=0;e<64;e++) qn2 += q[e]*q[e];
  float q2; float fq = expmap_factor(qn2, sc, q2);
  #pragma unroll
  for (int e=0;e<64;e++) q[e] *= fq;
  __syncthreads();

  float m = -1e30f, l = 0.f;
  float o[64];
  #pragma unroll
  for (int e=0;e<64;e++) o[e] = 0.f;

  for (int j=0;j<128;j++){
    float xy = 0.f;
    #pragma unroll
    for (int c=0;c<16;c++){
      float4 kv = Ks4[j*16 + ((c + j) & 15)];
      xy += q[4*c]*kv.x + q[4*c+1]*kv.y + q[4*c+2]*kv.z + q[4*c+3]*kv.w;
    }
    float k2 = k2s[j];
    float Af = 1.f - 2.f*ch*xy + ch*k2;
    float Bf = 1.f - ch*q2;
    float den = fmaxf(1.f - 2.f*ch*xy + ch*ch*q2*k2, EPSF);
    float num2 = fmaxf(Af*Af*q2 - 2.f*Af*Bf*xy + Bf*Bf*k2, 0.f);
    float rn = sqrtf(num2)/den;
    rn = (rn >= 1.f) ? ONE_M_EPS : rn;
    float arg = fminf(sc*rn, ONE_M_EPS);
    float d = __logf((1.f+arg)/(1.f-arg)) / sc;  // 2*atanh(arg)/sc
    float s = -gs*d;
    float mn = fmaxf(m, s);
    float sca = __expf(m - mn);
    float p = __expf(s - mn);
    l = l*sca + p;
    m = mn;
    #pragma unroll
    for (int c=0;c<8;c++){
      uint4 vv = Vs4[j*8 + ((c + j) & 7)];
      o[c*8+0] = o[c*8+0]*sca + p*bflo(vv.x);
      o[c*8+1] = o[c*8+1]*sca + p*bfhi(vv.x);
      o[c*8+2] = o[c*8+2]*sca + p*bflo(vv.y);
      o[c*8+3] = o[c*8+3]*sca + p*bfhi(vv.y);
      o[c*8+4] = o[c*8+4]*sca + p*bflo(vv.z);
      o[c*8+5] = o[c*8+5]*sca + p*bfhi(vv.z);
      o[c*8+6] = o[c*8+6]*sca + p*bflo(vv.w);
      o[c*8+7] = o[c*8+7]*sca + p*bfhi(vv.w);
    }
  }
  float invl = 1.f/l;
  ushort* dst = ao + (size_t)(be*128 + qrow)*1024 + h*64;
  #pragma unroll
  for (int e=0;e<64;e++) dst[e] = f2bf(o[e]*invl);
}

// ---------------- post-attention: mobius residual + LN2 roundtrip -> t (bf16) ----------------
__global__ __launch_bounds__(256) void k_postattn(const float* __restrict__ x,
    const float* __restrict__ proj, const float* __restrict__ cg,
    const float* __restrict__ lns, const float* __restrict__ lnb,
    float* __restrict__ xatt, ushort* __restrict__ tout){
  __shared__ float tmp[8];
  int r = blockIdx.x, t = threadIdx.x;
  float c = cg[0], sc = fmaxf(sqrtf(c), EPSF);
  float4 pv = ((const float4*)(proj + (size_t)r*1024))[t];
  float4 xv = ((const float4*)(x + (size_t)r*1024))[t];
  float pn2 = blkSum(pv.x*pv.x+pv.y*pv.y+pv.z*pv.z+pv.w*pv.w, tmp);
  float y2; float fy = expmap_factor(pn2, sc, y2);
  float ya = pv.x*fy, yb = pv.y*fy, yc = pv.z*fy, yd = pv.w*fy;
  float2 s = blkSum2(xv.x*xv.x+xv.y*xv.y+xv.z*xv.z+xv.w*xv.w,
                     xv.x*ya+xv.y*yb+xv.z*yc+xv.w*yd, tmp);
  float x2 = s.x, xy = s.y;
  float Af = 1.f + 2.f*c*xy + c*y2;
  float Bf = 1.f - c*x2;
  float den = fmaxf(1.f + 2.f*c*xy + c*c*x2*y2, EPSF);
  float num2 = fmaxf(Af*Af*x2 + 2.f*Af*Bf*xy + Bf*Bf*y2, 0.f);
  float rn = sqrtf(num2)/den;
  float fp = (rn >= 1.f) ? (ONE_M_EPS/fmaxf(rn,EPSF)) : 1.f;
  float xan = (rn >= 1.f) ? ONE_M_EPS : rn;
  float g = fp/den;
  float xa = (Af*xv.x + Bf*ya)*g;
  float xb = (Af*xv.y + Bf*yb)*g;
  float xc = (Af*xv.z + Bf*yc)*g;
  float xd = (Af*xv.w + Bf*yd)*g;
  float4 xo; xo.x=xa; xo.y=xb; xo.z=xc; xo.w=xd;
  ((float4*)(xatt + (size_t)r*1024))[t] = xo;
  // logmap0(x_att)
  float at = (rn >= 1.f) ? ATANH_1ME : atanh_c(xan);
  float fl = (xan < EPSF) ? 0.f : at / sc / fmaxf(xan, EPSF);
  float ux = xa*fl, uy = xb*fl, uz = xc*fl, uw = xd*fl;
  float2 s12 = blkSum2(ux+uy+uz+uw, ux*ux+uy*uy+uz*uz+uw*uw, tmp);
  float mu = s12.x*(1.f/1024.f);
  float var = s12.y*(1.f/1024.f) - mu*mu;
  float inv = rsqrtf(var + 1e-6f);
  float4 sv = ((const float4*)lns)[t];
  float4 bv = ((const float4*)lnb)[t];
  float ta = (ux-mu)*inv*sv.x + bv.x;
  float tb = (uy-mu)*inv*sv.y + bv.y;
  float tc = (uz-mu)*inv*sv.z + bv.z;
  float td = (uw-mu)*inv*sv.w + bv.w;
  float tn2 = blkSum(ta*ta+tb*tb+tc*tc+td*td, tmp);
  float f = roundtrip_factor(tn2, sc);
  ushort4 o; o.x=f2bf(ta*f); o.y=f2bf(tb*f); o.z=f2bf(tc*f); o.w=f2bf(td*f);
  ((ushort4*)(tout + (size_t)r*1024))[t] = o;
}

// ---------------- final: out = mobius_add(x_att, expmap0(tf)) ----------------
__global__ __launch_bounds__(256) void k_final(const float* __restrict__ xatt,
    const float* __restrict__ tf, const float* __restrict__ cg, float* __restrict__ out){
  __shared__ float tmp[8];
  int r = blockIdx.x, t = threadIdx.x;
  float c = cg[0], sc = fmaxf(sqrtf(c), EPSF);
  float4 fv = ((const float4*)(tf + (size_t)r*1024))[t];
  float4 xv = ((const float4*)(xatt + (size_t)r*1024))[t];
  float fn2 = blkSum(fv.x*fv.x+fv.y*fv.y+fv.z*fv.z+fv.w*fv.w, tmp);
  float y2; float fy = expmap_factor(fn2, sc, y2);
  float ya = fv.x*fy, yb = fv.y*fy, yc = fv.z*fy, yd = fv.w*fy;
  float2 s = blkSum2(xv.x*xv.x+xv.y*xv.y+xv.z*xv.z+xv.w*xv.w,
                     xv.x*ya+xv.y*yb+xv.z*yc+xv.w*yd, tmp);
  float x2 = s.x, xy = s.y;
  float Af = 1.f + 2.f*c*xy + c*y2;
  float Bf = 1.f - c*x2;
  float den = fmaxf(1.f + 2.f*c*xy + c*c*x2*y2, EPSF);
  float num2 = fmaxf(Af*Af*x2 + 2.f*Af*Bf*xy + Bf*Bf*y2, 0.f);
  float rn = sqrtf(num2)/den;
  float fp = (rn >= 1.f) ? (ONE_M_EPS/fmaxf(rn,EPSF)) : 1.f;
  float g = fp/den;
  float4 o;
  o.x = (Af*xv.x + Bf*ya)*g;
  o.y = (Af*xv.y + Bf*yb)*g;
  o.z = (Af*xv.z + Bf*yc)*g;
  o.w = (Af*xv.w + Bf*yd)*g;
  ((float4*)(out + (size_t)r*1024))[t] = o;
}

extern "C" void kernel_launch(void* const* d_in, const int* in_sizes, int n_in,
                              void* d_out, int out_size, void* d_ws, size_t ws_size,
                              hipStream_t stream){
  (void)in_sizes; (void)n_in; (void)out_size; (void)ws_size;
  const float* x     = (const float*)d_in[0];
  const float* cg    = (const float*)d_in[1];
  const float* qkv_w = (const float*)d_in[2];
  const float* qkv_b = (const float*)d_in[3];
  const float* out_w = (const float*)d_in[4];
  const float* out_b = (const float*)d_in[5];
  const float* ffn_w1= (const float*)d_in[6];
  const float* ffn_b1= (const float*)d_in[7];
  const float* ffn_w2= (const float*)d_in[8];
  const float* ffn_b2= (const float*)d_in[9];
  const float* ln1s  = (const float*)d_in[10];
  const float* ln1b  = (const float*)d_in[11];
  const float* ln2s  = (const float*)d_in[12];
  const float* ln2b  = (const float*)d_in[13];
  const float* clog  = (const float*)d_in[14];
  const float* geo   = (const float*)d_in[15];

  char* p = (char*)d_ws;
  auto take = [&](size_t n){ char* r = p; p += (n + 255) & ~(size_t)255; return r; };
  ushort* wt_qkv  = (ushort*)take((size_t)3072*1024*2);
  ushort* wt_out  = (ushort*)take((size_t)1024*1024*2);
  ushort* wt_ffn1 = (ushort*)take((size_t)4096*1024*2);
  ushort* wt_ffn2 = (ushort*)take((size_t)1024*4096*2);
  float*  bufA    = (float*)take((size_t)1024*3072*4);  // qkv f32 ; later h bf16
  ushort* bufB    = (ushort*)take((size_t)1024*1024*2); // x_tan ; later ao
  float*  bufC    = (float*)take((size_t)1024*1024*4);  // proj ; later tf
  float*  xatt    = (float*)take((size_t)1024*1024*4);
  ushort* tbuf    = (ushort*)take((size_t)1024*1024*2);

  dim3 tb(32,8);
  k_tcvt<<<dim3(3072/32,1024/32), tb, 0, stream>>>(qkv_w, wt_qkv, 1024, 3072);
  k_tcvt<<<dim3(1024/32,1024/32), tb, 0, stream>>>(out_w, wt_out, 1024, 1024);
  k_tcvt<<<dim3(4096/32,1024/32), tb, 0, stream>>>(ffn_w1, wt_ffn1, 1024, 4096);
  k_tcvt<<<dim3(1024/32,4096/32), tb, 0, stream>>>(ffn_w2, wt_ffn2, 4096, 1024);

  k_prep<<<1024, 256, 0, stream>>>(x, cg, ln1s, ln1b, bufB);
  k_gemm<0><<<dim3(24,8), 256, 0, stream>>>(bufB, wt_qkv, qkv_b, (void*)bufA, 1024, 3072, 1024);
  k_attn<<<dim3(16,8,2), 64, 0, stream>>>(bufA, clog, geo, bufB);
  k_gemm<0><<<dim3(8,8), 256, 0, stream>>>(bufB, wt_out, out_b, (void*)bufC, 1024, 1024, 1024);
  k_postattn<<<1024, 256, 0, stream>>>(x, bufC, cg, ln2s, ln2b, xatt, tbuf);
  k_gemm<2><<<dim3(32,8), 256, 0, stream>>>(tbuf, wt_ffn1, ffn_b1, (void*)bufA, 1024, 4096, 1024);
  k_gemm<0><<<dim3(8,8), 256, 0, stream>>>((const ushort*)bufA, wt_ffn2, ffn_b2, (void*)bufC, 1024, 1024, 4096);
  k_final<<<1024, 256, 0, stream>>>(xatt, bufC, cg, (float*)d_out);
}

// Round 2
// 299.487 us; speedup vs baseline: 1.8132x; 1.8132x over previous
//
#include <hip/hip_runtime.h>

typedef unsigned int uint;
typedef unsigned short ushort;
typedef __attribute__((ext_vector_type(8))) short bf16x8;
typedef __attribute__((ext_vector_type(4))) float f32x4;

#define EPSF 1e-7f
#define ONE_M_EPS 0.99999988079071044921875f /* f32 nearest to 1-1e-7 */
#define ATANH_1ME 8.4056213f                 /* atanh(1-1e-7), f64-accurate */
#define Y2_CLIP 0.99999982f                  /* (1-1e-7)^2 */

__device__ __forceinline__ float bflo(uint u){ union{uint u;float f;}x; x.u = u<<16; return x.f; }
__device__ __forceinline__ float bfhi(uint u){ union{uint u;float f;}x; x.u = u & 0xffff0000u; return x.f; }
__device__ __forceinline__ ushort f2bf(float f){
  union{float f;uint u;}x; x.f=f; uint u=x.u;
  return (ushort)((u + 0x7fffu + ((u>>16)&1u)) >> 16);
}
__device__ __forceinline__ float atanh_c(float a){
  a = fminf(a, ONE_M_EPS);
  return 0.5f*__logf((1.f+a)/(1.f-a));
}
__device__ __forceinline__ float gelu_t(float v){
  return 0.5f*v*(1.f + tanhf(0.7978845608f*(v + 0.044715f*v*v*v)));
}

// expmap0 scalar factor: result = factor * v  (v has squared norm n2); r2 = ||result||^2
__device__ __forceinline__ float expmap_factor(float n2, float sc, float& r2){
  float n = sqrtf(n2);
  if (n < EPSF) { r2 = 0.f; return 0.f; }
  float mag = tanhf(sc*n)/sc;
  float f = mag/n;
  if (mag >= 1.f) { f *= ONE_M_EPS/mag; r2 = Y2_CLIP; }
  else r2 = mag*mag;
  return f;
}
// logmap0(project(expmap0(t,c)),c) = factor * t ; t has squared norm tn2
__device__ __forceinline__ float roundtrip_factor(float tn2, float sc){
  float tn = sqrtf(tn2);
  if (tn < EPSF) return 0.f;
  float mag = tanhf(sc*tn)/sc;
  if (mag >= 1.f) {
    return ATANH_1ME / (sc * tn);
  } else {
    if (mag < EPSF) return 0.f;
    return (mag/tn) * (atanh_c(mag) / (sc * mag));
  }
}

__device__ __forceinline__ void rope64(float* v, int row){
  #pragma unroll
  for (int i=0;i<32;i++){
    float fr = __expf(-(float)i * 0.28782313662f); // ln(10000)/32
    float sn, cn; __sincosf((float)row * fr, &sn, &cn);
    float a = v[i], b = v[i+32];
    v[i] = a*cn - b*sn;
    v[i+32] = a*sn + b*cn;
  }
}

// ---------------- block reductions (256 threads) ----------------
__device__ __forceinline__ float blkSum(float v, float* tmp){
  #pragma unroll
  for (int o=32;o>0;o>>=1) v += __shfl_xor(v, o, 64);
  int w = threadIdx.x >> 6;
  if ((threadIdx.x & 63) == 0) tmp[w] = v;
  __syncthreads();
  v = tmp[0]+tmp[1]+tmp[2]+tmp[3];
  __syncthreads();
  return v;
}
__device__ __forceinline__ float2 blkSum2(float a, float b, float* tmp){
  #pragma unroll
  for (int o=32;o>0;o>>=1){ a += __shfl_xor(a, o, 64); b += __shfl_xor(b, o, 64); }
  int w = threadIdx.x >> 6;
  if ((threadIdx.x & 63) == 0){ tmp[w] = a; tmp[4+w] = b; }
  __syncthreads();
  float2 r; r.x = tmp[0]+tmp[1]+tmp[2]+tmp[3]; r.y = tmp[4]+tmp[5]+tmp[6]+tmp[7];
  __syncthreads();
  return r;
}

// ---------------- transpose + f32->bf16 : W[K][N] -> WT[N][K] ----------------
__global__ void k_tcvt(const float* __restrict__ W, ushort* __restrict__ WT, int K, int N){
  __shared__ float s[32][33];
  int n0 = blockIdx.x*32, k0 = blockIdx.y*32;
  int tx = threadIdx.x, ty = threadIdx.y; // (32,8)
  #pragma unroll
  for (int i=0;i<4;i++)
    s[ty+8*i][tx] = W[(size_t)(k0+ty+8*i)*N + n0+tx];
  __syncthreads();
  #pragma unroll
  for (int i=0;i<4;i++)
    WT[(size_t)(n0+ty+8*i)*K + k0+tx] = f2bf(s[tx][ty+8*i]);
}

// ---------------- prep: x -> x_tan (bf16) ----------------
__global__ __launch_bounds__(256) void k_prep(const float* __restrict__ x,
    const float* __restrict__ cg, const float* __restrict__ lns, const float* __restrict__ lnb,
    ushort* __restrict__ xtan){
  __shared__ float tmp[8];
  int r = blockIdx.x, t = threadIdx.x;
  float c = cg[0];
  float sc = fmaxf(sqrtf(c), EPSF);
  float4 xv = ((const float4*)(x + (size_t)r*1024))[t];
  float n2 = blkSum(xv.x*xv.x + xv.y*xv.y + xv.z*xv.z + xv.w*xv.w, tmp);
  float n = sqrtf(n2);
  float f1 = (n < EPSF) ? 0.f : (atanh_c(n) / sc / n);
  float ux = xv.x*f1, uy = xv.y*f1, uz = xv.z*f1, uw = xv.w*f1;
  float2 s12 = blkSum2(ux+uy+uz+uw, ux*ux+uy*uy+uz*uz+uw*uw, tmp);
  float mu = s12.x*(1.f/1024.f);
  float var = s12.y*(1.f/1024.f) - mu*mu;
  float inv = rsqrtf(var + 1e-6f);
  float4 sv = ((const float4*)lns)[t];
  float4 bv = ((const float4*)lnb)[t];
  float ta = (ux-mu)*inv*sv.x + bv.x;
  float tb = (uy-mu)*inv*sv.y + bv.y;
  float tc = (uz-mu)*inv*sv.z + bv.z;
  float td = (uw-mu)*inv*sv.w + bv.w;
  float tn2 = blkSum(ta*ta+tb*tb+tc*tc+td*td, tmp);
  float f = roundtrip_factor(tn2, sc);
  ushort4 o; o.x=f2bf(ta*f); o.y=f2bf(tb*f); o.z=f2bf(tc*f); o.w=f2bf(td*f);
  ((ushort4*)(xtan + (size_t)r*1024))[t] = o;
}

// ---------------- GEMM: C[M][N] = A[M][K](bf16) * Bt[N][K](bf16)^T + bias ----------------
// EPI: 0 = f32 out (+bias), 2 = gelu + bf16 out, 3 = f32 split-K partial (bias only z==0)
template<int EPI>
__global__ __launch_bounds__(256) void k_gemm(const ushort* __restrict__ A,
    const ushort* __restrict__ Bt, const float* __restrict__ bias,
    void* __restrict__ C, int M, int N, int Kstride, int Kchunk){
  __shared__ ushort As[128][72];
  __shared__ ushort Bs[128][72];
  const int tid = threadIdx.x;
  const int lane = tid & 63;
  const int wid = tid >> 6;
  const int ro = (wid >> 1) * 64, co = (wid & 1) * 64;
  const int l15 = lane & 15, hi = lane >> 4;
  const int m0 = blockIdx.y * 128, n0 = blockIdx.x * 128;
  const int z = blockIdx.z;
  const int srow = tid >> 3, scol = (tid & 7) * 8;
  const ushort* Ag = A + (size_t)(m0 + srow) * Kstride + (size_t)z * Kchunk + scol;
  const ushort* Bg = Bt + (size_t)(n0 + srow) * Kstride + (size_t)z * Kchunk + scol;
  f32x4 acc[4][4];
  #pragma unroll
  for (int i=0;i<4;i++)
    #pragma unroll
    for (int j=0;j<4;j++) acc[i][j] = (f32x4){0.f,0.f,0.f,0.f};
  for (int kt = 0; kt < Kchunk; kt += 64){
    uint4 ar[4], br[4];
    #pragma unroll
    for (int i=0;i<4;i++){
      ar[i] = *(const uint4*)(Ag + (size_t)(32*i)*Kstride + kt);
      br[i] = *(const uint4*)(Bg + (size_t)(32*i)*Kstride + kt);
    }
    __syncthreads();
    #pragma unroll
    for (int i=0;i<4;i++){
      *(uint4*)&As[srow + 32*i][scol] = ar[i];
      *(uint4*)&Bs[srow + 32*i][scol] = br[i];
    }
    __syncthreads();
    #pragma unroll
    for (int ks=0;ks<2;ks++){
      bf16x8 af[4], bfv[4];
      #pragma unroll
      for (int m=0;m<4;m++) af[m] = *(const bf16x8*)&As[ro + m*16 + l15][ks*32 + hi*8];
      #pragma unroll
      for (int n=0;n<4;n++) bfv[n] = *(const bf16x8*)&Bs[co + n*16 + l15][ks*32 + hi*8];
      #pragma unroll
      for (int m=0;m<4;m++)
        #pragma unroll
        for (int n=0;n<4;n++)
          acc[m][n] = __builtin_amdgcn_mfma_f32_16x16x32_bf16(af[m], bfv[n], acc[m][n], 0, 0, 0);
    }
  }
  #pragma unroll
  for (int m=0;m<4;m++){
    #pragma unroll
    for (int n=0;n<4;n++){
      int gc = n0 + co + n*16 + l15;
      float bb = (EPI == 3) ? (z == 0 ? bias[gc] : 0.f) : bias[gc];
      #pragma unroll
      for (int i=0;i<4;i++){
        int gr = m0 + ro + m*16 + hi*4 + i;
        float v = acc[m][n][i] + bb;
        if (EPI == 2) v = gelu_t(v);
        if (EPI == 2) ((ushort*)C)[(size_t)gr*N + gc] = f2bf(v);
        else ((float*)C)[(size_t)z*M*N + (size_t)gr*N + gc] = v;
      }
    }
  }
}

// ---------------- fused hyperbolic attention, high-occupancy ----------------
// grid (H=16, Be=8, 4), 256 threads. Block handles 32 q-rows (qs*32..+31).
// Thread (r = tid&31, g = tid>>5): q-row r, k-range [g*16, g*16+16). 8-way online-softmax merge.
__global__ __launch_bounds__(256) void k_attn2(const float* __restrict__ qkv,
    const float* __restrict__ c_logits, const float* __restrict__ geo,
    ushort* __restrict__ ao){
  __shared__ float Ks[128*64];   // chunk-rotated float4 layout; reused as o-merge scratch
  __shared__ ushort Vs[128*64];  // chunk-rotated uint4 layout
  __shared__ float k2s[128];
  __shared__ float2 mlb[256];
  const int h = blockIdx.x, be = blockIdx.y, qs = blockIdx.z;
  const int tid = threadIdx.x;
  const int r = tid & 31, g = tid >> 5;
  const float cl = c_logits[h];
  const float ch = (cl > 20.f) ? cl : log1pf(__expf(cl));
  const float sc = fmaxf(sqrtf(ch), EPSF);
  const float gs = geo[h];
  float4* Ks4 = (float4*)Ks;
  uint4*  Vs4 = (uint4*)Vs;

  // ---- stage K (threads 0..127) / V (threads 128..255) ----
  if (tid < 128){
    int row = tid;
    const float* base = qkv + (size_t)(be*128 + row)*3072 + 1024 + h*64;
    float v[64];
    #pragma unroll
    for (int e=0;e<64;e++) v[e] = base[e];
    rope64(v, row);
    float n2 = 0.f;
    #pragma unroll
    for (int e=0;e<64;e++) n2 += v[e]*v[e];
    float r2; float f = expmap_factor(n2, sc, r2);
    #pragma unroll
    for (int c=0;c<16;c++){
      float4 val; val.x=v[4*c]*f; val.y=v[4*c+1]*f; val.z=v[4*c+2]*f; val.w=v[4*c+3]*f;
      Ks4[row*16 + ((c + row) & 15)] = val;
    }
    k2s[row] = r2;
  } else {
    int row = tid - 128;
    const float* base = qkv + (size_t)(be*128 + row)*3072 + 2048 + h*64;
    #pragma unroll
    for (int c=0;c<8;c++){
      uint4 pv;
      pv.x = (uint)f2bf(base[8*c+0]) | ((uint)f2bf(base[8*c+1])<<16);
      pv.y = (uint)f2bf(base[8*c+2]) | ((uint)f2bf(base[8*c+3])<<16);
      pv.z = (uint)f2bf(base[8*c+4]) | ((uint)f2bf(base[8*c+5])<<16);
      pv.w = (uint)f2bf(base[8*c+6]) | ((uint)f2bf(base[8*c+7])<<16);
      Vs4[row*8 + ((c + row) & 7)] = pv;
    }
  }

  // ---- q prep (each thread; 8x redundant across g, hits L1/L2) ----
  const int qrow = qs*32 + r;
  float q[64];
  {
    const float* base = qkv + (size_t)(be*128 + qrow)*3072 + h*64;
    #pragma unroll
    for (int e=0;e<64;e++) q[e] = base[e];
  }
  rope64(q, qrow);
  float qn2 = 0.f;
  #pragma unroll
  for (int e=0;e<64;e++) qn2 += q[e]*q[e];
  float q2; float fq = expmap_factor(qn2, sc, q2);
  #pragma unroll
  for (int e=0;e<64;e++) q[e] *= fq;
  __syncthreads();

  // ---- local flash pass over 16 k's ----
  float m = -1e30f, l = 0.f;
  float o[64];
  #pragma unroll
  for (int e=0;e<64;e++) o[e] = 0.f;
  const int j0 = g * 16;
  #pragma unroll 2
  for (int jj=0;jj<16;jj++){
    int j = j0 + jj;
    float xy = 0.f;
    #pragma unroll
    for (int c=0;c<16;c++){
      float4 kv = Ks4[j*16 + ((c + j) & 15)];
      xy += q[4*c]*kv.x + q[4*c+1]*kv.y + q[4*c+2]*kv.z + q[4*c+3]*kv.w;
    }
    float k2 = k2s[j];
    float Af = 1.f - 2.f*ch*xy + ch*k2;
    float Bf = 1.f - ch*q2;
    float den = fmaxf(1.f - 2.f*ch*xy + ch*ch*q2*k2, EPSF);
    float num2 = fmaxf(Af*Af*q2 - 2.f*Af*Bf*xy + Bf*Bf*k2, 0.f);
    float rn = sqrtf(num2)/den;
    rn = (rn >= 1.f) ? ONE_M_EPS : rn;
    float arg = fminf(sc*rn, ONE_M_EPS);
    float d = __logf((1.f+arg)/(1.f-arg)) / sc;
    float s = -gs*d;
    float mn = fmaxf(m, s);
    float sca = __expf(m - mn);
    float p = __expf(s - mn);
    l = l*sca + p;
    m = mn;
    #pragma unroll
    for (int c=0;c<8;c++){
      uint4 vv = Vs4[j*8 + ((c + j) & 7)];
      o[c*8+0] = o[c*8+0]*sca + p*bflo(vv.x);
      o[c*8+1] = o[c*8+1]*sca + p*bfhi(vv.x);
      o[c*8+2] = o[c*8+2]*sca + p*bflo(vv.y);
      o[c*8+3] = o[c*8+3]*sca + p*bfhi(vv.y);
      o[c*8+4] = o[c*8+4]*sca + p*bflo(vv.z);
      o[c*8+5] = o[c*8+5]*sca + p*bfhi(vv.z);
      o[c*8+6] = o[c*8+6]*sca + p*bflo(vv.w);
      o[c*8+7] = o[c*8+7]*sca + p*bfhi(vv.w);
    }
  }

  // ---- merge 8 partials per q-row ----
  mlb[tid] = make_float2(m, l);
  __syncthreads();
  float M = -1e30f;
  float2 ml[8];
  #pragma unroll
  for (int g2=0;g2<8;g2++){ ml[g2] = mlb[(g2<<5)|r]; M = fmaxf(M, ml[g2].x); }
  float L = 0.f;
  #pragma unroll
  for (int g2=0;g2<8;g2++) L += ml[g2].y * __expf(ml[g2].x - M);
  float w = __expf(m - M);
  #pragma unroll
  for (int e=0;e<64;e++) o[e] *= w;

  float4* S4 = Ks4; // safe: all j-loop Ks reads complete at the barrier above
  #define WSLOT(s) { int b = (((s)<<5)|r)<<4; \
    _Pragma("unroll") for (int c=0;c<16;c++){ \
      float4 t4; t4.x=o[4*c]; t4.y=o[4*c+1]; t4.z=o[4*c+2]; t4.w=o[4*c+3]; \
      S4[b + ((c + r) & 15)] = t4; } }
  #define ASLOT(s) { int b = (((s)<<5)|r)<<4; \
    _Pragma("unroll") for (int c=0;c<16;c++){ \
      float4 t4 = S4[b + ((c + r) & 15)]; \
      o[4*c]+=t4.x; o[4*c+1]+=t4.y; o[4*c+2]+=t4.z; o[4*c+3]+=t4.w; } }

  if (g >= 4) WSLOT(g-4);
  __syncthreads();
  if (g < 4)  ASLOT(g);
  __syncthreads();
  if (g == 2 || g == 3) WSLOT(g-2);
  __syncthreads();
  if (g < 2)  ASLOT(g);
  __syncthreads();
  if (g == 1) WSLOT(0);
  __syncthreads();
  if (g == 0){
    ASLOT(0);
    float invl = 1.f/L;
    ushort* dst = ao + (size_t)(be*128 + qrow)*1024 + h*64;
    uint4* dst4 = (uint4*)dst;
    #pragma unroll
    for (int c=0;c<4;c++){
      uint4 pv;
      pv.x = (uint)f2bf(o[16*c+0]*invl) | ((uint)f2bf(o[16*c+1]*invl)<<16);
      pv.y = (uint)f2bf(o[16*c+2]*invl) | ((uint)f2bf(o[16*c+3]*invl)<<16);
      pv.z = (uint)f2bf(o[16*c+4]*invl) | ((uint)f2bf(o[16*c+5]*invl)<<16);
      pv.w = (uint)f2bf(o[16*c+6]*invl) | ((uint)f2bf(o[16*c+7]*invl)<<16);
      dst4[2*c] = pv;
      pv.x = (uint)f2bf(o[16*c+8]*invl)  | ((uint)f2bf(o[16*c+9]*invl)<<16);
      pv.y = (uint)f2bf(o[16*c+10]*invl) | ((uint)f2bf(o[16*c+11]*invl)<<16);
      pv.z = (uint)f2bf(o[16*c+12]*invl) | ((uint)f2bf(o[16*c+13]*invl)<<16);
      pv.w = (uint)f2bf(o[16*c+14]*invl) | ((uint)f2bf(o[16*c+15]*invl)<<16);
      dst4[2*c+1] = pv;
    }
  }
  #undef WSLOT
  #undef ASLOT
}

// ---------------- post-attention: mobius residual + LN2 roundtrip -> t (bf16) ----------------
// proj = partial0 + partial1 (split-K GEMM output)
__global__ __launch_bounds__(256) void k_postattn(const float* __restrict__ x,
    const float* __restrict__ proj, const float* __restrict__ cg,
    const float* __restrict__ lns, const float* __restrict__ lnb,
    float* __restrict__ xatt, ushort* __restrict__ tout){
  __shared__ float tmp[8];
  int r = blockIdx.x, t = threadIdx.x;
  float c = cg[0], sc = fmaxf(sqrtf(c), EPSF);
  float4 pa = ((const float4*)(proj + (size_t)r*1024))[t];
  float4 pb = ((const float4*)(proj + 1024*1024 + (size_t)r*1024))[t];
  float4 pv; pv.x=pa.x+pb.x; pv.y=pa.y+pb.y; pv.z=pa.z+pb.z; pv.w=pa.w+pb.w;
  float4 xv = ((const float4*)(x + (size_t)r*1024))[t];
  float pn2 = blkSum(pv.x*pv.x+pv.y*pv.y+pv.z*pv.z+pv.w*pv.w, tmp);
  float y2; float fy = expmap_factor(pn2, sc, y2);
  float ya = pv.x*fy, yb = pv.y*fy, yc = pv.z*fy, yd = pv.w*fy;
  float2 s = blkSum2(xv.x*xv.x+xv.y*xv.y+xv.z*xv.z+xv.w*xv.w,
                     xv.x*ya+xv.y*yb+xv.z*yc+xv.w*yd, tmp);
  float x2 = s.x, xy = s.y;
  float Af = 1.f + 2.f*c*xy + c*y2;
  float Bf = 1.f - c*x2;
  float den = fmaxf(1.f + 2.f*c*xy + c*c*x2*y2, EPSF);
  float num2 = fmaxf(Af*Af*x2 + 2.f*Af*Bf*xy + Bf*Bf*y2, 0.f);
  float rn = sqrtf(num2)/den;
  float fp = (rn >= 1.f) ? (ONE_M_EPS/fmaxf(rn,EPSF)) : 1.f;
  float xan = (rn >= 1.f) ? ONE_M_EPS : rn;
  float g = fp/den;
  float xa = (Af*xv.x + Bf*ya)*g;
  float xb = (Af*xv.y + Bf*yb)*g;
  float xc = (Af*xv.z + Bf*yc)*g;
  float xd = (Af*xv.w + Bf*yd)*g;
  float4 xo; xo.x=xa; xo.y=xb; xo.z=xc; xo.w=xd;
  ((float4*)(xatt + (size_t)r*1024))[t] = xo;
  float at = (rn >= 1.f) ? ATANH_1ME : atanh_c(xan);
  float fl = (xan < EPSF) ? 0.f : at / sc / fmaxf(xan, EPSF);
  float ux = xa*fl, uy = xb*fl, uz = xc*fl, uw = xd*fl;
  float2 s12 = blkSum2(ux+uy+uz+uw, ux*ux+uy*uy+uz*uz+uw*uw, tmp);
  float mu = s12.x*(1.f/1024.f);
  float var = s12.y*(1.f/1024.f) - mu*mu;
  float inv = rsqrtf(var + 1e-6f);
  float4 sv = ((const float4*)lns)[t];
  float4 bv = ((const float4*)lnb)[t];
  float ta = (ux-mu)*inv*sv.x + bv.x;
  float tb = (uy-mu)*inv*sv.y + bv.y;
  float tc = (uz-mu)*inv*sv.z + bv.z;
  float td = (uw-mu)*inv*sv.w + bv.w;
  float tn2 = blkSum(ta*ta+tb*tb+tc*tc+td*td, tmp);
  float f = roundtrip_factor(tn2, sc);
  ushort4 o; o.x=f2bf(ta*f); o.y=f2bf(tb*f); o.z=f2bf(tc*f); o.w=f2bf(td*f);
  ((ushort4*)(tout + (size_t)r*1024))[t] = o;
}

// ---------------- final: out = mobius_add(x_att, expmap0(tf)) ----------------
// tf = partial0 + partial1 (split-K GEMM output)
__global__ __launch_bounds__(256) void k_final(const float* __restrict__ xatt,
    const float* __restrict__ tf, const float* __restrict__ cg, float* __restrict__ out){
  __shared__ float tmp[8];
  int r = blockIdx.x, t = threadIdx.x;
  float c = cg[0], sc = fmaxf(sqrtf(c), EPSF);
  float4 fa = ((const float4*)(tf + (size_t)r*1024))[t];
  float4 fb = ((const float4*)(tf + 1024*1024 + (size_t)r*1024))[t];
  float4 fv; fv.x=fa.x+fb.x; fv.y=fa.y+fb.y; fv.z=fa.z+fb.z; fv.w=fa.w+fb.w;
  float4 xv = ((const float4*)(xatt + (size_t)r*1024))[t];
  float fn2 = blkSum(fv.x*fv.x+fv.y*fv.y+fv.z*fv.z+fv.w*fv.w, tmp);
  float y2; float fy = expmap_factor(fn2, sc, y2);
  float ya = fv.x*fy, yb = fv.y*fy, yc = fv.z*fy, yd = fv.w*fy;
  float2 s = blkSum2(xv.x*xv.x+xv.y*xv.y+xv.z*xv.z+xv.w*xv.w,
                     xv.x*ya+xv.y*yb+xv.z*yc+xv.w*yd, tmp);
  float x2 = s.x, xy = s.y;
  float Af = 1.f + 2.f*c*xy + c*y2;
  float Bf = 1.f - c*x2;
  float den = fmaxf(1.f + 2.f*c*xy + c*c*x2*y2, EPSF);
  float num2 = fmaxf(Af*Af*x2 + 2.f*Af*Bf*xy + Bf*Bf*y2, 0.f);
  float rn = sqrtf(num2)/den;
  float fp = (rn >= 1.f) ? (ONE_M_EPS/fmaxf(rn,EPSF)) : 1.f;
  float g = fp/den;
  float4 o;
  o.x = (Af*xv.x + Bf*ya)*g;
  o.y = (Af*xv.y + Bf*yb)*g;
  o.z = (Af*xv.z + Bf*yc)*g;
  o.w = (Af*xv.w + Bf*yd)*g;
  ((float4*)(out + (size_t)r*1024))[t] = o;
}

extern "C" void kernel_launch(void* const* d_in, const int* in_sizes, int n_in,
                              void* d_out, int out_size, void* d_ws, size_t ws_size,
                              hipStream_t stream){
  (void)in_sizes; (void)n_in; (void)out_size; (void)ws_size;
  const float* x     = (const float*)d_in[0];
  const float* cg    = (const float*)d_in[1];
  const float* qkv_w = (const float*)d_in[2];
  const float* qkv_b = (const float*)d_in[3];
  const float* out_w = (const float*)d_in[4];
  const float* out_b = (const float*)d_in[5];
  const float* ffn_w1= (const float*)d_in[6];
  const float* ffn_b1= (const float*)d_in[7];
  const float* ffn_w2= (const float*)d_in[8];
  const float* ffn_b2= (const float*)d_in[9];
  const float* ln1s  = (const float*)d_in[10];
  const float* ln1b  = (const float*)d_in[11];
  const float* ln2s  = (const float*)d_in[12];
  const float* ln2b  = (const float*)d_in[13];
  const float* clog  = (const float*)d_in[14];
  const float* geo   = (const float*)d_in[15];

  char* p = (char*)d_ws;
  auto take = [&](size_t n){ char* r = p; p += (n + 255) & ~(size_t)255; return r; };
  ushort* wt_qkv  = (ushort*)take((size_t)3072*1024*2);
  ushort* wt_out  = (ushort*)take((size_t)1024*1024*2);
  ushort* wt_ffn1 = (ushort*)take((size_t)4096*1024*2);
  ushort* wt_ffn2 = (ushort*)take((size_t)1024*4096*2);
  float*  bufA    = (float*)take((size_t)1024*3072*4);  // qkv f32 ; later h bf16
  ushort* bufB    = (ushort*)take((size_t)1024*1024*2); // x_tan ; later ao
  float*  bufC    = (float*)take((size_t)2*1024*1024*4); // split-K partials (2x 4MB)
  float*  xatt    = (float*)take((size_t)1024*1024*4);
  ushort* tbuf    = (ushort*)take((size_t)1024*1024*2);

  dim3 tb(32,8);
  k_tcvt<<<dim3(3072/32,1024/32), tb, 0, stream>>>(qkv_w, wt_qkv, 1024, 3072);
  k_tcvt<<<dim3(1024/32,1024/32), tb, 0, stream>>>(out_w, wt_out, 1024, 1024);
  k_tcvt<<<dim3(4096/32,1024/32), tb, 0, stream>>>(ffn_w1, wt_ffn1, 1024, 4096);
  k_tcvt<<<dim3(1024/32,4096/32), tb, 0, stream>>>(ffn_w2, wt_ffn2, 4096, 1024);

  k_prep<<<1024, 256, 0, stream>>>(x, cg, ln1s, ln1b, bufB);
  k_gemm<0><<<dim3(24,8,1), 256, 0, stream>>>(bufB, wt_qkv, qkv_b, (void*)bufA, 1024, 3072, 1024, 1024);
  k_attn2<<<dim3(16,8,4), 256, 0, stream>>>(bufA, clog, geo, bufB);
  k_gemm<3><<<dim3(8,8,2), 256, 0, stream>>>(bufB, wt_out, out_b, (void*)bufC, 1024, 1024, 1024, 512);
  k_postattn<<<1024, 256, 0, stream>>>(x, bufC, cg, ln2s, ln2b, xatt, tbuf);
  k_gemm<2><<<dim3(32,8,1), 256, 0, stream>>>(tbuf, wt_ffn1, ffn_b1, (void*)bufA, 1024, 4096, 1024, 1024);
  k_gemm<3><<<dim3(8,8,2), 256, 0, stream>>>((const ushort*)bufA, wt_ffn2, ffn_b2, (void*)bufC, 1024, 1024, 4096, 2048);
  k_final<<<1024, 256, 0, stream>>>(xatt, bufC, cg, (float*)d_out);
}

// Round 3
// 182.772 us; speedup vs baseline: 2.9711x; 1.6386x over previous
//
#include <hip/hip_runtime.h>

typedef unsigned int uint;
typedef unsigned short ushort;
typedef __attribute__((ext_vector_type(8))) short bf16x8;
typedef __attribute__((ext_vector_type(4))) float f32x4;

#define EPSF 1e-7f
#define ONE_M_EPS 0.99999988079071044921875f /* f32 nearest to 1-1e-7 */
#define ATANH_1ME 8.4056213f                 /* atanh(1-1e-7), f64-accurate */
#define Y2_CLIP 0.99999982f                  /* (1-1e-7)^2 */

__device__ __forceinline__ float bflo(uint u){ union{uint u;float f;}x; x.u = u<<16; return x.f; }
__device__ __forceinline__ float bfhi(uint u){ union{uint u;float f;}x; x.u = u & 0xffff0000u; return x.f; }
__device__ __forceinline__ ushort f2bf(float f){
  union{float f;uint u;}x; x.f=f; uint u=x.u;
  return (ushort)((u + 0x7fffu + ((u>>16)&1u)) >> 16);
}
__device__ __forceinline__ float atanh_c(float a){
  a = fminf(a, ONE_M_EPS);
  return 0.5f*__logf((1.f+a)/(1.f-a));
}
__device__ __forceinline__ float gelu_t(float v){
  return 0.5f*v*(1.f + tanhf(0.7978845608f*(v + 0.044715f*v*v*v)));
}

// expmap0 scalar factor: result = factor * v  (v has squared norm n2); r2 = ||result||^2
__device__ __forceinline__ float expmap_factor(float n2, float sc, float& r2){
  float n = sqrtf(n2);
  if (n < EPSF) { r2 = 0.f; return 0.f; }
  float mag = tanhf(sc*n)/sc;
  float f = mag/n;
  if (mag >= 1.f) { f *= ONE_M_EPS/mag; r2 = Y2_CLIP; }
  else r2 = mag*mag;
  return f;
}
// logmap0(project(expmap0(t,c)),c) = factor * t ; t has squared norm tn2
__device__ __forceinline__ float roundtrip_factor(float tn2, float sc){
  float tn = sqrtf(tn2);
  if (tn < EPSF) return 0.f;
  float mag = tanhf(sc*tn)/sc;
  if (mag >= 1.f) {
    return ATANH_1ME / (sc * tn);
  } else {
    if (mag < EPSF) return 0.f;
    return (mag/tn) * (atanh_c(mag) / (sc * mag));
  }
}

__device__ __forceinline__ void rope64(float* v, int row){
  #pragma unroll
  for (int i=0;i<32;i++){
    float fr = __expf(-(float)i * 0.28782313662f); // ln(10000)/32
    float sn, cn; __sincosf((float)row * fr, &sn, &cn);
    float a = v[i], b = v[i+32];
    v[i] = a*cn - b*sn;
    v[i+32] = a*sn + b*cn;
  }
}

// ---------------- block reductions (256 threads) ----------------
__device__ __forceinline__ float blkSum(float v, float* tmp){
  #pragma unroll
  for (int o=32;o>0;o>>=1) v += __shfl_xor(v, o, 64);
  int w = threadIdx.x >> 6;
  if ((threadIdx.x & 63) == 0) tmp[w] = v;
  __syncthreads();
  v = tmp[0]+tmp[1]+tmp[2]+tmp[3];
  __syncthreads();
  return v;
}
__device__ __forceinline__ float2 blkSum2(float a, float b, float* tmp){
  #pragma unroll
  for (int o=32;o>0;o>>=1){ a += __shfl_xor(a, o, 64); b += __shfl_xor(b, o, 64); }
  int w = threadIdx.x >> 6;
  if ((threadIdx.x & 63) == 0){ tmp[w] = a; tmp[4+w] = b; }
  __syncthreads();
  float2 r; r.x = tmp[0]+tmp[1]+tmp[2]+tmp[3]; r.y = tmp[4]+tmp[5]+tmp[6]+tmp[7];
  __syncthreads();
  return r;
}

// ---------------- transpose + f32->bf16 : W[K][N] -> WT[N][K] ----------------
__global__ void k_tcvt(const float* __restrict__ W, ushort* __restrict__ WT, int K, int N){
  __shared__ float s[32][33];
  int n0 = blockIdx.x*32, k0 = blockIdx.y*32;
  int tx = threadIdx.x, ty = threadIdx.y; // (32,8)
  #pragma unroll
  for (int i=0;i<4;i++)
    s[ty+8*i][tx] = W[(size_t)(k0+ty+8*i)*N + n0+tx];
  __syncthreads();
  #pragma unroll
  for (int i=0;i<4;i++)
    WT[(size_t)(n0+ty+8*i)*K + k0+tx] = f2bf(s[tx][ty+8*i]);
}

// ---------------- prep: x -> x_tan (bf16) ----------------
__global__ __launch_bounds__(256) void k_prep(const float* __restrict__ x,
    const float* __restrict__ cg, const float* __restrict__ lns, const float* __restrict__ lnb,
    ushort* __restrict__ xtan){
  __shared__ float tmp[8];
  int r = blockIdx.x, t = threadIdx.x;
  float c = cg[0];
  float sc = fmaxf(sqrtf(c), EPSF);
  float4 xv = ((const float4*)(x + (size_t)r*1024))[t];
  float n2 = blkSum(xv.x*xv.x + xv.y*xv.y + xv.z*xv.z + xv.w*xv.w, tmp);
  float n = sqrtf(n2);
  float f1 = (n < EPSF) ? 0.f : (atanh_c(n) / sc / n);
  float ux = xv.x*f1, uy = xv.y*f1, uz = xv.z*f1, uw = xv.w*f1;
  float2 s12 = blkSum2(ux+uy+uz+uw, ux*ux+uy*uy+uz*uz+uw*uw, tmp);
  float mu = s12.x*(1.f/1024.f);
  float var = s12.y*(1.f/1024.f) - mu*mu;
  float inv = rsqrtf(var + 1e-6f);
  float4 sv = ((const float4*)lns)[t];
  float4 bv = ((const float4*)lnb)[t];
  float ta = (ux-mu)*inv*sv.x + bv.x;
  float tb = (uy-mu)*inv*sv.y + bv.y;
  float tc = (uz-mu)*inv*sv.z + bv.z;
  float td = (uw-mu)*inv*sv.w + bv.w;
  float tn2 = blkSum(ta*ta+tb*tb+tc*tc+td*td, tmp);
  float f = roundtrip_factor(tn2, sc);
  ushort4 o; o.x=f2bf(ta*f); o.y=f2bf(tb*f); o.z=f2bf(tc*f); o.w=f2bf(td*f);
  ((ushort4*)(xtan + (size_t)r*1024))[t] = o;
}

// ---------------- GEMM: C[M][N] = A[M][K](bf16) * Bt[N][K](bf16)^T + bias ----------------
// 2-phase pipelined: global_load_lds double-buffer, XOR-swizzled LDS, XCD-aware remap.
// EPI: 0 = f32 out (+bias), 2 = gelu + bf16 out, 3 = f32 split-K partial (bias only z==0)
template<int EPI>
__global__ __launch_bounds__(256) void k_gemm(const ushort* __restrict__ A,
    const ushort* __restrict__ Bt, const float* __restrict__ bias,
    void* __restrict__ C, int M, int N, int Kstride, int Kchunk){
  __shared__ ushort As[2][128*64];
  __shared__ ushort Bs[2][128*64];
  const int tid = threadIdx.x;
  const int lane = tid & 63;
  const int wid = tid >> 6;
  const int ro = (wid >> 1) * 64, co = (wid & 1) * 64;
  const int l15 = lane & 15, hi = lane >> 4;
  // XCD-aware bijective remap (m204), column-major decode: per-XCD chunk =
  // a few B-panels + the full A panel (~3 MB, fits per-XCD 4 MB L2).
  const int nwg = gridDim.x * gridDim.y;
  const int lin = blockIdx.y * gridDim.x + blockIdx.x;
  const int qq = nwg >> 3, rr = nwg & 7;
  const int xcd = lin & 7, ii = lin >> 3;
  const int swz = (xcd < rr) ? (xcd*(qq+1) + ii) : (rr*(qq+1) + (xcd-rr)*qq + ii);
  const int m0 = (swz % gridDim.y) * 128;
  const int n0 = (swz / gridDim.y) * 128;
  const int z = blockIdx.z;
  const int kbase = z * Kchunk;
  const int swr = (l15 & 7) << 3;   // read-side XOR (elements)

  f32x4 acc[4][4];
  #pragma unroll
  for (int i=0;i<4;i++)
    #pragma unroll
    for (int j=0;j<4;j++) acc[i][j] = (f32x4){0.f,0.f,0.f,0.f};

  // stage one 128x64 A-tile + B-tile into buffer `buf` (async, 8 gload_lds/thread)
  auto stage = [&](int buf, int koff){
    #pragma unroll
    for (int r2=0;r2<4;r2++){
      int idx = r2*256 + tid;
      int row = idx >> 3, cc = idx & 7;
      int off = koff + ((cc ^ (row & 7)) << 3);   // inverse-swizzled source chunk
      const ushort* ga = A  + (size_t)(m0+row)*Kstride + off;
      const ushort* gb = Bt + (size_t)(n0+row)*Kstride + off;
      int lo = (r2*256 + (tid & 192)) * 8;        // wave-uniform LDS base (ushorts)
      __builtin_amdgcn_global_load_lds((const __attribute__((address_space(1))) uint*)ga,
          (__attribute__((address_space(3))) uint*)&As[buf][lo], 16, 0, 0);
      __builtin_amdgcn_global_load_lds((const __attribute__((address_space(1))) uint*)gb,
          (__attribute__((address_space(3))) uint*)&Bs[buf][lo], 16, 0, 0);
    }
  };
  auto compute = [&](int buf){
    #pragma unroll
    for (int ks=0;ks<2;ks++){
      bf16x8 af[4], bfv[4];
      int cb = (ks*32 + hi*8) ^ swr;
      #pragma unroll
      for (int m2=0;m2<4;m2++) af[m2]  = *(const bf16x8*)&As[buf][(ro+m2*16+l15)*64 + cb];
      #pragma unroll
      for (int n2=0;n2<4;n2++) bfv[n2] = *(const bf16x8*)&Bs[buf][(co+n2*16+l15)*64 + cb];
      #pragma unroll
      for (int m2=0;m2<4;m2++)
        #pragma unroll
        for (int n2=0;n2<4;n2++)
          acc[m2][n2] = __builtin_amdgcn_mfma_f32_16x16x32_bf16(af[m2], bfv[n2], acc[m2][n2], 0, 0, 0);
    }
  };

  const int nt = Kchunk >> 6;
  stage(0, kbase);
  __syncthreads();                 // compiler emits vmcnt(0) before barrier
  int cur = 0;
  for (int t = 1; t < nt; ++t){
    stage(cur ^ 1, kbase + t*64);  // issue next-tile loads (fly under compute)
    compute(cur);
    __syncthreads();               // drain staging + protect buffer reuse
    cur ^= 1;
  }
  compute(cur);

  #pragma unroll
  for (int m=0;m<4;m++){
    #pragma unroll
    for (int n=0;n<4;n++){
      int gc = n0 + co + n*16 + l15;
      float bb = (EPI == 3) ? (z == 0 ? bias[gc] : 0.f) : bias[gc];
      #pragma unroll
      for (int i=0;i<4;i++){
        int gr = m0 + ro + m*16 + hi*4 + i;
        float v = acc[m][n][i] + bb;
        if (EPI == 2) v = gelu_t(v);
        if (EPI == 2) ((ushort*)C)[(size_t)gr*N + gc] = f2bf(v);
        else ((float*)C)[(size_t)z*M*N + (size_t)gr*N + gc] = v;
      }
    }
  }
}

// ---------------- fused hyperbolic attention, high-occupancy ----------------
// grid (H=16, Be=8, 4), 256 threads. Block handles 32 q-rows (qs*32..+31).
// Thread (r = tid&31, g = tid>>5): q-row r, k-range [g*16, g*16+16). 8-way online-softmax merge.
__global__ __launch_bounds__(256) void k_attn2(const float* __restrict__ qkv,
    const float* __restrict__ c_logits, const float* __restrict__ geo,
    ushort* __restrict__ ao){
  __shared__ float Ks[128*64];   // chunk-rotated float4 layout; reused as o-merge scratch
  __shared__ ushort Vs[128*64];  // chunk-rotated uint4 layout
  __shared__ float k2s[128];
  __shared__ float2 mlb[256];
  const int h = blockIdx.x, be = blockIdx.y, qs = blockIdx.z;
  const int tid = threadIdx.x;
  const int r = tid & 31, g = tid >> 5;
  const float cl = c_logits[h];
  const float ch = (cl > 20.f) ? cl : log1pf(__expf(cl));
  const float sc = fmaxf(sqrtf(ch), EPSF);
  const float gs = geo[h];
  float4* Ks4 = (float4*)Ks;
  uint4*  Vs4 = (uint4*)Vs;

  // ---- stage K (threads 0..127) / V (threads 128..255) ----
  if (tid < 128){
    int row = tid;
    const float* base = qkv + (size_t)(be*128 + row)*3072 + 1024 + h*64;
    float v[64];
    #pragma unroll
    for (int e=0;e<64;e++) v[e] = base[e];
    rope64(v, row);
    float n2 = 0.f;
    #pragma unroll
    for (int e=0;e<64;e++) n2 += v[e]*v[e];
    float r2; float f = expmap_factor(n2, sc, r2);
    #pragma unroll
    for (int c=0;c<16;c++){
      float4 val; val.x=v[4*c]*f; val.y=v[4*c+1]*f; val.z=v[4*c+2]*f; val.w=v[4*c+3]*f;
      Ks4[row*16 + ((c + row) & 15)] = val;
    }
    k2s[row] = r2;
  } else {
    int row = tid - 128;
    const float* base = qkv + (size_t)(be*128 + row)*3072 + 2048 + h*64;
    #pragma unroll
    for (int c=0;c<8;c++){
      uint4 pv;
      pv.x = (uint)f2bf(base[8*c+0]) | ((uint)f2bf(base[8*c+1])<<16);
      pv.y = (uint)f2bf(base[8*c+2]) | ((uint)f2bf(base[8*c+3])<<16);
      pv.z = (uint)f2bf(base[8*c+4]) | ((uint)f2bf(base[8*c+5])<<16);
      pv.w = (uint)f2bf(base[8*c+6]) | ((uint)f2bf(base[8*c+7])<<16);
      Vs4[row*8 + ((c + row) & 7)] = pv;
    }
  }

  // ---- q prep (each thread; 8x redundant across g, hits L1/L2) ----
  const int qrow = qs*32 + r;
  float q[64];
  {
    const float* base = qkv + (size_t)(be*128 + qrow)*3072 + h*64;
    #pragma unroll
    for (int e=0;e<64;e++) q[e] = base[e];
  }
  rope64(q, qrow);
  float qn2 = 0.f;
  #pragma unroll
  for (int e=0;e<64;e++) qn2 += q[e]*q[e];
  float q2; float fq = expmap_factor(qn2, sc, q2);
  #pragma unroll
  for (int e=0;e<64;e++) q[e] *= fq;
  __syncthreads();

  // ---- local flash pass over 16 k's ----
  float m = -1e30f, l = 0.f;
  float o[64];
  #pragma unroll
  for (int e=0;e<64;e++) o[e] = 0.f;
  const int j0 = g * 16;
  #pragma unroll 2
  for (int jj=0;jj<16;jj++){
    int j = j0 + jj;
    float xy = 0.f;
    #pragma unroll
    for (int c=0;c<16;c++){
      float4 kv = Ks4[j*16 + ((c + j) & 15)];
      xy += q[4*c]*kv.x + q[4*c+1]*kv.y + q[4*c+2]*kv.z + q[4*c+3]*kv.w;
    }
    float k2 = k2s[j];
    float Af = 1.f - 2.f*ch*xy + ch*k2;
    float Bf = 1.f - ch*q2;
    float den = fmaxf(1.f - 2.f*ch*xy + ch*ch*q2*k2, EPSF);
    float num2 = fmaxf(Af*Af*q2 - 2.f*Af*Bf*xy + Bf*Bf*k2, 0.f);
    float rn = sqrtf(num2)/den;
    rn = (rn >= 1.f) ? ONE_M_EPS : rn;
    float arg = fminf(sc*rn, ONE_M_EPS);
    float d = __logf((1.f+arg)/(1.f-arg)) / sc;
    float s = -gs*d;
    float mn = fmaxf(m, s);
    float sca = __expf(m - mn);
    float p = __expf(s - mn);
    l = l*sca + p;
    m = mn;
    #pragma unroll
    for (int c=0;c<8;c++){
      uint4 vv = Vs4[j*8 + ((c + j) & 7)];
      o[c*8+0] = o[c*8+0]*sca + p*bflo(vv.x);
      o[c*8+1] = o[c*8+1]*sca + p*bfhi(vv.x);
      o[c*8+2] = o[c*8+2]*sca + p*bflo(vv.y);
      o[c*8+3] = o[c*8+3]*sca + p*bfhi(vv.y);
      o[c*8+4] = o[c*8+4]*sca + p*bflo(vv.z);
      o[c*8+5] = o[c*8+5]*sca + p*bfhi(vv.z);
      o[c*8+6] = o[c*8+6]*sca + p*bflo(vv.w);
      o[c*8+7] = o[c*8+7]*sca + p*bfhi(vv.w);
    }
  }

  // ---- merge 8 partials per q-row ----
  mlb[tid] = make_float2(m, l);
  __syncthreads();
  float M = -1e30f;
  float2 ml[8];
  #pragma unroll
  for (int g2=0;g2<8;g2++){ ml[g2] = mlb[(g2<<5)|r]; M = fmaxf(M, ml[g2].x); }
  float L = 0.f;
  #pragma unroll
  for (int g2=0;g2<8;g2++) L += ml[g2].y * __expf(ml[g2].x - M);
  float w = __expf(m - M);
  #pragma unroll
  for (int e=0;e<64;e++) o[e] *= w;

  float4* S4 = Ks4; // safe: all j-loop Ks reads complete at the barrier above
  #define WSLOT(s) { int b = (((s)<<5)|r)<<4; \
    _Pragma("unroll") for (int c=0;c<16;c++){ \
      float4 t4; t4.x=o[4*c]; t4.y=o[4*c+1]; t4.z=o[4*c+2]; t4.w=o[4*c+3]; \
      S4[b + ((c + r) & 15)] = t4; } }
  #define ASLOT(s) { int b = (((s)<<5)|r)<<4; \
    _Pragma("unroll") for (int c=0;c<16;c++){ \
      float4 t4 = S4[b + ((c + r) & 15)]; \
      o[4*c]+=t4.x; o[4*c+1]+=t4.y; o[4*c+2]+=t4.z; o[4*c+3]+=t4.w; } }

  if (g >= 4) WSLOT(g-4);
  __syncthreads();
  if (g < 4)  ASLOT(g);
  __syncthreads();
  if (g == 2 || g == 3) WSLOT(g-2);
  __syncthreads();
  if (g < 2)  ASLOT(g);
  __syncthreads();
  if (g == 1) WSLOT(0);
  __syncthreads();
  if (g == 0){
    ASLOT(0);
    float invl = 1.f/L;
    ushort* dst = ao + (size_t)(be*128 + qrow)*1024 + h*64;
    uint4* dst4 = (uint4*)dst;
    #pragma unroll
    for (int c=0;c<4;c++){
      uint4 pv;
      pv.x = (uint)f2bf(o[16*c+0]*invl) | ((uint)f2bf(o[16*c+1]*invl)<<16);
      pv.y = (uint)f2bf(o[16*c+2]*invl) | ((uint)f2bf(o[16*c+3]*invl)<<16);
      pv.z = (uint)f2bf(o[16*c+4]*invl) | ((uint)f2bf(o[16*c+5]*invl)<<16);
      pv.w = (uint)f2bf(o[16*c+6]*invl) | ((uint)f2bf(o[16*c+7]*invl)<<16);
      dst4[2*c] = pv;
      pv.x = (uint)f2bf(o[16*c+8]*invl)  | ((uint)f2bf(o[16*c+9]*invl)<<16);
      pv.y = (uint)f2bf(o[16*c+10]*invl) | ((uint)f2bf(o[16*c+11]*invl)<<16);
      pv.z = (uint)f2bf(o[16*c+12]*invl) | ((uint)f2bf(o[16*c+13]*invl)<<16);
      pv.w = (uint)f2bf(o[16*c+14]*invl) | ((uint)f2bf(o[16*c+15]*invl)<<16);
      dst4[2*c+1] = pv;
    }
  }
  #undef WSLOT
  #undef ASLOT
}

// ---------------- post-attention: mobius residual + LN2 roundtrip -> t (bf16) ----------------
// proj = partial0 + partial1 (split-K GEMM output)
__global__ __launch_bounds__(256) void k_postattn(const float* __restrict__ x,
    const float* __restrict__ proj, const float* __restrict__ cg,
    const float* __restrict__ lns, const float* __restrict__ lnb,
    float* __restrict__ xatt, ushort* __restrict__ tout){
  __shared__ float tmp[8];
  int r = blockIdx.x, t = threadIdx.x;
  float c = cg[0], sc = fmaxf(sqrtf(c), EPSF);
  float4 pa = ((const float4*)(proj + (size_t)r*1024))[t];
  float4 pb = ((const float4*)(proj + 1024*1024 + (size_t)r*1024))[t];
  float4 pv; pv.x=pa.x+pb.x; pv.y=pa.y+pb.y; pv.z=pa.z+pb.z; pv.w=pa.w+pb.w;
  float4 xv = ((const float4*)(x + (size_t)r*1024))[t];
  float pn2 = blkSum(pv.x*pv.x+pv.y*pv.y+pv.z*pv.z+pv.w*pv.w, tmp);
  float y2; float fy = expmap_factor(pn2, sc, y2);
  float ya = pv.x*fy, yb = pv.y*fy, yc = pv.z*fy, yd = pv.w*fy;
  float2 s = blkSum2(xv.x*xv.x+xv.y*xv.y+xv.z*xv.z+xv.w*xv.w,
                     xv.x*ya+xv.y*yb+xv.z*yc+xv.w*yd, tmp);
  float x2 = s.x, xy = s.y;
  float Af = 1.f + 2.f*c*xy + c*y2;
  float Bf = 1.f - c*x2;
  float den = fmaxf(1.f + 2.f*c*xy + c*c*x2*y2, EPSF);
  float num2 = fmaxf(Af*Af*x2 + 2.f*Af*Bf*xy + Bf*Bf*y2, 0.f);
  float rn = sqrtf(num2)/den;
  float fp = (rn >= 1.f) ? (ONE_M_EPS/fmaxf(rn,EPSF)) : 1.f;
  float xan = (rn >= 1.f) ? ONE_M_EPS : rn;
  float g = fp/den;
  float xa = (Af*xv.x + Bf*ya)*g;
  float xb = (Af*xv.y + Bf*yb)*g;
  float xc = (Af*xv.z + Bf*yc)*g;
  float xd = (Af*xv.w + Bf*yd)*g;
  float4 xo; xo.x=xa; xo.y=xb; xo.z=xc; xo.w=xd;
  ((float4*)(xatt + (size_t)r*1024))[t] = xo;
  float at = (rn >= 1.f) ? ATANH_1ME : atanh_c(xan);
  float fl = (xan < EPSF) ? 0.f : at / sc / fmaxf(xan, EPSF);
  float ux = xa*fl, uy = xb*fl, uz = xc*fl, uw = xd*fl;
  float2 s12 = blkSum2(ux+uy+uz+uw, ux*ux+uy*uy+uz*uz+uw*uw, tmp);
  float mu = s12.x*(1.f/1024.f);
  float var = s12.y*(1.f/1024.f) - mu*mu;
  float inv = rsqrtf(var + 1e-6f);
  float4 sv = ((const float4*)lns)[t];
  float4 bv = ((const float4*)lnb)[t];
  float ta = (ux-mu)*inv*sv.x + bv.x;
  float tb = (uy-mu)*inv*sv.y + bv.y;
  float tc = (uz-mu)*inv*sv.z + bv.z;
  float td = (uw-mu)*inv*sv.w + bv.w;
  float tn2 = blkSum(ta*ta+tb*tb+tc*tc+td*td, tmp);
  float f = roundtrip_factor(tn2, sc);
  ushort4 o; o.x=f2bf(ta*f); o.y=f2bf(tb*f); o.z=f2bf(tc*f); o.w=f2bf(td*f);
  ((ushort4*)(tout + (size_t)r*1024))[t] = o;
}

// ---------------- final: out = mobius_add(x_att, expmap0(tf)) ----------------
// tf = partial0 + partial1 (split-K GEMM output)
__global__ __launch_bounds__(256) void k_final(const float* __restrict__ xatt,
    const float* __restrict__ tf, const float* __restrict__ cg, float* __restrict__ out){
  __shared__ float tmp[8];
  int r = blockIdx.x, t = threadIdx.x;
  float c = cg[0], sc = fmaxf(sqrtf(c), EPSF);
  float4 fa = ((const float4*)(tf + (size_t)r*1024))[t];
  float4 fb = ((const float4*)(tf + 1024*1024 + (size_t)r*1024))[t];
  float4 fv; fv.x=fa.x+fb.x; fv.y=fa.y+fb.y; fv.z=fa.z+fb.z; fv.w=fa.w+fb.w;
  float4 xv = ((const float4*)(xatt + (size_t)r*1024))[t];
  float fn2 = blkSum(fv.x*fv.x+fv.y*fv.y+fv.z*fv.z+fv.w*fv.w, tmp);
  float y2; float fy = expmap_factor(fn2, sc, y2);
  float ya = fv.x*fy, yb = fv.y*fy, yc = fv.z*fy, yd = fv.w*fy;
  float2 s = blkSum2(xv.x*xv.x+xv.y*xv.y+xv.z*xv.z+xv.w*xv.w,
                     xv.x*ya+xv.y*yb+xv.z*yc+xv.w*yd, tmp);
  float x2 = s.x, xy = s.y;
  float Af = 1.f + 2.f*c*xy + c*y2;
  float Bf = 1.f - c*x2;
  float den = fmaxf(1.f + 2.f*c*xy + c*c*x2*y2, EPSF);
  float num2 = fmaxf(Af*Af*x2 + 2.f*Af*Bf*xy + Bf*Bf*y2, 0.f);
  float rn = sqrtf(num2)/den;
  float fp = (rn >= 1.f) ? (ONE_M_EPS/fmaxf(rn,EPSF)) : 1.f;
  float g = fp/den;
  float4 o;
  o.x = (Af*xv.x + Bf*ya)*g;
  o.y = (Af*xv.y + Bf*yb)*g;
  o.z = (Af*xv.z + Bf*yc)*g;
  o.w = (Af*xv.w + Bf*yd)*g;
  ((float4*)(out + (size_t)r*1024))[t] = o;
}

extern "C" void kernel_launch(void* const* d_in, const int* in_sizes, int n_in,
                              void* d_out, int out_size, void* d_ws, size_t ws_size,
                              hipStream_t stream){
  (void)in_sizes; (void)n_in; (void)out_size; (void)ws_size;
  const float* x     = (const float*)d_in[0];
  const float* cg    = (const float*)d_in[1];
  const float* qkv_w = (const float*)d_in[2];
  const float* qkv_b = (const float*)d_in[3];
  const float* out_w = (const float*)d_in[4];
  const float* out_b = (const float*)d_in[5];
  const float* ffn_w1= (const float*)d_in[6];
  const float* ffn_b1= (const float*)d_in[7];
  const float* ffn_w2= (const float*)d_in[8];
  const float* ffn_b2= (const float*)d_in[9];
  const float* ln1s  = (const float*)d_in[10];
  const float* ln1b  = (const float*)d_in[11];
  const float* ln2s  = (const float*)d_in[12];
  const float* ln2b  = (const float*)d_in[13];
  const float* clog  = (const float*)d_in[14];
  const float* geo   = (const float*)d_in[15];

  char* p = (char*)d_ws;
  auto take = [&](size_t n){ char* r = p; p += (n + 255) & ~(size_t)255; return r; };
  ushort* wt_qkv  = (ushort*)take((size_t)3072*1024*2);
  ushort* wt_out  = (ushort*)take((size_t)1024*1024*2);
  ushort* wt_ffn1 = (ushort*)take((size_t)4096*1024*2);
  ushort* wt_ffn2 = (ushort*)take((size_t)1024*4096*2);
  float*  bufA    = (float*)take((size_t)1024*3072*4);  // qkv f32 ; later h bf16
  ushort* bufB    = (ushort*)take((size_t)1024*1024*2); // x_tan ; later ao
  float*  bufC    = (float*)take((size_t)2*1024*1024*4); // split-K partials (2x 4MB)
  float*  xatt    = (float*)take((size_t)1024*1024*4);
  ushort* tbuf    = (ushort*)take((size_t)1024*1024*2);

  dim3 tb(32,8);
  k_tcvt<<<dim3(3072/32,1024/32), tb, 0, stream>>>(qkv_w, wt_qkv, 1024, 3072);
  k_tcvt<<<dim3(1024/32,1024/32), tb, 0, stream>>>(out_w, wt_out, 1024, 1024);
  k_tcvt<<<dim3(4096/32,1024/32), tb, 0, stream>>>(ffn_w1, wt_ffn1, 1024, 4096);
  k_tcvt<<<dim3(1024/32,4096/32), tb, 0, stream>>>(ffn_w2, wt_ffn2, 4096, 1024);

  k_prep<<<1024, 256, 0, stream>>>(x, cg, ln1s, ln1b, bufB);
  k_gemm<0><<<dim3(24,8,1), 256, 0, stream>>>(bufB, wt_qkv, qkv_b, (void*)bufA, 1024, 3072, 1024, 1024);
  k_attn2<<<dim3(16,8,4), 256, 0, stream>>>(bufA, clog, geo, bufB);
  k_gemm<3><<<dim3(8,8,2), 256, 0, stream>>>(bufB, wt_out, out_b, (void*)bufC, 1024, 1024, 1024, 512);
  k_postattn<<<1024, 256, 0, stream>>>(x, bufC, cg, ln2s, ln2b, xatt, tbuf);
  k_gemm<2><<<dim3(32,8,1), 256, 0, stream>>>(tbuf, wt_ffn1, ffn_b1, (void*)bufA, 1024, 4096, 1024, 1024);
  k_gemm<3><<<dim3(8,8,2), 256, 0, stream>>>((const ushort*)bufA, wt_ffn2, ffn_b2, (void*)bufC, 1024, 1024, 4096, 2048);
  k_final<<<1024, 256, 0, stream>>>(xatt, bufC, cg, (float*)d_out);
}

// Round 4
// 147.361 us; speedup vs baseline: 3.6850x; 1.2403x over previous
//
#include <hip/hip_runtime.h>

typedef unsigned int uint;
typedef unsigned short ushort;
typedef __attribute__((ext_vector_type(8))) short bf16x8;
typedef __attribute__((ext_vector_type(4))) float f32x4;

#define EPSF 1e-7f
#define ONE_M_EPS 0.99999988079071044921875f /* f32 nearest to 1-1e-7 */
#define ATANH_1ME 8.4056213f                 /* atanh(1-1e-7), f64-accurate */
#define Y2_CLIP 0.99999982f                  /* (1-1e-7)^2 */

__device__ __forceinline__ ushort f2bf(float f){
  union{float f;uint u;}x; x.f=f; uint u=x.u;
  return (ushort)((u + 0x7fffu + ((u>>16)&1u)) >> 16);
}
__device__ __forceinline__ float atanh_c(float a){
  a = fminf(a, ONE_M_EPS);
  return 0.5f*__logf((1.f+a)/(1.f-a));
}
__device__ __forceinline__ float gelu_t(float v){
  return 0.5f*v*(1.f + tanhf(0.7978845608f*(v + 0.044715f*v*v*v)));
}

__device__ __forceinline__ float expmap_factor(float n2, float sc, float& r2){
  float n = sqrtf(n2);
  if (n < EPSF) { r2 = 0.f; return 0.f; }
  float mag = tanhf(sc*n)/sc;
  float f = mag/n;
  if (mag >= 1.f) { f *= ONE_M_EPS/mag; r2 = Y2_CLIP; }
  else r2 = mag*mag;
  return f;
}
__device__ __forceinline__ float roundtrip_factor(float tn2, float sc){
  float tn = sqrtf(tn2);
  if (tn < EPSF) return 0.f;
  float mag = tanhf(sc*tn)/sc;
  if (mag >= 1.f) {
    return ATANH_1ME / (sc * tn);
  } else {
    if (mag < EPSF) return 0.f;
    return (mag/tn) * (atanh_c(mag) / (sc * mag));
  }
}

__device__ __forceinline__ void rope64(float* v, int row){
  #pragma unroll
  for (int i=0;i<32;i++){
    float fr = __expf(-(float)i * 0.28782313662f); // ln(10000)/32 ; const-folded
    float sn, cn; __sincosf((float)row * fr, &sn, &cn);
    float a = v[i], b = v[i+32];
    v[i] = a*cn - b*sn;
    v[i+32] = a*sn + b*cn;
  }
}

// ---------------- block reductions (256 threads) ----------------
__device__ __forceinline__ float blkSum(float v, float* tmp){
  #pragma unroll
  for (int o=32;o>0;o>>=1) v += __shfl_xor(v, o, 64);
  int w = threadIdx.x >> 6;
  if ((threadIdx.x & 63) == 0) tmp[w] = v;
  __syncthreads();
  v = tmp[0]+tmp[1]+tmp[2]+tmp[3];
  __syncthreads();
  return v;
}
__device__ __forceinline__ float2 blkSum2(float a, float b, float* tmp){
  #pragma unroll
  for (int o=32;o>0;o>>=1){ a += __shfl_xor(a, o, 64); b += __shfl_xor(b, o, 64); }
  int w = threadIdx.x >> 6;
  if ((threadIdx.x & 63) == 0){ tmp[w] = a; tmp[4+w] = b; }
  __syncthreads();
  float2 r; r.x = tmp[0]+tmp[1]+tmp[2]+tmp[3]; r.y = tmp[4]+tmp[5]+tmp[6]+tmp[7];
  __syncthreads();
  return r;
}

// ---------------- fused transpose + f32->bf16 for all 4 weights ----------------
__global__ void k_tcvt_all(const float* __restrict__ qkv_w, const float* __restrict__ out_w,
    const float* __restrict__ ffn_w1, const float* __restrict__ ffn_w2,
    ushort* __restrict__ wq, ushort* __restrict__ wo,
    ushort* __restrict__ w1, ushort* __restrict__ w2){
  __shared__ float s[32][33];
  int b = blockIdx.x;
  const float* W; ushort* WT; int K, N;
  if (b < 3072){ W=qkv_w; WT=wq; K=1024; N=3072; }
  else if (b < 4096){ b-=3072; W=out_w; WT=wo; K=1024; N=1024; }
  else if (b < 8192){ b-=4096; W=ffn_w1; WT=w1; K=1024; N=4096; }
  else { b-=8192; W=ffn_w2; WT=w2; K=4096; N=1024; }
  int nbn = N >> 5;
  int n0 = (b % nbn)*32, k0 = (b / nbn)*32;
  int tx = threadIdx.x, ty = threadIdx.y; // (32,8)
  #pragma unroll
  for (int i=0;i<4;i++)
    s[ty+8*i][tx] = W[(size_t)(k0+ty+8*i)*N + n0+tx];
  __syncthreads();
  #pragma unroll
  for (int i=0;i<4;i++)
    WT[(size_t)(n0+ty+8*i)*K + k0+tx] = f2bf(s[tx][ty+8*i]);
}

// ---------------- prep: x -> x_tan (bf16) ----------------
__global__ __launch_bounds__(256) void k_prep(const float* __restrict__ x,
    const float* __restrict__ cg, const float* __restrict__ lns, const float* __restrict__ lnb,
    ushort* __restrict__ xtan){
  __shared__ float tmp[8];
  int r = blockIdx.x, t = threadIdx.x;
  float c = cg[0];
  float sc = fmaxf(sqrtf(c), EPSF);
  float4 xv = ((const float4*)(x + (size_t)r*1024))[t];
  float n2 = blkSum(xv.x*xv.x + xv.y*xv.y + xv.z*xv.z + xv.w*xv.w, tmp);
  float n = sqrtf(n2);
  float f1 = (n < EPSF) ? 0.f : (atanh_c(n) / sc / n);
  float ux = xv.x*f1, uy = xv.y*f1, uz = xv.z*f1, uw = xv.w*f1;
  float2 s12 = blkSum2(ux+uy+uz+uw, ux*ux+uy*uy+uz*uz+uw*uw, tmp);
  float mu = s12.x*(1.f/1024.f);
  float var = s12.y*(1.f/1024.f) - mu*mu;
  float inv = rsqrtf(var + 1e-6f);
  float4 sv = ((const float4*)lns)[t];
  float4 bv = ((const float4*)lnb)[t];
  float ta = (ux-mu)*inv*sv.x + bv.x;
  float tb = (uy-mu)*inv*sv.y + bv.y;
  float tc = (uz-mu)*inv*sv.z + bv.z;
  float td = (uw-mu)*inv*sv.w + bv.w;
  float tn2 = blkSum(ta*ta+tb*tb+tc*tc+td*td, tmp);
  float f = roundtrip_factor(tn2, sc);
  ushort4 o; o.x=f2bf(ta*f); o.y=f2bf(tb*f); o.z=f2bf(tc*f); o.w=f2bf(td*f);
  ((ushort4*)(xtan + (size_t)r*1024))[t] = o;
}

// ---------------- GEMM: C[M][N] = A[M][K](bf16) * Bt[N][K](bf16)^T + bias ----------------
// 2-phase pipelined global_load_lds double-buffer, XOR-swizzled LDS, XCD-aware remap.
// BN = 128 (4 waves 64x64) or 64 (4 waves 32x64).
// EPI: 0 = f32 out (+bias), 2 = gelu + bf16 out, 3 = f32 split-K partial (bias z==0, 8x8 grid, 2x4 XCD chunks)
template<int EPI, int BN>
__global__ __launch_bounds__(256) void k_gemm(const ushort* __restrict__ A,
    const ushort* __restrict__ Bt, const float* __restrict__ bias,
    void* __restrict__ C, int M, int N, int Kstride, int Kchunk){
  constexpr int MF = (BN == 128) ? 4 : 2;   // m-fragments per wave
  constexpr int NF = 4;                     // n-fragments per wave
  __shared__ ushort As[2][128*64];
  __shared__ ushort Bs[2][BN*64];
  const int tid = threadIdx.x;
  const int lane = tid & 63;
  const int wid = tid >> 6;
  const int ro = (BN == 128) ? (wid >> 1) * 64 : wid * 32;
  const int co = (BN == 128) ? (wid & 1) * 64 : 0;
  const int l15 = lane & 15, hi = lane >> 4;
  int m0, n0;
  if (EPI == 3){
    // 8x8 grid; xcd = hw round-robin = blockIdx.x (z,y strides are multiples of 8).
    // 2(m) x 4(n) tile chunk per XCD: A-dup 2x, B-dup 4x.
    int x = blockIdx.x, y = blockIdx.y;
    m0 = (((x & 3) << 1) | (y & 1)) * 128;
    n0 = (((x >> 2) << 2) | (y >> 1)) * 128;
  } else {
    const int nwg = gridDim.x * gridDim.y;
    const int lin = blockIdx.y * gridDim.x + blockIdx.x;
    const int qq = nwg >> 3, rr = nwg & 7;
    const int xcd = lin & 7, ii = lin >> 3;
    const int swz = (xcd < rr) ? (xcd*(qq+1) + ii) : (rr*(qq+1) + (xcd-rr)*qq + ii);
    m0 = (swz % gridDim.y) * 128;
    n0 = (swz / gridDim.y) * BN;
  }
  const int z = blockIdx.z;
  const int kbase = z * Kchunk;
  const int swr = (l15 & 7) << 3;   // read-side XOR (elements)

  f32x4 acc[MF][NF];
  #pragma unroll
  for (int i=0;i<MF;i++)
    #pragma unroll
    for (int j=0;j<NF;j++) acc[i][j] = (f32x4){0.f,0.f,0.f,0.f};

  auto stage = [&](int buf, int koff){
    #pragma unroll
    for (int r2=0;r2<4;r2++){
      int idx = r2*256 + tid;
      int row = idx >> 3, cc = idx & 7;
      int off = koff + ((cc ^ (row & 7)) << 3);
      const ushort* ga = A + (size_t)(m0+row)*Kstride + off;
      int lo = (r2*256 + (tid & 192)) * 8;
      __builtin_amdgcn_global_load_lds((const __attribute__((address_space(1))) uint*)ga,
          (__attribute__((address_space(3))) uint*)&As[buf][lo], 16, 0, 0);
    }
    #pragma unroll
    for (int r2=0;r2<BN/32;r2++){
      int idx = r2*256 + tid;
      int row = idx >> 3, cc = idx & 7;
      int off = koff + ((cc ^ (row & 7)) << 3);
      const ushort* gb = Bt + (size_t)(n0+row)*Kstride + off;
      int lo = (r2*256 + (tid & 192)) * 8;
      __builtin_amdgcn_global_load_lds((const __attribute__((address_space(1))) uint*)gb,
          (__attribute__((address_space(3))) uint*)&Bs[buf][lo], 16, 0, 0);
    }
  };
  auto compute = [&](int buf){
    #pragma unroll
    for (int ks=0;ks<2;ks++){
      bf16x8 af[MF], bfv[NF];
      int cb = (ks*32 + hi*8) ^ swr;
      #pragma unroll
      for (int m2=0;m2<MF;m2++) af[m2]  = *(const bf16x8*)&As[buf][(ro+m2*16+l15)*64 + cb];
      #pragma unroll
      for (int n2=0;n2<NF;n2++) bfv[n2] = *(const bf16x8*)&Bs[buf][(co+n2*16+l15)*64 + cb];
      #pragma unroll
      for (int m2=0;m2<MF;m2++)
        #pragma unroll
        for (int n2=0;n2<NF;n2++)
          acc[m2][n2] = __builtin_amdgcn_mfma_f32_16x16x32_bf16(af[m2], bfv[n2], acc[m2][n2], 0, 0, 0);
    }
  };

  const int nt = Kchunk >> 6;
  stage(0, kbase);
  __syncthreads();
  int cur = 0;
  for (int t = 1; t < nt; ++t){
    stage(cur ^ 1, kbase + t*64);
    compute(cur);
    __syncthreads();
    cur ^= 1;
  }
  compute(cur);

  #pragma unroll
  for (int m=0;m<MF;m++){
    #pragma unroll
    for (int n=0;n<NF;n++){
      int gc = n0 + co + n*16 + l15;
      float bb = (EPI == 3) ? (z == 0 ? bias[gc] : 0.f) : bias[gc];
      #pragma unroll
      for (int i=0;i<4;i++){
        int gr = m0 + ro + m*16 + hi*4 + i;
        float v = acc[m][n][i] + bb;
        if (EPI == 2) v = gelu_t(v);
        if (EPI == 2) ((ushort*)C)[(size_t)gr*N + gc] = f2bf(v);
        else ((float*)C)[(size_t)z*M*N + (size_t)gr*N + gc] = v;
      }
    }
  }
}

// ---------------- fused hyperbolic attention, two-pass scoring ----------------
// grid (H=16, Be=8, 4), 256 threads. Block: 32 q-rows. Thread (r=tid&31, g=tid>>5):
// q-row r, k-range [g*16, g*16+16). Chunk-local max + single-exp accumulate, then 8-way merge.
__global__ __launch_bounds__(256) void k_attn3(const float* __restrict__ qkv,
    const float* __restrict__ c_logits, const float* __restrict__ geo,
    ushort* __restrict__ ao){
  __shared__ float Ks[128*64];   // chunk-rotated float4; reused as o-merge scratch
  __shared__ float Vs[128*64];   // f32 V, chunk-rotated float4
  __shared__ float k2s[128];
  __shared__ float2 mlb[256];
  const int h = blockIdx.x, be = blockIdx.y, qs = blockIdx.z;
  const int tid = threadIdx.x;
  const int r = tid & 31, g = tid >> 5;
  const float cl = c_logits[h];
  const float ch = (cl > 20.f) ? cl : log1pf(__expf(cl));
  const float sc = fmaxf(sqrtf(ch), EPSF);
  const float gs = geo[h];
  float4* Ks4 = (float4*)Ks;
  float4* Vs4 = (float4*)Vs;

  // ---- stage K (threads 0..127) / V (threads 128..255) ----
  if (tid < 128){
    int row = tid;
    const float4* b4 = (const float4*)(qkv + (size_t)(be*128 + row)*3072 + 1024 + h*64);
    float v[64];
    #pragma unroll
    for (int c=0;c<16;c++){
      float4 t4 = b4[c];
      v[4*c]=t4.x; v[4*c+1]=t4.y; v[4*c+2]=t4.z; v[4*c+3]=t4.w;
    }
    rope64(v, row);
    float n2 = 0.f;
    #pragma unroll
    for (int e=0;e<64;e++) n2 += v[e]*v[e];
    float r2; float f = expmap_factor(n2, sc, r2);
    #pragma unroll
    for (int c=0;c<16;c++){
      float4 val; val.x=v[4*c]*f; val.y=v[4*c+1]*f; val.z=v[4*c+2]*f; val.w=v[4*c+3]*f;
      Ks4[row*16 + ((c + row) & 15)] = val;
    }
    k2s[row] = r2;
  } else {
    int row = tid - 128;
    const float4* b4 = (const float4*)(qkv + (size_t)(be*128 + row)*3072 + 2048 + h*64);
    #pragma unroll
    for (int c=0;c<16;c++)
      Vs4[row*16 + ((c + row) & 15)] = b4[c];
  }

  // ---- q prep (redundant across g; parallel so ~free) ----
  const int qrow = qs*32 + r;
  float q[64];
  {
    const float4* b4 = (const float4*)(qkv + (size_t)(be*128 + qrow)*3072 + h*64);
    #pragma unroll
    for (int c=0;c<16;c++){
      float4 t4 = b4[c];
      q[4*c]=t4.x; q[4*c+1]=t4.y; q[4*c+2]=t4.z; q[4*c+3]=t4.w;
    }
  }
  rope64(q, qrow);
  float qn2 = 0.f;
  #pragma unroll
  for (int e=0;e<64;e++) qn2 += q[e]*q[e];
  float q2; float fq = expmap_factor(qn2, sc, q2);
  #pragma unroll
  for (int e=0;e<64;e++) q[e] *= fq;
  __syncthreads();

  // ---- pass 1: 16 scores ----
  const float Bf = 1.f - ch*q2;        // invariant
  const float e2 = 2.f*ch;
  const int j0 = g * 16;
  float s[16];
  #pragma unroll
  for (int jj=0;jj<16;jj++){
    int j = j0 + jj;
    float xy = 0.f;
    #pragma unroll
    for (int c=0;c<16;c++){
      float4 kv = Ks4[j*16 + ((c + j) & 15)];
      xy += q[4*c]*kv.x + q[4*c+1]*kv.y + q[4*c+2]*kv.z + q[4*c+3]*kv.w;
    }
    float k2 = k2s[j];
    float Af = 1.f + ch*k2 - e2*xy;
    float den = fmaxf(Af - ch*k2*Bf, EPSF);
    float num2 = fmaxf(Af*(Af*q2 - 2.f*Bf*xy) + Bf*Bf*k2, 0.f);
    float rn = sqrtf(num2)/den;
    rn = (rn >= 1.f) ? ONE_M_EPS : rn;
    float arg = fminf(sc*rn, ONE_M_EPS);
    float d = __logf((1.f+arg)/(1.f-arg)) / sc;
    s[jj] = -gs*d;
  }
  // ---- chunk max ----
  float m = s[0];
  #pragma unroll
  for (int jj=1;jj<16;jj++) m = fmaxf(m, s[jj]);
  // ---- pass 2: exp + V accumulate ----
  float l = 0.f;
  float o[64];
  #pragma unroll
  for (int e=0;e<64;e++) o[e] = 0.f;
  #pragma unroll 2
  for (int jj=0;jj<16;jj++){
    int j = j0 + jj;
    float p = __expf(s[jj] - m);
    l += p;
    #pragma unroll
    for (int c=0;c<16;c++){
      float4 vv = Vs4[j*16 + ((c + j) & 15)];
      o[4*c+0] += p*vv.x;
      o[4*c+1] += p*vv.y;
      o[4*c+2] += p*vv.z;
      o[4*c+3] += p*vv.w;
    }
  }

  // ---- merge 8 partials per q-row ----
  mlb[tid] = make_float2(m, l);
  __syncthreads();
  float M = -1e30f;
  float2 ml[8];
  #pragma unroll
  for (int g2=0;g2<8;g2++){ ml[g2] = mlb[(g2<<5)|r]; M = fmaxf(M, ml[g2].x); }
  float L = 0.f;
  #pragma unroll
  for (int g2=0;g2<8;g2++) L += ml[g2].y * __expf(ml[g2].x - M);
  float w = __expf(m - M);
  #pragma unroll
  for (int e=0;e<64;e++) o[e] *= w;

  float4* S4 = Ks4; // all Ks reads complete at barrier above
  #define WSLOT(s_) { int b = (((s_)<<5)|r)<<4; \
    _Pragma("unroll") for (int c=0;c<16;c++){ \
      float4 t4; t4.x=o[4*c]; t4.y=o[4*c+1]; t4.z=o[4*c+2]; t4.w=o[4*c+3]; \
      S4[b + ((c + r) & 15)] = t4; } }
  #define ASLOT(s_) { int b = (((s_)<<5)|r)<<4; \
    _Pragma("unroll") for (int c=0;c<16;c++){ \
      float4 t4 = S4[b + ((c + r) & 15)]; \
      o[4*c]+=t4.x; o[4*c+1]+=t4.y; o[4*c+2]+=t4.z; o[4*c+3]+=t4.w; } }

  if (g >= 4) WSLOT(g-4);
  __syncthreads();
  if (g < 4)  ASLOT(g);
  __syncthreads();
  if (g == 2 || g == 3) WSLOT(g-2);
  __syncthreads();
  if (g < 2)  ASLOT(g);
  __syncthreads();
  if (g == 1) WSLOT(0);
  __syncthreads();
  if (g == 0){
    ASLOT(0);
    float invl = 1.f/L;
    ushort* dst = ao + (size_t)(be*128 + qrow)*1024 + h*64;
    uint4* dst4 = (uint4*)dst;
    #pragma unroll
    for (int c=0;c<4;c++){
      uint4 pv;
      pv.x = (uint)f2bf(o[16*c+0]*invl) | ((uint)f2bf(o[16*c+1]*invl)<<16);
      pv.y = (uint)f2bf(o[16*c+2]*invl) | ((uint)f2bf(o[16*c+3]*invl)<<16);
      pv.z = (uint)f2bf(o[16*c+4]*invl) | ((uint)f2bf(o[16*c+5]*invl)<<16);
      pv.w = (uint)f2bf(o[16*c+6]*invl) | ((uint)f2bf(o[16*c+7]*invl)<<16);
      dst4[2*c] = pv;
      pv.x = (uint)f2bf(o[16*c+8]*invl)  | ((uint)f2bf(o[16*c+9]*invl)<<16);
      pv.y = (uint)f2bf(o[16*c+10]*invl) | ((uint)f2bf(o[16*c+11]*invl)<<16);
      pv.z = (uint)f2bf(o[16*c+12]*invl) | ((uint)f2bf(o[16*c+13]*invl)<<16);
      pv.w = (uint)f2bf(o[16*c+14]*invl) | ((uint)f2bf(o[16*c+15]*invl)<<16);
      dst4[2*c+1] = pv;
    }
  }
  #undef WSLOT
  #undef ASLOT
}

// ---------------- post-attention: mobius residual + LN2 roundtrip -> t (bf16) ----------------
// proj = sum of 4 split-K partials
__global__ __launch_bounds__(256) void k_postattn(const float* __restrict__ x,
    const float* __restrict__ proj, const float* __restrict__ cg,
    const float* __restrict__ lns, const float* __restrict__ lnb,
    float* __restrict__ xatt, ushort* __restrict__ tout){
  __shared__ float tmp[8];
  int r = blockIdx.x, t = threadIdx.x;
  float c = cg[0], sc = fmaxf(sqrtf(c), EPSF);
  float4 pa = ((const float4*)(proj + (size_t)r*1024))[t];
  float4 pb = ((const float4*)(proj + 1024*1024 + (size_t)r*1024))[t];
  float4 pc = ((const float4*)(proj + 2*1024*1024 + (size_t)r*1024))[t];
  float4 pd = ((const float4*)(proj + 3*1024*1024 + (size_t)r*1024))[t];
  float4 pv; pv.x=(pa.x+pb.x)+(pc.x+pd.x); pv.y=(pa.y+pb.y)+(pc.y+pd.y);
  pv.z=(pa.z+pb.z)+(pc.z+pd.z); pv.w=(pa.w+pb.w)+(pc.w+pd.w);
  float4 xv = ((const float4*)(x + (size_t)r*1024))[t];
  float pn2 = blkSum(pv.x*pv.x+pv.y*pv.y+pv.z*pv.z+pv.w*pv.w, tmp);
  float y2; float fy = expmap_factor(pn2, sc, y2);
  float ya = pv.x*fy, yb = pv.y*fy, yc = pv.z*fy, yd = pv.w*fy;
  float2 s = blkSum2(xv.x*xv.x+xv.y*xv.y+xv.z*xv.z+xv.w*xv.w,
                     xv.x*ya+xv.y*yb+xv.z*yc+xv.w*yd, tmp);
  float x2 = s.x, xy = s.y;
  float Af = 1.f + 2.f*c*xy + c*y2;
  float Bf = 1.f - c*x2;
  float den = fmaxf(1.f + 2.f*c*xy + c*c*x2*y2, EPSF);
  float num2 = fmaxf(Af*Af*x2 + 2.f*Af*Bf*xy + Bf*Bf*y2, 0.f);
  float rn = sqrtf(num2)/den;
  float fp = (rn >= 1.f) ? (ONE_M_EPS/fmaxf(rn,EPSF)) : 1.f;
  float xan = (rn >= 1.f) ? ONE_M_EPS : rn;
  float g = fp/den;
  float xa = (Af*xv.x + Bf*ya)*g;
  float xb = (Af*xv.y + Bf*yb)*g;
  float xc = (Af*xv.z + Bf*yc)*g;
  float xd = (Af*xv.w + Bf*yd)*g;
  float4 xo; xo.x=xa; xo.y=xb; xo.z=xc; xo.w=xd;
  ((float4*)(xatt + (size_t)r*1024))[t] = xo;
  float at = (rn >= 1.f) ? ATANH_1ME : atanh_c(xan);
  float fl = (xan < EPSF) ? 0.f : at / sc / fmaxf(xan, EPSF);
  float ux = xa*fl, uy = xb*fl, uz = xc*fl, uw = xd*fl;
  float2 s12 = blkSum2(ux+uy+uz+uw, ux*ux+uy*uy+uz*uz+uw*uw, tmp);
  float mu = s12.x*(1.f/1024.f);
  float var = s12.y*(1.f/1024.f) - mu*mu;
  float inv = rsqrtf(var + 1e-6f);
  float4 sv = ((const float4*)lns)[t];
  float4 bv = ((const float4*)lnb)[t];
  float ta = (ux-mu)*inv*sv.x + bv.x;
  float tb = (uy-mu)*inv*sv.y + bv.y;
  float tc = (uz-mu)*inv*sv.z + bv.z;
  float td = (uw-mu)*inv*sv.w + bv.w;
  float tn2 = blkSum(ta*ta+tb*tb+tc*tc+td*td, tmp);
  float f = roundtrip_factor(tn2, sc);
  ushort4 o; o.x=f2bf(ta*f); o.y=f2bf(tb*f); o.z=f2bf(tc*f); o.w=f2bf(td*f);
  ((ushort4*)(tout + (size_t)r*1024))[t] = o;
}

// ---------------- final: out = mobius_add(x_att, expmap0(tf)) ----------------
// tf = sum of 4 split-K partials
__global__ __launch_bounds__(256) void k_final(const float* __restrict__ xatt,
    const float* __restrict__ tf, const float* __restrict__ cg, float* __restrict__ out){
  __shared__ float tmp[8];
  int r = blockIdx.x, t = threadIdx.x;
  float c = cg[0], sc = fmaxf(sqrtf(c), EPSF);
  float4 fa = ((const float4*)(tf + (size_t)r*1024))[t];
  float4 fb = ((const float4*)(tf + 1024*1024 + (size_t)r*1024))[t];
  float4 fc = ((const float4*)(tf + 2*1024*1024 + (size_t)r*1024))[t];
  float4 fd = ((const float4*)(tf + 3*1024*1024 + (size_t)r*1024))[t];
  float4 fv; fv.x=(fa.x+fb.x)+(fc.x+fd.x); fv.y=(fa.y+fb.y)+(fc.y+fd.y);
  fv.z=(fa.z+fb.z)+(fc.z+fd.z); fv.w=(fa.w+fb.w)+(fc.w+fd.w);
  float4 xv = ((const float4*)(xatt + (size_t)r*1024))[t];
  float fn2 = blkSum(fv.x*fv.x+fv.y*fv.y+fv.z*fv.z+fv.w*fv.w, tmp);
  float y2; float fy = expmap_factor(fn2, sc, y2);
  float ya = fv.x*fy, yb = fv.y*fy, yc = fv.z*fy, yd = fv.w*fy;
  float2 s = blkSum2(xv.x*xv.x+xv.y*xv.y+xv.z*xv.z+xv.w*xv.w,
                     xv.x*ya+xv.y*yb+xv.z*yc+xv.w*yd, tmp);
  float x2 = s.x, xy = s.y;
  float Af = 1.f + 2.f*c*xy + c*y2;
  float Bf = 1.f - c*x2;
  float den = fmaxf(1.f + 2.f*c*xy + c*c*x2*y2, EPSF);
  float num2 = fmaxf(Af*Af*x2 + 2.f*Af*Bf*xy + Bf*Bf*y2, 0.f);
  float rn = sqrtf(num2)/den;
  float fp = (rn >= 1.f) ? (ONE_M_EPS/fmaxf(rn,EPSF)) : 1.f;
  float g = fp/den;
  float4 o;
  o.x = (Af*xv.x + Bf*ya)*g;
  o.y = (Af*xv.y + Bf*yb)*g;
  o.z = (Af*xv.z + Bf*yc)*g;
  o.w = (Af*xv.w + Bf*yd)*g;
  ((float4*)(out + (size_t)r*1024))[t] = o;
}

extern "C" void kernel_launch(void* const* d_in, const int* in_sizes, int n_in,
                              void* d_out, int out_size, void* d_ws, size_t ws_size,
                              hipStream_t stream){
  (void)in_sizes; (void)n_in; (void)out_size; (void)ws_size;
  const float* x     = (const float*)d_in[0];
  const float* cg    = (const float*)d_in[1];
  const float* qkv_w = (const float*)d_in[2];
  const float* qkv_b = (const float*)d_in[3];
  const float* out_w = (const float*)d_in[4];
  const float* out_b = (const float*)d_in[5];
  const float* ffn_w1= (const float*)d_in[6];
  const float* ffn_b1= (const float*)d_in[7];
  const float* ffn_w2= (const float*)d_in[8];
  const float* ffn_b2= (const float*)d_in[9];
  const float* ln1s  = (const float*)d_in[10];
  const float* ln1b  = (const float*)d_in[11];
  const float* ln2s  = (const float*)d_in[12];
  const float* ln2b  = (const float*)d_in[13];
  const float* clog  = (const float*)d_in[14];
  const float* geo   = (const float*)d_in[15];

  char* p = (char*)d_ws;
  auto take = [&](size_t n){ char* r = p; p += (n + 255) & ~(size_t)255; return r; };
  ushort* wt_qkv  = (ushort*)take((size_t)3072*1024*2);
  ushort* wt_out  = (ushort*)take((size_t)1024*1024*2);
  ushort* wt_ffn1 = (ushort*)take((size_t)4096*1024*2);
  ushort* wt_ffn2 = (ushort*)take((size_t)1024*4096*2);
  float*  bufA    = (float*)take((size_t)1024*3072*4);   // qkv f32 ; later h bf16
  ushort* bufB    = (ushort*)take((size_t)1024*1024*2);  // x_tan ; later ao
  float*  bufC    = (float*)take((size_t)4*1024*1024*4); // split-K partials (4x 4MB)
  float*  xatt    = (float*)take((size_t)1024*1024*4);
  ushort* tbuf    = (ushort*)take((size_t)1024*1024*2);

  k_tcvt_all<<<12288, dim3(32,8), 0, stream>>>(qkv_w, out_w, ffn_w1, ffn_w2,
                                               wt_qkv, wt_out, wt_ffn1, wt_ffn2);
  k_prep<<<1024, 256, 0, stream>>>(x, cg, ln1s, ln1b, bufB);
  k_gemm<0,64><<<dim3(48,8,1), 256, 0, stream>>>(bufB, wt_qkv, qkv_b, (void*)bufA, 1024, 3072, 1024, 1024);
  k_attn3<<<dim3(16,8,4), 256, 0, stream>>>(bufA, clog, geo, bufB);
  k_gemm<3,128><<<dim3(8,8,4), 256, 0, stream>>>(bufB, wt_out, out_b, (void*)bufC, 1024, 1024, 1024, 256);
  k_postattn<<<1024, 256, 0, stream>>>(x, bufC, cg, ln2s, ln2b, xatt, tbuf);
  k_gemm<2,64><<<dim3(64,8,1), 256, 0, stream>>>(tbuf, wt_ffn1, ffn_b1, (void*)bufA, 1024, 4096, 1024, 1024);
  k_gemm<3,128><<<dim3(8,8,4), 256, 0, stream>>>((const ushort*)bufA, wt_ffn2, ffn_b2, (void*)bufC, 1024, 1024, 4096, 1024);
  k_final<<<1024, 256, 0, stream>>>(xatt, bufC, cg, (float*)d_out);
}

// Round 5
// 138.480 us; speedup vs baseline: 3.9214x; 1.0641x over previous
//
#include <hip/hip_runtime.h>

typedef unsigned int uint;
typedef unsigned short ushort;
typedef __attribute__((ext_vector_type(8))) short bf16x8;
typedef __attribute__((ext_vector_type(4))) float f32x4;

#define EPSF 1e-7f
#define ONE_M_EPS 0.99999988079071044921875f /* f32 nearest to 1-1e-7 */
#define ATANH_1ME 8.4056213f                 /* atanh(1-1e-7), f64-accurate */
#define Y2_CLIP 0.99999982f                  /* (1-1e-7)^2 */

__device__ __forceinline__ ushort f2bf(float f){
  union{float f;uint u;}x; x.f=f; uint u=x.u;
  return (ushort)((u + 0x7fffu + ((u>>16)&1u)) >> 16);
}
__device__ __forceinline__ float atanh_c(float a){
  a = fminf(a, ONE_M_EPS);
  return 0.5f*__logf((1.f+a)/(1.f-a));
}
__device__ __forceinline__ float gelu_t(float v){
  return 0.5f*v*(1.f + tanhf(0.7978845608f*(v + 0.044715f*v*v*v)));
}

__device__ __forceinline__ float expmap_factor(float n2, float sc, float& r2){
  float n = sqrtf(n2);
  if (n < EPSF) { r2 = 0.f; return 0.f; }
  float mag = tanhf(sc*n)/sc;
  float f = mag/n;
  if (mag >= 1.f) { f *= ONE_M_EPS/mag; r2 = Y2_CLIP; }
  else r2 = mag*mag;
  return f;
}
__device__ __forceinline__ float roundtrip_factor(float tn2, float sc){
  float tn = sqrtf(tn2);
  if (tn < EPSF) return 0.f;
  float mag = tanhf(sc*tn)/sc;
  if (mag >= 1.f) {
    return ATANH_1ME / (sc * tn);
  } else {
    if (mag < EPSF) return 0.f;
    return (mag/tn) * (atanh_c(mag) / (sc * mag));
  }
}

__device__ __forceinline__ void rope64(float* v, int row){
  #pragma unroll
  for (int i=0;i<32;i++){
    float fr = __expf(-(float)i * 0.28782313662f); // ln(10000)/32 ; const-folded
    float sn, cn; __sincosf((float)row * fr, &sn, &cn);
    float a = v[i], b = v[i+32];
    v[i] = a*cn - b*sn;
    v[i+32] = a*sn + b*cn;
  }
}

// ---------------- block reductions (256 threads) ----------------
__device__ __forceinline__ float blkSum(float v, float* tmp){
  #pragma unroll
  for (int o=32;o>0;o>>=1) v += __shfl_xor(v, o, 64);
  int w = threadIdx.x >> 6;
  if ((threadIdx.x & 63) == 0) tmp[w] = v;
  __syncthreads();
  v = tmp[0]+tmp[1]+tmp[2]+tmp[3];
  __syncthreads();
  return v;
}
__device__ __forceinline__ float2 blkSum2(float a, float b, float* tmp){
  #pragma unroll
  for (int o=32;o>0;o>>=1){ a += __shfl_xor(a, o, 64); b += __shfl_xor(b, o, 64); }
  int w = threadIdx.x >> 6;
  if ((threadIdx.x & 63) == 0){ tmp[w] = a; tmp[4+w] = b; }
  __syncthreads();
  float2 r; r.x = tmp[0]+tmp[1]+tmp[2]+tmp[3]; r.y = tmp[4]+tmp[5]+tmp[6]+tmp[7];
  __syncthreads();
  return r;
}

// ---------------- fused front-end: 4 weight transposes + prep ----------------
// blocks [0,12288): transpose+cvt ; [12288,13312): prep rows
__global__ __launch_bounds__(256) void k_pre(const float* __restrict__ qkv_w,
    const float* __restrict__ out_w, const float* __restrict__ ffn_w1,
    const float* __restrict__ ffn_w2, const float* __restrict__ x,
    const float* __restrict__ cg, const float* __restrict__ lns, const float* __restrict__ lnb,
    ushort* __restrict__ wq, ushort* __restrict__ wo,
    ushort* __restrict__ w1, ushort* __restrict__ w2, ushort* __restrict__ xtan){
  __shared__ float s[32][33];
  int b = blockIdx.x;
  if (b < 12288){
    const float* W; ushort* WT; int K, N;
    if (b < 3072){ W=qkv_w; WT=wq; K=1024; N=3072; }
    else if (b < 4096){ b-=3072; W=out_w; WT=wo; K=1024; N=1024; }
    else if (b < 8192){ b-=4096; W=ffn_w1; WT=w1; K=1024; N=4096; }
    else { b-=8192; W=ffn_w2; WT=w2; K=4096; N=1024; }
    int nbn = N >> 5;
    int n0 = (b % nbn)*32, k0 = (b / nbn)*32;
    int tx = threadIdx.x & 31, ty = threadIdx.x >> 5; // (32,8)
    #pragma unroll
    for (int i=0;i<4;i++)
      s[ty+8*i][tx] = W[(size_t)(k0+ty+8*i)*N + n0+tx];
    __syncthreads();
    #pragma unroll
    for (int i=0;i<4;i++)
      WT[(size_t)(n0+ty+8*i)*K + k0+tx] = f2bf(s[tx][ty+8*i]);
  } else {
    float* tmp = &s[0][0];
    int r = b - 12288, t = threadIdx.x;
    float c = cg[0];
    float sc = fmaxf(sqrtf(c), EPSF);
    float4 xv = ((const float4*)(x + (size_t)r*1024))[t];
    float n2 = blkSum(xv.x*xv.x + xv.y*xv.y + xv.z*xv.z + xv.w*xv.w, tmp);
    float n = sqrtf(n2);
    float f1 = (n < EPSF) ? 0.f : (atanh_c(n) / sc / n);
    float ux = xv.x*f1, uy = xv.y*f1, uz = xv.z*f1, uw = xv.w*f1;
    float2 s12 = blkSum2(ux+uy+uz+uw, ux*ux+uy*uy+uz*uz+uw*uw, tmp);
    float mu = s12.x*(1.f/1024.f);
    float var = s12.y*(1.f/1024.f) - mu*mu;
    float inv = rsqrtf(var + 1e-6f);
    float4 sv = ((const float4*)lns)[t];
    float4 bv = ((const float4*)lnb)[t];
    float ta = (ux-mu)*inv*sv.x + bv.x;
    float tb = (uy-mu)*inv*sv.y + bv.y;
    float tc = (uz-mu)*inv*sv.z + bv.z;
    float td = (uw-mu)*inv*sv.w + bv.w;
    float tn2 = blkSum(ta*ta+tb*tb+tc*tc+td*td, tmp);
    float f = roundtrip_factor(tn2, sc);
    ushort4 o; o.x=f2bf(ta*f); o.y=f2bf(tb*f); o.z=f2bf(tc*f); o.w=f2bf(td*f);
    ((ushort4*)(xtan + (size_t)r*1024))[t] = o;
  }
}

// ---------------- GEMM: C[M][N] = A[M][K](bf16) * Bt[N][K](bf16)^T + bias ----------------
// 2-phase pipelined global_load_lds double-buffer, XOR-swizzled LDS, bijective XCD remap.
// BM=128, BN=64, 4 waves (each 32x64). nt = Kchunk/64 iters.
// EPI: 2 = gelu + bf16 out (z must be 0), 3 = f32 split-K partial at z*M*N (bias only z==0)
template<int EPI>
__global__ __launch_bounds__(256) void k_gemm(const ushort* __restrict__ A,
    const ushort* __restrict__ Bt, const float* __restrict__ bias,
    void* __restrict__ C, int M, int N, int Kstride, int Kchunk){
  constexpr int MF = 2, NF = 4;
  __shared__ ushort As[2][128*64];
  __shared__ ushort Bs[2][64*64];
  const int tid = threadIdx.x;
  const int lane = tid & 63;
  const int wid = tid >> 6;
  const int ro = wid * 32, co = 0;
  const int l15 = lane & 15, hi = lane >> 4;
  // bijective XCD remap per z-slice (slice size % 8 == 0), column-major decode
  const int nwg = gridDim.x * gridDim.y;
  const int lin = blockIdx.y * gridDim.x + blockIdx.x;
  const int qq = nwg >> 3, rr = nwg & 7;
  const int xcd = lin & 7, ii = lin >> 3;
  const int swz = (xcd < rr) ? (xcd*(qq+1) + ii) : (rr*(qq+1) + (xcd-rr)*qq + ii);
  const int m0 = (swz % gridDim.y) * 128;
  const int n0 = (swz / gridDim.y) * 64;
  const int z = blockIdx.z;
  const int kbase = z * Kchunk;
  const int swr = (l15 & 7) << 3;   // read-side XOR (elements)

  f32x4 acc[MF][NF];
  #pragma unroll
  for (int i=0;i<MF;i++)
    #pragma unroll
    for (int j=0;j<NF;j++) acc[i][j] = (f32x4){0.f,0.f,0.f,0.f};

  auto stage = [&](int buf, int koff){
    #pragma unroll
    for (int r2=0;r2<4;r2++){
      int idx = r2*256 + tid;
      int row = idx >> 3, cc = idx & 7;
      int off = koff + ((cc ^ (row & 7)) << 3);
      const ushort* ga = A + (size_t)(m0+row)*Kstride + off;
      int lo = (r2*256 + (tid & 192)) * 8;
      __builtin_amdgcn_global_load_lds((const __attribute__((address_space(1))) uint*)ga,
          (__attribute__((address_space(3))) uint*)&As[buf][lo], 16, 0, 0);
    }
    #pragma unroll
    for (int r2=0;r2<2;r2++){
      int idx = r2*256 + tid;
      int row = idx >> 3, cc = idx & 7;
      int off = koff + ((cc ^ (row & 7)) << 3);
      const ushort* gb = Bt + (size_t)(n0+row)*Kstride + off;
      int lo = (r2*256 + (tid & 192)) * 8;
      __builtin_amdgcn_global_load_lds((const __attribute__((address_space(1))) uint*)gb,
          (__attribute__((address_space(3))) uint*)&Bs[buf][lo], 16, 0, 0);
    }
  };
  auto compute = [&](int buf){
    #pragma unroll
    for (int ks=0;ks<2;ks++){
      bf16x8 af[MF], bfv[NF];
      int cb = (ks*32 + hi*8) ^ swr;
      #pragma unroll
      for (int m2=0;m2<MF;m2++) af[m2]  = *(const bf16x8*)&As[buf][(ro+m2*16+l15)*64 + cb];
      #pragma unroll
      for (int n2=0;n2<NF;n2++) bfv[n2] = *(const bf16x8*)&Bs[buf][(co+n2*16+l15)*64 + cb];
      #pragma unroll
      for (int m2=0;m2<MF;m2++)
        #pragma unroll
        for (int n2=0;n2<NF;n2++)
          acc[m2][n2] = __builtin_amdgcn_mfma_f32_16x16x32_bf16(af[m2], bfv[n2], acc[m2][n2], 0, 0, 0);
    }
  };

  const int nt = Kchunk >> 6;
  stage(0, kbase);
  __syncthreads();
  int cur = 0;
  for (int t = 1; t < nt; ++t){
    stage(cur ^ 1, kbase + t*64);
    compute(cur);
    __syncthreads();
    cur ^= 1;
  }
  compute(cur);

  #pragma unroll
  for (int m=0;m<MF;m++){
    #pragma unroll
    for (int n=0;n<NF;n++){
      int gc = n0 + co + n*16 + l15;
      float bb = (EPI == 3) ? (z == 0 ? bias[gc] : 0.f) : bias[gc];
      #pragma unroll
      for (int i=0;i<4;i++){
        int gr = m0 + ro + m*16 + hi*4 + i;
        float v = acc[m][n][i] + bb;
        if (EPI == 2) v = gelu_t(v);
        if (EPI == 2) ((ushort*)C)[(size_t)gr*N + gc] = f2bf(v);
        else ((float*)C)[(size_t)z*M*N + (size_t)gr*N + gc] = v;
      }
    }
  }
}

// ---------------- fused hyperbolic attention, two-pass scoring ----------------
// grid (H=16, Be=8, 4), 256 threads. qkv input = 2 split-K f32 partials (stride PSTRIDE).
__global__ __launch_bounds__(256) void k_attn3(const float* __restrict__ qkv,
    const float* __restrict__ c_logits, const float* __restrict__ geo,
    ushort* __restrict__ ao){
  constexpr size_t PSTRIDE = (size_t)1024*3072;
  __shared__ float Ks[128*64];   // chunk-rotated float4; reused as o-merge scratch
  __shared__ float Vs[128*64];   // f32 V, chunk-rotated float4
  __shared__ float k2s[128];
  __shared__ float2 mlb[256];
  const int h = blockIdx.x, be = blockIdx.y, qs = blockIdx.z;
  const int tid = threadIdx.x;
  const int r = tid & 31, g = tid >> 5;
  const float cl = c_logits[h];
  const float ch = (cl > 20.f) ? cl : log1pf(__expf(cl));
  const float sc = fmaxf(sqrtf(ch), EPSF);
  const float gs = geo[h];
  float4* Ks4 = (float4*)Ks;
  float4* Vs4 = (float4*)Vs;

  // ---- stage K (threads 0..127) / V (threads 128..255), summing 2 partials ----
  if (tid < 128){
    int row = tid;
    const float4* pa = (const float4*)(qkv + (size_t)(be*128 + row)*3072 + 1024 + h*64);
    const float4* pb = (const float4*)(qkv + PSTRIDE + (size_t)(be*128 + row)*3072 + 1024 + h*64);
    float v[64];
    #pragma unroll
    for (int c=0;c<16;c++){
      float4 ta = pa[c], tb = pb[c];
      v[4*c]=ta.x+tb.x; v[4*c+1]=ta.y+tb.y; v[4*c+2]=ta.z+tb.z; v[4*c+3]=ta.w+tb.w;
    }
    rope64(v, row);
    float n2 = 0.f;
    #pragma unroll
    for (int e=0;e<64;e++) n2 += v[e]*v[e];
    float r2; float f = expmap_factor(n2, sc, r2);
    #pragma unroll
    for (int c=0;c<16;c++){
      float4 val; val.x=v[4*c]*f; val.y=v[4*c+1]*f; val.z=v[4*c+2]*f; val.w=v[4*c+3]*f;
      Ks4[row*16 + ((c + row) & 15)] = val;
    }
    k2s[row] = r2;
  } else {
    int row = tid - 128;
    const float4* pa = (const float4*)(qkv + (size_t)(be*128 + row)*3072 + 2048 + h*64);
    const float4* pb = (const float4*)(qkv + PSTRIDE + (size_t)(be*128 + row)*3072 + 2048 + h*64);
    #pragma unroll
    for (int c=0;c<16;c++){
      float4 ta = pa[c], tb = pb[c];
      float4 vv; vv.x=ta.x+tb.x; vv.y=ta.y+tb.y; vv.z=ta.z+tb.z; vv.w=ta.w+tb.w;
      Vs4[row*16 + ((c + row) & 15)] = vv;
    }
  }

  // ---- q prep (redundant across g; parallel so ~free) ----
  const int qrow = qs*32 + r;
  float q[64];
  {
    const float4* pa = (const float4*)(qkv + (size_t)(be*128 + qrow)*3072 + h*64);
    const float4* pb = (const float4*)(qkv + PSTRIDE + (size_t)(be*128 + qrow)*3072 + h*64);
    #pragma unroll
    for (int c=0;c<16;c++){
      float4 ta = pa[c], tb = pb[c];
      q[4*c]=ta.x+tb.x; q[4*c+1]=ta.y+tb.y; q[4*c+2]=ta.z+tb.z; q[4*c+3]=ta.w+tb.w;
    }
  }
  rope64(q, qrow);
  float qn2 = 0.f;
  #pragma unroll
  for (int e=0;e<64;e++) qn2 += q[e]*q[e];
  float q2; float fq = expmap_factor(qn2, sc, q2);
  #pragma unroll
  for (int e=0;e<64;e++) q[e] *= fq;
  __syncthreads();

  // ---- pass 1: 16 scores ----
  const float Bf = 1.f - ch*q2;
  const float e2 = 2.f*ch;
  const int j0 = g * 16;
  float s[16];
  #pragma unroll
  for (int jj=0;jj<16;jj++){
    int j = j0 + jj;
    float xy = 0.f;
    #pragma unroll
    for (int c=0;c<16;c++){
      float4 kv = Ks4[j*16 + ((c + j) & 15)];
      xy += q[4*c]*kv.x + q[4*c+1]*kv.y + q[4*c+2]*kv.z + q[4*c+3]*kv.w;
    }
    float k2 = k2s[j];
    float Af = 1.f + ch*k2 - e2*xy;
    float den = fmaxf(Af - ch*k2*Bf, EPSF);
    float num2 = fmaxf(Af*(Af*q2 - 2.f*Bf*xy) + Bf*Bf*k2, 0.f);
    float rn = sqrtf(num2)/den;
    rn = (rn >= 1.f) ? ONE_M_EPS : rn;
    float arg = fminf(sc*rn, ONE_M_EPS);
    float d = __logf((1.f+arg)/(1.f-arg)) / sc;
    s[jj] = -gs*d;
  }
  // ---- chunk max ----
  float m = s[0];
  #pragma unroll
  for (int jj=1;jj<16;jj++) m = fmaxf(m, s[jj]);
  // ---- pass 2: exp + V accumulate ----
  float l = 0.f;
  float o[64];
  #pragma unroll
  for (int e=0;e<64;e++) o[e] = 0.f;
  #pragma unroll 2
  for (int jj=0;jj<16;jj++){
    int j = j0 + jj;
    float p = __expf(s[jj] - m);
    l += p;
    #pragma unroll
    for (int c=0;c<16;c++){
      float4 vv = Vs4[j*16 + ((c + j) & 15)];
      o[4*c+0] += p*vv.x;
      o[4*c+1] += p*vv.y;
      o[4*c+2] += p*vv.z;
      o[4*c+3] += p*vv.w;
    }
  }

  // ---- merge 8 partials per q-row ----
  mlb[tid] = make_float2(m, l);
  __syncthreads();
  float M = -1e30f;
  float2 ml[8];
  #pragma unroll
  for (int g2=0;g2<8;g2++){ ml[g2] = mlb[(g2<<5)|r]; M = fmaxf(M, ml[g2].x); }
  float L = 0.f;
  #pragma unroll
  for (int g2=0;g2<8;g2++) L += ml[g2].y * __expf(ml[g2].x - M);
  float w = __expf(m - M);
  #pragma unroll
  for (int e=0;e<64;e++) o[e] *= w;

  float4* S4 = Ks4; // all Ks reads complete at barrier above
  #define WSLOT(s_) { int b = (((s_)<<5)|r)<<4; \
    _Pragma("unroll") for (int c=0;c<16;c++){ \
      float4 t4; t4.x=o[4*c]; t4.y=o[4*c+1]; t4.z=o[4*c+2]; t4.w=o[4*c+3]; \
      S4[b + ((c + r) & 15)] = t4; } }
  #define ASLOT(s_) { int b = (((s_)<<5)|r)<<4; \
    _Pragma("unroll") for (int c=0;c<16;c++){ \
      float4 t4 = S4[b + ((c + r) & 15)]; \
      o[4*c]+=t4.x; o[4*c+1]+=t4.y; o[4*c+2]+=t4.z; o[4*c+3]+=t4.w; } }

  if (g >= 4) WSLOT(g-4);
  __syncthreads();
  if (g < 4)  ASLOT(g);
  __syncthreads();
  if (g == 2 || g == 3) WSLOT(g-2);
  __syncthreads();
  if (g < 2)  ASLOT(g);
  __syncthreads();
  if (g == 1) WSLOT(0);
  __syncthreads();
  if (g == 0){
    ASLOT(0);
    float invl = 1.f/L;
    ushort* dst = ao + (size_t)(be*128 + qrow)*1024 + h*64;
    uint4* dst4 = (uint4*)dst;
    #pragma unroll
    for (int c=0;c<4;c++){
      uint4 pv;
      pv.x = (uint)f2bf(o[16*c+0]*invl) | ((uint)f2bf(o[16*c+1]*invl)<<16);
      pv.y = (uint)f2bf(o[16*c+2]*invl) | ((uint)f2bf(o[16*c+3]*invl)<<16);
      pv.z = (uint)f2bf(o[16*c+4]*invl) | ((uint)f2bf(o[16*c+5]*invl)<<16);
      pv.w = (uint)f2bf(o[16*c+6]*invl) | ((uint)f2bf(o[16*c+7]*invl)<<16);
      dst4[2*c] = pv;
      pv.x = (uint)f2bf(o[16*c+8]*invl)  | ((uint)f2bf(o[16*c+9]*invl)<<16);
      pv.y = (uint)f2bf(o[16*c+10]*invl) | ((uint)f2bf(o[16*c+11]*invl)<<16);
      pv.z = (uint)f2bf(o[16*c+12]*invl) | ((uint)f2bf(o[16*c+13]*invl)<<16);
      pv.w = (uint)f2bf(o[16*c+14]*invl) | ((uint)f2bf(o[16*c+15]*invl)<<16);
      dst4[2*c+1] = pv;
    }
  }
  #undef WSLOT
  #undef ASLOT
}

// ---------------- post-attention: mobius residual + LN2 roundtrip -> t (bf16) ----------------
// proj = sum of 4 split-K partials
__global__ __launch_bounds__(256) void k_postattn(const float* __restrict__ x,
    const float* __restrict__ proj, const float* __restrict__ cg,
    const float* __restrict__ lns, const float* __restrict__ lnb,
    float* __restrict__ xatt, ushort* __restrict__ tout){
  __shared__ float tmp[8];
  int r = blockIdx.x, t = threadIdx.x;
  float c = cg[0], sc = fmaxf(sqrtf(c), EPSF);
  float4 pa = ((const float4*)(proj + (size_t)r*1024))[t];
  float4 pb = ((const float4*)(proj + 1024*1024 + (size_t)r*1024))[t];
  float4 pc = ((const float4*)(proj + 2*1024*1024 + (size_t)r*1024))[t];
  float4 pd = ((const float4*)(proj + 3*1024*1024 + (size_t)r*1024))[t];
  float4 pv; pv.x=(pa.x+pb.x)+(pc.x+pd.x); pv.y=(pa.y+pb.y)+(pc.y+pd.y);
  pv.z=(pa.z+pb.z)+(pc.z+pd.z); pv.w=(pa.w+pb.w)+(pc.w+pd.w);
  float4 xv = ((const float4*)(x + (size_t)r*1024))[t];
  float pn2 = blkSum(pv.x*pv.x+pv.y*pv.y+pv.z*pv.z+pv.w*pv.w, tmp);
  float y2; float fy = expmap_factor(pn2, sc, y2);
  float ya = pv.x*fy, yb = pv.y*fy, yc = pv.z*fy, yd = pv.w*fy;
  float2 s = blkSum2(xv.x*xv.x+xv.y*xv.y+xv.z*xv.z+xv.w*xv.w,
                     xv.x*ya+xv.y*yb+xv.z*yc+xv.w*yd, tmp);
  float x2 = s.x, xy = s.y;
  float Af = 1.f + 2.f*c*xy + c*y2;
  float Bf = 1.f - c*x2;
  float den = fmaxf(1.f + 2.f*c*xy + c*c*x2*y2, EPSF);
  float num2 = fmaxf(Af*Af*x2 + 2.f*Af*Bf*xy + Bf*Bf*y2, 0.f);
  float rn = sqrtf(num2)/den;
  float fp = (rn >= 1.f) ? (ONE_M_EPS/fmaxf(rn,EPSF)) : 1.f;
  float xan = (rn >= 1.f) ? ONE_M_EPS : rn;
  float g = fp/den;
  float xa = (Af*xv.x + Bf*ya)*g;
  float xb = (Af*xv.y + Bf*yb)*g;
  float xc = (Af*xv.z + Bf*yc)*g;
  float xd = (Af*xv.w + Bf*yd)*g;
  float4 xo; xo.x=xa; xo.y=xb; xo.z=xc; xo.w=xd;
  ((float4*)(xatt + (size_t)r*1024))[t] = xo;
  float at = (rn >= 1.f) ? ATANH_1ME : atanh_c(xan);
  float fl = (xan < EPSF) ? 0.f : at / sc / fmaxf(xan, EPSF);
  float ux = xa*fl, uy = xb*fl, uz = xc*fl, uw = xd*fl;
  float2 s12 = blkSum2(ux+uy+uz+uw, ux*ux+uy*uy+uz*uz+uw*uw, tmp);
  float mu = s12.x*(1.f/1024.f);
  float var = s12.y*(1.f/1024.f) - mu*mu;
  float inv = rsqrtf(var + 1e-6f);
  float4 sv = ((const float4*)lns)[t];
  float4 bv = ((const float4*)lnb)[t];
  float ta = (ux-mu)*inv*sv.x + bv.x;
  float tb = (uy-mu)*inv*sv.y + bv.y;
  float tc = (uz-mu)*inv*sv.z + bv.z;
  float td = (uw-mu)*inv*sv.w + bv.w;
  float tn2 = blkSum(ta*ta+tb*tb+tc*tc+td*td, tmp);
  float f = roundtrip_factor(tn2, sc);
  ushort4 o; o.x=f2bf(ta*f); o.y=f2bf(tb*f); o.z=f2bf(tc*f); o.w=f2bf(td*f);
  ((ushort4*)(tout + (size_t)r*1024))[t] = o;
}

// ---------------- final: out = mobius_add(x_att, expmap0(tf)) ----------------
// tf = sum of 4 split-K partials
__global__ __launch_bounds__(256) void k_final(const float* __restrict__ xatt,
    const float* __restrict__ tf, const float* __restrict__ cg, float* __restrict__ out){
  __shared__ float tmp[8];
  int r = blockIdx.x, t = threadIdx.x;
  float c = cg[0], sc = fmaxf(sqrtf(c), EPSF);
  float4 fa = ((const float4*)(tf + (size_t)r*1024))[t];
  float4 fb = ((const float4*)(tf + 1024*1024 + (size_t)r*1024))[t];
  float4 fc = ((const float4*)(tf + 2*1024*1024 + (size_t)r*1024))[t];
  float4 fd = ((const float4*)(tf + 3*1024*1024 + (size_t)r*1024))[t];
  float4 fv; fv.x=(fa.x+fb.x)+(fc.x+fd.x); fv.y=(fa.y+fb.y)+(fc.y+fd.y);
  fv.z=(fa.z+fb.z)+(fc.z+fd.z); fv.w=(fa.w+fb.w)+(fc.w+fd.w);
  float4 xv = ((const float4*)(xatt + (size_t)r*1024))[t];
  float fn2 = blkSum(fv.x*fv.x+fv.y*fv.y+fv.z*fv.z+fv.w*fv.w, tmp);
  float y2; float fy = expmap_factor(fn2, sc, y2);
  float ya = fv.x*fy, yb = fv.y*fy, yc = fv.z*fy, yd = fv.w*fy;
  float2 s = blkSum2(xv.x*xv.x+xv.y*xv.y+xv.z*xv.z+xv.w*xv.w,
                     xv.x*ya+xv.y*yb+xv.z*yc+xv.w*yd, tmp);
  float x2 = s.x, xy = s.y;
  float Af = 1.f + 2.f*c*xy + c*y2;
  float Bf = 1.f - c*x2;
  float den = fmaxf(1.f + 2.f*c*xy + c*c*x2*y2, EPSF);
  float num2 = fmaxf(Af*Af*x2 + 2.f*Af*Bf*xy + Bf*Bf*y2, 0.f);
  float rn = sqrtf(num2)/den;
  float fp = (rn >= 1.f) ? (ONE_M_EPS/fmaxf(rn,EPSF)) : 1.f;
  float g = fp/den;
  float4 o;
  o.x = (Af*xv.x + Bf*ya)*g;
  o.y = (Af*xv.y + Bf*yb)*g;
  o.z = (Af*xv.z + Bf*yc)*g;
  o.w = (Af*xv.w + Bf*yd)*g;
  ((float4*)(out + (size_t)r*1024))[t] = o;
}

extern "C" void kernel_launch(void* const* d_in, const int* in_sizes, int n_in,
                              void* d_out, int out_size, void* d_ws, size_t ws_size,
                              hipStream_t stream){
  (void)in_sizes; (void)n_in; (void)out_size; (void)ws_size;
  const float* x     = (const float*)d_in[0];
  const float* cg    = (const float*)d_in[1];
  const float* qkv_w = (const float*)d_in[2];
  const float* qkv_b = (const float*)d_in[3];
  const float* out_w = (const float*)d_in[4];
  const float* out_b = (const float*)d_in[5];
  const float* ffn_w1= (const float*)d_in[6];
  const float* ffn_b1= (const float*)d_in[7];
  const float* ffn_w2= (const float*)d_in[8];
  const float* ffn_b2= (const float*)d_in[9];
  const float* ln1s  = (const float*)d_in[10];
  const float* ln1b  = (const float*)d_in[11];
  const float* ln2s  = (const float*)d_in[12];
  const float* ln2b  = (const float*)d_in[13];
  const float* clog  = (const float*)d_in[14];
  const float* geo   = (const float*)d_in[15];

  char* p = (char*)d_ws;
  auto take = [&](size_t n){ char* r = p; p += (n + 255) & ~(size_t)255; return r; };
  ushort* wt_qkv  = (ushort*)take((size_t)3072*1024*2);
  ushort* wt_out  = (ushort*)take((size_t)1024*1024*2);
  ushort* wt_ffn1 = (ushort*)take((size_t)4096*1024*2);
  ushort* wt_ffn2 = (ushort*)take((size_t)1024*4096*2);
  float*  bufA    = (float*)take((size_t)2*1024*3072*4);  // qkv 2 partials ; later gelu bf16
  ushort* bufB    = (ushort*)take((size_t)1024*1024*2);   // x_tan ; later ao
  float*  bufC    = (float*)take((size_t)4*1024*1024*4);  // split-K partials (4x 4MB)
  float*  xatt    = (float*)take((size_t)1024*1024*4);
  ushort* tbuf    = (ushort*)take((size_t)1024*1024*2);

  k_pre<<<13312, 256, 0, stream>>>(qkv_w, out_w, ffn_w1, ffn_w2, x, cg, ln1s, ln1b,
                                   wt_qkv, wt_out, wt_ffn1, wt_ffn2, bufB);
  // qkv: split-K2, f32 partials (2 x 12MB)
  k_gemm<3><<<dim3(48,8,2), 256, 0, stream>>>(bufB, wt_qkv, qkv_b, (void*)bufA, 1024, 3072, 1024, 512);
  k_attn3<<<dim3(16,8,4), 256, 0, stream>>>(bufA, clog, geo, bufB);
  // out-proj: split-K4
  k_gemm<3><<<dim3(16,8,4), 256, 0, stream>>>(bufB, wt_out, out_b, (void*)bufC, 1024, 1024, 1024, 256);
  k_postattn<<<1024, 256, 0, stream>>>(x, bufC, cg, ln2s, ln2b, xatt, tbuf);
  // ffn1: gelu epilogue, full K
  k_gemm<2><<<dim3(64,8,1), 256, 0, stream>>>(tbuf, wt_ffn1, ffn_b1, (void*)bufA, 1024, 4096, 1024, 1024);
  // ffn2: split-K4
  k_gemm<3><<<dim3(16,8,4), 256, 0, stream>>>((const ushort*)bufA, wt_ffn2, ffn_b2, (void*)bufC, 1024, 1024, 4096, 1024);
  k_final<<<1024, 256, 0, stream>>>(xatt, bufC, cg, (float*)d_out);
}

// Round 6
// 123.383 us; speedup vs baseline: 4.4012x; 1.1224x over previous
//
#include <hip/hip_runtime.h>

typedef unsigned int uint;
typedef unsigned short ushort;
typedef __attribute__((ext_vector_type(8))) short bf16x8;
typedef __attribute__((ext_vector_type(4))) float f32x4;

#define EPSF 1e-7f
#define ONE_M_EPS 0.99999988079071044921875f /* f32 nearest to 1-1e-7 */
#define ATANH_1ME 8.4056213f                 /* atanh(1-1e-7), f64-accurate */
#define Y2_CLIP 0.99999982f                  /* (1-1e-7)^2 */

__device__ __forceinline__ ushort f2bf(float f){
  union{float f;uint u;}x; x.f=f; uint u=x.u;
  return (ushort)((u + 0x7fffu + ((u>>16)&1u)) >> 16);
}
__device__ __forceinline__ float bf2f(ushort u){
  union{uint u;float f;}x; x.u = ((uint)u)<<16; return x.f;
}
__device__ __forceinline__ float atanh_c(float a){
  a = fminf(a, ONE_M_EPS);
  return 0.5f*__logf((1.f+a)/(1.f-a));
}
__device__ __forceinline__ float gelu_t(float v){
  return 0.5f*v*(1.f + tanhf(0.7978845608f*(v + 0.044715f*v*v*v)));
}

__device__ __forceinline__ float expmap_factor(float n2, float sc, float& r2){
  float n = sqrtf(n2);
  if (n < EPSF) { r2 = 0.f; return 0.f; }
  float mag = tanhf(sc*n)/sc;
  float f = mag/n;
  if (mag >= 1.f) { f *= ONE_M_EPS/mag; r2 = Y2_CLIP; }
  else r2 = mag*mag;
  return f;
}
__device__ __forceinline__ float roundtrip_factor(float tn2, float sc){
  float tn = sqrtf(tn2);
  if (tn < EPSF) return 0.f;
  float mag = tanhf(sc*tn)/sc;
  if (mag >= 1.f) {
    return ATANH_1ME / (sc * tn);
  } else {
    if (mag < EPSF) return 0.f;
    return (mag/tn) * (atanh_c(mag) / (sc * mag));
  }
}

__device__ __forceinline__ void rope64(float* v, int row){
  #pragma unroll
  for (int i=0;i<32;i++){
    float fr = __expf(-(float)i * 0.28782313662f); // ln(10000)/32
    float sn, cn; __sincosf((float)row * fr, &sn, &cn);
    float a = v[i], b = v[i+32];
    v[i] = a*cn - b*sn;
    v[i+32] = a*sn + b*cn;
  }
}

// ---------------- block reductions (256 threads) ----------------
__device__ __forceinline__ float blkSum(float v, float* tmp){
  #pragma unroll
  for (int o=32;o>0;o>>=1) v += __shfl_xor(v, o, 64);
  int w = threadIdx.x >> 6;
  if ((threadIdx.x & 63) == 0) tmp[w] = v;
  __syncthreads();
  v = tmp[0]+tmp[1]+tmp[2]+tmp[3];
  __syncthreads();
  return v;
}
__device__ __forceinline__ float2 blkSum2(float a, float b, float* tmp){
  #pragma unroll
  for (int o=32;o>0;o>>=1){ a += __shfl_xor(a, o, 64); b += __shfl_xor(b, o, 64); }
  int w = threadIdx.x >> 6;
  if ((threadIdx.x & 63) == 0){ tmp[w] = a; tmp[4+w] = b; }
  __syncthreads();
  float2 r; r.x = tmp[0]+tmp[1]+tmp[2]+tmp[3]; r.y = tmp[4]+tmp[5]+tmp[6]+tmp[7];
  __syncthreads();
  return r;
}

// ---------------- fused front-end: 4 weight transposes + prep ----------------
__global__ __launch_bounds__(256) void k_pre(const float* __restrict__ qkv_w,
    const float* __restrict__ out_w, const float* __restrict__ ffn_w1,
    const float* __restrict__ ffn_w2, const float* __restrict__ x,
    const float* __restrict__ cg, const float* __restrict__ lns, const float* __restrict__ lnb,
    ushort* __restrict__ wq, ushort* __restrict__ wo,
    ushort* __restrict__ w1, ushort* __restrict__ w2, ushort* __restrict__ xtan){
  __shared__ float s[32][33];
  int b = blockIdx.x;
  if (b < 12288){
    const float* W; ushort* WT; int K, N;
    if (b < 3072){ W=qkv_w; WT=wq; K=1024; N=3072; }
    else if (b < 4096){ b-=3072; W=out_w; WT=wo; K=1024; N=1024; }
    else if (b < 8192){ b-=4096; W=ffn_w1; WT=w1; K=1024; N=4096; }
    else { b-=8192; W=ffn_w2; WT=w2; K=4096; N=1024; }
    int nbn = N >> 5;
    int n0 = (b % nbn)*32, k0 = (b / nbn)*32;
    int tx = threadIdx.x & 31, ty = threadIdx.x >> 5; // (32,8)
    #pragma unroll
    for (int i=0;i<4;i++)
      s[ty+8*i][tx] = W[(size_t)(k0+ty+8*i)*N + n0+tx];
    __syncthreads();
    #pragma unroll
    for (int i=0;i<4;i++)
      WT[(size_t)(n0+ty+8*i)*K + k0+tx] = f2bf(s[tx][ty+8*i]);
  } else {
    float* tmp = &s[0][0];
    int r = b - 12288, t = threadIdx.x;
    float c = cg[0];
    float sc = fmaxf(sqrtf(c), EPSF);
    float4 xv = ((const float4*)(x + (size_t)r*1024))[t];
    float n2 = blkSum(xv.x*xv.x + xv.y*xv.y + xv.z*xv.z + xv.w*xv.w, tmp);
    float n = sqrtf(n2);
    float f1 = (n < EPSF) ? 0.f : (atanh_c(n) / sc / n);
    float ux = xv.x*f1, uy = xv.y*f1, uz = xv.z*f1, uw = xv.w*f1;
    float2 s12 = blkSum2(ux+uy+uz+uw, ux*ux+uy*uy+uz*uz+uw*uw, tmp);
    float mu = s12.x*(1.f/1024.f);
    float var = s12.y*(1.f/1024.f) - mu*mu;
    float inv = rsqrtf(var + 1e-6f);
    float4 sv = ((const float4*)lns)[t];
    float4 bv = ((const float4*)lnb)[t];
    float ta = (ux-mu)*inv*sv.x + bv.x;
    float tb = (uy-mu)*inv*sv.y + bv.y;
    float tc = (uz-mu)*inv*sv.z + bv.z;
    float td = (uw-mu)*inv*sv.w + bv.w;
    float tn2 = blkSum(ta*ta+tb*tb+tc*tc+td*td, tmp);
    float f = roundtrip_factor(tn2, sc);
    ushort4 o; o.x=f2bf(ta*f); o.y=f2bf(tb*f); o.z=f2bf(tc*f); o.w=f2bf(td*f);
    ((ushort4*)(xtan + (size_t)r*1024))[t] = o;
  }
}

// ---------------- GEMM: C[M][N] = A[M][K](bf16) * Bt[N][K](bf16)^T + bias ----------------
// 2-phase pipelined global_load_lds double-buffer, XOR-swizzled LDS, bijective XCD remap.
// BM=128, BN=64, 4 waves (each 32x64).
// EPI: 2 = gelu + bf16 out (z==0), 3 = f32 split-K partial at z*M*N (bias only z==0)
template<int EPI>
__global__ __launch_bounds__(256) void k_gemm(const ushort* __restrict__ A,
    const ushort* __restrict__ Bt, const float* __restrict__ bias,
    void* __restrict__ C, int M, int N, int Kstride, int Kchunk){
  constexpr int MF = 2, NF = 4;
  __shared__ ushort As[2][128*64];
  __shared__ ushort Bs[2][64*64];
  const int tid = threadIdx.x;
  const int lane = tid & 63;
  const int wid = tid >> 6;
  const int ro = wid * 32, co = 0;
  const int l15 = lane & 15, hi = lane >> 4;
  const int nwg = gridDim.x * gridDim.y;
  const int lin = blockIdx.y * gridDim.x + blockIdx.x;
  const int qq = nwg >> 3, rr = nwg & 7;
  const int xcd = lin & 7, ii = lin >> 3;
  const int swz = (xcd < rr) ? (xcd*(qq+1) + ii) : (rr*(qq+1) + (xcd-rr)*qq + ii);
  const int m0 = (swz % gridDim.y) * 128;
  const int n0 = (swz / gridDim.y) * 64;
  const int z = blockIdx.z;
  const int kbase = z * Kchunk;
  const int swr = (l15 & 7) << 3;

  f32x4 acc[MF][NF];
  #pragma unroll
  for (int i=0;i<MF;i++)
    #pragma unroll
    for (int j=0;j<NF;j++) acc[i][j] = (f32x4){0.f,0.f,0.f,0.f};

  auto stage = [&](int buf, int koff){
    #pragma unroll
    for (int r2=0;r2<4;r2++){
      int idx = r2*256 + tid;
      int row = idx >> 3, cc = idx & 7;
      int off = koff + ((cc ^ (row & 7)) << 3);
      const ushort* ga = A + (size_t)(m0+row)*Kstride + off;
      int lo = (r2*256 + (tid & 192)) * 8;
      __builtin_amdgcn_global_load_lds((const __attribute__((address_space(1))) uint*)ga,
          (__attribute__((address_space(3))) uint*)&As[buf][lo], 16, 0, 0);
    }
    #pragma unroll
    for (int r2=0;r2<2;r2++){
      int idx = r2*256 + tid;
      int row = idx >> 3, cc = idx & 7;
      int off = koff + ((cc ^ (row & 7)) << 3);
      const ushort* gb = Bt + (size_t)(n0+row)*Kstride + off;
      int lo = (r2*256 + (tid & 192)) * 8;
      __builtin_amdgcn_global_load_lds((const __attribute__((address_space(1))) uint*)gb,
          (__attribute__((address_space(3))) uint*)&Bs[buf][lo], 16, 0, 0);
    }
  };
  auto compute = [&](int buf){
    #pragma unroll
    for (int ks=0;ks<2;ks++){
      bf16x8 af[MF], bfv[NF];
      int cb = (ks*32 + hi*8) ^ swr;
      #pragma unroll
      for (int m2=0;m2<MF;m2++) af[m2]  = *(const bf16x8*)&As[buf][(ro+m2*16+l15)*64 + cb];
      #pragma unroll
      for (int n2=0;n2<NF;n2++) bfv[n2] = *(const bf16x8*)&Bs[buf][(co+n2*16+l15)*64 + cb];
      #pragma unroll
      for (int m2=0;m2<MF;m2++)
        #pragma unroll
        for (int n2=0;n2<NF;n2++)
          acc[m2][n2] = __builtin_amdgcn_mfma_f32_16x16x32_bf16(af[m2], bfv[n2], acc[m2][n2], 0, 0, 0);
    }
  };

  const int nt = Kchunk >> 6;
  stage(0, kbase);
  __syncthreads();
  int cur = 0;
  for (int t = 1; t < nt; ++t){
    stage(cur ^ 1, kbase + t*64);
    compute(cur);
    __syncthreads();
    cur ^= 1;
  }
  compute(cur);

  #pragma unroll
  for (int m=0;m<MF;m++){
    #pragma unroll
    for (int n=0;n<NF;n++){
      int gc = n0 + co + n*16 + l15;
      float bb = (EPI == 3) ? (z == 0 ? bias[gc] : 0.f) : bias[gc];
      #pragma unroll
      for (int i=0;i<4;i++){
        int gr = m0 + ro + m*16 + hi*4 + i;
        float v = acc[m][n][i] + bb;
        if (EPI == 2) v = gelu_t(v);
        if (EPI == 2) ((ushort*)C)[(size_t)gr*N + gc] = f2bf(v);
        else ((float*)C)[(size_t)z*M*N + (size_t)gr*N + gc] = v;
      }
    }
  }
}

// ---------------- MFMA hyperbolic attention ----------------
// grid (H=16, Be=8, qs=4), 128 threads (2 waves). Block: 32 q-rows x 128 kv.
// Q/K/V staged as hi/lo bf16 pairs (value = hi + lo, ~f32 precision through MFMA).
// qkv input = 2 split-K f32 partials (stride PSTRIDE).
__global__ __launch_bounds__(128) void k_attn4(const float* __restrict__ qkv,
    const float* __restrict__ c_logits, const float* __restrict__ geo,
    ushort* __restrict__ ao){
  constexpr size_t PSTRIDE = (size_t)1024*3072;
  __shared__ ushort Kh[128*64], Kl[128*64];   // after QK^T: Ph/Pl overlay (32x128)
  __shared__ ushort Vth[64*128], Vtl[64*128]; // V transposed [d][kv]
  __shared__ ushort Qh[32*64], Ql[32*64];
  __shared__ float k2s[128], q2s[32];
  const int h = blockIdx.x, be = blockIdx.y, qs = blockIdx.z;
  const int tid = threadIdx.x;
  const float cl = c_logits[h];
  const float ch = (cl > 20.f) ? cl : log1pf(__expf(cl));
  const float sc = fmaxf(sqrtf(ch), EPSF);
  const float gs = geo[h];

  // ---- stage K row tid (rope + expmap + hi/lo split, XOR-swizzled 16B chunks) ----
  {
    int kv = tid;
    const float4* pa = (const float4*)(qkv + (size_t)(be*128+kv)*3072 + 1024 + h*64);
    const float4* pb = (const float4*)(qkv + PSTRIDE + (size_t)(be*128+kv)*3072 + 1024 + h*64);
    float v[64];
    #pragma unroll
    for (int c=0;c<16;c++){
      float4 ta = pa[c], tb = pb[c];
      v[4*c]=ta.x+tb.x; v[4*c+1]=ta.y+tb.y; v[4*c+2]=ta.z+tb.z; v[4*c+3]=ta.w+tb.w;
    }
    rope64(v, kv);
    float n2 = 0.f;
    #pragma unroll
    for (int e=0;e<64;e++) n2 += v[e]*v[e];
    float r2; float f = expmap_factor(n2, sc, r2);
    k2s[kv] = r2;
    #pragma unroll
    for (int cch=0; cch<8; cch++){
      uint4 uh, ul;
      uint hw[4], lw[4];
      #pragma unroll
      for (int w2=0; w2<4; w2++){
        float a0 = v[cch*8 + w2*2] * f, a1 = v[cch*8 + w2*2 + 1] * f;
        ushort h0 = f2bf(a0); ushort l0 = f2bf(a0 - bf2f(h0));
        ushort h1 = f2bf(a1); ushort l1 = f2bf(a1 - bf2f(h1));
        hw[w2] = (uint)h0 | ((uint)h1<<16);
        lw[w2] = (uint)l0 | ((uint)l1<<16);
      }
      uh.x=hw[0]; uh.y=hw[1]; uh.z=hw[2]; uh.w=hw[3];
      ul.x=lw[0]; ul.y=lw[1]; ul.z=lw[2]; ul.w=lw[3];
      int idx = kv*64 + ((cch ^ (kv&7))<<3);
      *(uint4*)&Kh[idx] = uh;
      *(uint4*)&Kl[idx] = ul;
    }
  }
  // ---- stage V row tid (transpose into [d][kv], hi/lo) ----
  {
    int kv = tid;
    const float4* pa = (const float4*)(qkv + (size_t)(be*128+kv)*3072 + 2048 + h*64);
    const float4* pb = (const float4*)(qkv + PSTRIDE + (size_t)(be*128+kv)*3072 + 2048 + h*64);
    float v[64];
    #pragma unroll
    for (int c=0;c<16;c++){
      float4 ta = pa[c], tb = pb[c];
      v[4*c]=ta.x+tb.x; v[4*c+1]=ta.y+tb.y; v[4*c+2]=ta.z+tb.z; v[4*c+3]=ta.w+tb.w;
    }
    #pragma unroll
    for (int d=0; d<64; d++){
      float a = v[d];
      ushort hh = f2bf(a); ushort ll = f2bf(a - bf2f(hh));
      int idx = d*128 + (((kv>>3) ^ (d&7))<<3) + (kv&7);
      Vth[idx] = hh; Vtl[idx] = ll;
    }
  }
  // ---- stage Q rows (threads 0..31) ----
  if (tid < 32){
    int qrow = qs*32 + tid;
    const float4* pa = (const float4*)(qkv + (size_t)(be*128+qrow)*3072 + h*64);
    const float4* pb = (const float4*)(qkv + PSTRIDE + (size_t)(be*128+qrow)*3072 + h*64);
    float v[64];
    #pragma unroll
    for (int c=0;c<16;c++){
      float4 ta = pa[c], tb = pb[c];
      v[4*c]=ta.x+tb.x; v[4*c+1]=ta.y+tb.y; v[4*c+2]=ta.z+tb.z; v[4*c+3]=ta.w+tb.w;
    }
    rope64(v, qrow);
    float n2 = 0.f;
    #pragma unroll
    for (int e=0;e<64;e++) n2 += v[e]*v[e];
    float r2; float f = expmap_factor(n2, sc, r2);
    q2s[tid] = r2;
    #pragma unroll
    for (int cch=0; cch<8; cch++){
      uint4 uh, ul;
      uint hw[4], lw[4];
      #pragma unroll
      for (int w2=0; w2<4; w2++){
        float a0 = v[cch*8 + w2*2] * f, a1 = v[cch*8 + w2*2 + 1] * f;
        ushort h0 = f2bf(a0); ushort l0 = f2bf(a0 - bf2f(h0));
        ushort h1 = f2bf(a1); ushort l1 = f2bf(a1 - bf2f(h1));
        hw[w2] = (uint)h0 | ((uint)h1<<16);
        lw[w2] = (uint)l0 | ((uint)l1<<16);
      }
      uh.x=hw[0]; uh.y=hw[1]; uh.z=hw[2]; uh.w=hw[3];
      ul.x=lw[0]; ul.y=lw[1]; ul.z=lw[2]; ul.w=lw[3];
      int idx = tid*64 + ((cch ^ (tid&7))<<3);
      *(uint4*)&Qh[idx] = uh;
      *(uint4*)&Ql[idx] = ul;
    }
  }
  __syncthreads();

  // ---- QK^T: S[32][128] via 16x16x32 MFMA, hi/lo 3-pass ----
  const int lane = tid & 63, w = tid >> 6;
  const int l15 = lane & 15, hi4 = lane >> 4;
  f32x4 acc[8];
  #pragma unroll
  for (int nf=0;nf<8;nf++) acc[nf] = (f32x4){0.f,0.f,0.f,0.f};
  #pragma unroll
  for (int ks=0; ks<2; ks++){
    int qrowL = w*16 + l15;
    int qidx = qrowL*64 + (((ks*4 + hi4) ^ (qrowL&7))<<3);
    bf16x8 qh = *(const bf16x8*)&Qh[qidx];
    bf16x8 ql2 = *(const bf16x8*)&Ql[qidx];
    #pragma unroll
    for (int nf=0; nf<8; nf++){
      int krow = nf*16 + l15;
      int kidx = krow*64 + (((ks*4 + hi4) ^ (krow&7))<<3);
      bf16x8 kh = *(const bf16x8*)&Kh[kidx];
      bf16x8 kl2 = *(const bf16x8*)&Kl[kidx];
      acc[nf] = __builtin_amdgcn_mfma_f32_16x16x32_bf16(qh, kh, acc[nf], 0, 0, 0);
      acc[nf] = __builtin_amdgcn_mfma_f32_16x16x32_bf16(qh, kl2, acc[nf], 0, 0, 0);
      acc[nf] = __builtin_amdgcn_mfma_f32_16x16x32_bf16(ql2, kh, acc[nf], 0, 0, 0);
    }
  }
  __syncthreads();   // all K reads complete -> P may overlay Kh/Kl

  // ---- distance + softmax in registers (C-layout: row=(lane>>4)*4+i, col=lane&15) ----
  float q2v[4], Bfv[4];
  #pragma unroll
  for (int i=0;i<4;i++){ q2v[i] = q2s[w*16 + hi4*4 + i]; Bfv[i] = 1.f - ch*q2v[i]; }
  const float e2 = 2.f*ch;
  #pragma unroll
  for (int nf=0; nf<8; nf++){
    float k2 = k2s[nf*16 + l15];
    #pragma unroll
    for (int i=0;i<4;i++){
      float xy = acc[nf][i];
      float Af = 1.f + ch*k2 - e2*xy;
      float den = fmaxf(Af - ch*k2*Bfv[i], EPSF);
      float num2 = fmaxf(Af*(Af*q2v[i] - 2.f*Bfv[i]*xy) + Bfv[i]*Bfv[i]*k2, 0.f);
      float rn = sqrtf(num2)/den;
      rn = (rn >= 1.f) ? ONE_M_EPS : rn;
      float arg = fminf(sc*rn, ONE_M_EPS);
      float dd = __logf((1.f+arg)/(1.f-arg)) / sc;
      acc[nf][i] = -gs*dd;
    }
  }
  #pragma unroll
  for (int i=0;i<4;i++){
    float m = acc[0][i];
    #pragma unroll
    for (int nf=1;nf<8;nf++) m = fmaxf(m, acc[nf][i]);
    #pragma unroll
    for (int o=1;o<16;o<<=1) m = fmaxf(m, __shfl_xor(m, o));
    float l = 0.f;
    #pragma unroll
    for (int nf=0;nf<8;nf++){ float pp = __expf(acc[nf][i]-m); acc[nf][i] = pp; l += pp; }
    #pragma unroll
    for (int o=1;o<16;o<<=1) l += __shfl_xor(l, o);
    float inv = 1.f/l;
    #pragma unroll
    for (int nf=0;nf<8;nf++){
      float p = acc[nf][i]*inv;
      ushort ph = f2bf(p);
      ushort pl = f2bf(p - bf2f(ph));
      int row = w*16 + hi4*4 + i, col = nf*16 + l15;
      int idx = row*128 + (((col>>3) ^ (row&7))<<3) + (col&7);
      Kh[idx] = ph; Kl[idx] = pl;
    }
  }
  __syncthreads();

  // ---- PV: ao[32][64] via MFMA, hi/lo 3-pass ----
  f32x4 acc2[4];
  #pragma unroll
  for (int nf=0;nf<4;nf++) acc2[nf] = (f32x4){0.f,0.f,0.f,0.f};
  #pragma unroll
  for (int ks=0; ks<4; ks++){
    int prow = w*16 + l15;
    int pidx = prow*128 + (((ks*4 + hi4) ^ (prow&7))<<3);
    bf16x8 ph = *(const bf16x8*)&Kh[pidx];
    bf16x8 pl = *(const bf16x8*)&Kl[pidx];
    #pragma unroll
    for (int nf=0; nf<4; nf++){
      int vrow = nf*16 + l15;
      int vidx = vrow*128 + (((ks*4 + hi4) ^ (vrow&7))<<3);
      bf16x8 vh = *(const bf16x8*)&Vth[vidx];
      bf16x8 vl = *(const bf16x8*)&Vtl[vidx];
      acc2[nf] = __builtin_amdgcn_mfma_f32_16x16x32_bf16(ph, vh, acc2[nf], 0, 0, 0);
      acc2[nf] = __builtin_amdgcn_mfma_f32_16x16x32_bf16(ph, vl, acc2[nf], 0, 0, 0);
      acc2[nf] = __builtin_amdgcn_mfma_f32_16x16x32_bf16(pl, vh, acc2[nf], 0, 0, 0);
    }
  }
  #pragma unroll
  for (int nf=0; nf<4; nf++)
    #pragma unroll
    for (int i=0;i<4;i++){
      int row = qs*32 + w*16 + hi4*4 + i;
      int col = nf*16 + l15;
      ao[(size_t)(be*128 + row)*1024 + h*64 + col] = f2bf(acc2[nf][i]);
    }
}

// ---------------- post-attention: mobius residual + LN2 roundtrip -> t (bf16) ----------------
__global__ __launch_bounds__(256) void k_postattn(const float* __restrict__ x,
    const float* __restrict__ proj, const float* __restrict__ cg,
    const float* __restrict__ lns, const float* __restrict__ lnb,
    float* __restrict__ xatt, ushort* __restrict__ tout){
  __shared__ float tmp[8];
  int r = blockIdx.x, t = threadIdx.x;
  float c = cg[0], sc = fmaxf(sqrtf(c), EPSF);
  float4 pa = ((const float4*)(proj + (size_t)r*1024))[t];
  float4 pb = ((const float4*)(proj + 1024*1024 + (size_t)r*1024))[t];
  float4 pc = ((const float4*)(proj + 2*1024*1024 + (size_t)r*1024))[t];
  float4 pd = ((const float4*)(proj + 3*1024*1024 + (size_t)r*1024))[t];
  float4 pv; pv.x=(pa.x+pb.x)+(pc.x+pd.x); pv.y=(pa.y+pb.y)+(pc.y+pd.y);
  pv.z=(pa.z+pb.z)+(pc.z+pd.z); pv.w=(pa.w+pb.w)+(pc.w+pd.w);
  float4 xv = ((const float4*)(x + (size_t)r*1024))[t];
  float pn2 = blkSum(pv.x*pv.x+pv.y*pv.y+pv.z*pv.z+pv.w*pv.w, tmp);
  float y2; float fy = expmap_factor(pn2, sc, y2);
  float ya = pv.x*fy, yb = pv.y*fy, yc = pv.z*fy, yd = pv.w*fy;
  float2 s = blkSum2(xv.x*xv.x+xv.y*xv.y+xv.z*xv.z+xv.w*xv.w,
                     xv.x*ya+xv.y*yb+xv.z*yc+xv.w*yd, tmp);
  float x2 = s.x, xy = s.y;
  float Af = 1.f + 2.f*c*xy + c*y2;
  float Bf = 1.f - c*x2;
  float den = fmaxf(1.f + 2.f*c*xy + c*c*x2*y2, EPSF);
  float num2 = fmaxf(Af*Af*x2 + 2.f*Af*Bf*xy + Bf*Bf*y2, 0.f);
  float rn = sqrtf(num2)/den;
  float fp = (rn >= 1.f) ? (ONE_M_EPS/fmaxf(rn,EPSF)) : 1.f;
  float xan = (rn >= 1.f) ? ONE_M_EPS : rn;
  float g = fp/den;
  float xa = (Af*xv.x + Bf*ya)*g;
  float xb = (Af*xv.y + Bf*yb)*g;
  float xc = (Af*xv.z + Bf*yc)*g;
  float xd = (Af*xv.w + Bf*yd)*g;
  float4 xo; xo.x=xa; xo.y=xb; xo.z=xc; xo.w=xd;
  ((float4*)(xatt + (size_t)r*1024))[t] = xo;
  float at = (rn >= 1.f) ? ATANH_1ME : atanh_c(xan);
  float fl = (xan < EPSF) ? 0.f : at / sc / fmaxf(xan, EPSF);
  float ux = xa*fl, uy = xb*fl, uz = xc*fl, uw = xd*fl;
  float2 s12 = blkSum2(ux+uy+uz+uw, ux*ux+uy*uy+uz*uz+uw*uw, tmp);
  float mu = s12.x*(1.f/1024.f);
  float var = s12.y*(1.f/1024.f) - mu*mu;
  float inv = rsqrtf(var + 1e-6f);
  float4 sv = ((const float4*)lns)[t];
  float4 bv = ((const float4*)lnb)[t];
  float ta = (ux-mu)*inv*sv.x + bv.x;
  float tb = (uy-mu)*inv*sv.y + bv.y;
  float tc = (uz-mu)*inv*sv.z + bv.z;
  float td = (uw-mu)*inv*sv.w + bv.w;
  float tn2 = blkSum(ta*ta+tb*tb+tc*tc+td*td, tmp);
  float f = roundtrip_factor(tn2, sc);
  ushort4 o; o.x=f2bf(ta*f); o.y=f2bf(tb*f); o.z=f2bf(tc*f); o.w=f2bf(td*f);
  ((ushort4*)(tout + (size_t)r*1024))[t] = o;
}

// ---------------- final: out = mobius_add(x_att, expmap0(tf)) ----------------
__global__ __launch_bounds__(256) void k_final(const float* __restrict__ xatt,
    const float* __restrict__ tf, const float* __restrict__ cg, float* __restrict__ out){
  __shared__ float tmp[8];
  int r = blockIdx.x, t = threadIdx.x;
  float c = cg[0], sc = fmaxf(sqrtf(c), EPSF);
  float4 fa = ((const float4*)(tf + (size_t)r*1024))[t];
  float4 fb = ((const float4*)(tf + 1024*1024 + (size_t)r*1024))[t];
  float4 fc = ((const float4*)(tf + 2*1024*1024 + (size_t)r*1024))[t];
  float4 fd = ((const float4*)(tf + 3*1024*1024 + (size_t)r*1024))[t];
  float4 fv; fv.x=(fa.x+fb.x)+(fc.x+fd.x); fv.y=(fa.y+fb.y)+(fc.y+fd.y);
  fv.z=(fa.z+fb.z)+(fc.z+fd.z); fv.w=(fa.w+fb.w)+(fc.w+fd.w);
  float4 xv = ((const float4*)(xatt + (size_t)r*1024))[t];
  float fn2 = blkSum(fv.x*fv.x+fv.y*fv.y+fv.z*fv.z+fv.w*fv.w, tmp);
  float y2; float fy = expmap_factor(fn2, sc, y2);
  float ya = fv.x*fy, yb = fv.y*fy, yc = fv.z*fy, yd = fv.w*fy;
  float2 s = blkSum2(xv.x*xv.x+xv.y*xv.y+xv.z*xv.z+xv.w*xv.w,
                     xv.x*ya+xv.y*yb+xv.z*yc+xv.w*yd, tmp);
  float x2 = s.x, xy = s.y;
  float Af = 1.f + 2.f*c*xy + c*y2;
  float Bf = 1.f - c*x2;
  float den = fmaxf(1.f + 2.f*c*xy + c*c*x2*y2, EPSF);
  float num2 = fmaxf(Af*Af*x2 + 2.f*Af*Bf*xy + Bf*Bf*y2, 0.f);
  float rn = sqrtf(num2)/den;
  float fp = (rn >= 1.f) ? (ONE_M_EPS/fmaxf(rn,EPSF)) : 1.f;
  float g = fp/den;
  float4 o;
  o.x = (Af*xv.x + Bf*ya)*g;
  o.y = (Af*xv.y + Bf*yb)*g;
  o.z = (Af*xv.z + Bf*yc)*g;
  o.w = (Af*xv.w + Bf*yd)*g;
  ((float4*)(out + (size_t)r*1024))[t] = o;
}

extern "C" void kernel_launch(void* const* d_in, const int* in_sizes, int n_in,
                              void* d_out, int out_size, void* d_ws, size_t ws_size,
                              hipStream_t stream){
  (void)in_sizes; (void)n_in; (void)out_size; (void)ws_size;
  const float* x     = (const float*)d_in[0];
  const float* cg    = (const float*)d_in[1];
  const float* qkv_w = (const float*)d_in[2];
  const float* qkv_b = (const float*)d_in[3];
  const float* out_w = (const float*)d_in[4];
  const float* out_b = (const float*)d_in[5];
  const float* ffn_w1= (const float*)d_in[6];
  const float* ffn_b1= (const float*)d_in[7];
  const float* ffn_w2= (const float*)d_in[8];
  const float* ffn_b2= (const float*)d_in[9];
  const float* ln1s  = (const float*)d_in[10];
  const float* ln1b  = (const float*)d_in[11];
  const float* ln2s  = (const float*)d_in[12];
  const float* ln2b  = (const float*)d_in[13];
  const float* clog  = (const float*)d_in[14];
  const float* geo   = (const float*)d_in[15];

  char* p = (char*)d_ws;
  auto take = [&](size_t n){ char* r = p; p += (n + 255) & ~(size_t)255; return r; };
  ushort* wt_qkv  = (ushort*)take((size_t)3072*1024*2);
  ushort* wt_out  = (ushort*)take((size_t)1024*1024*2);
  ushort* wt_ffn1 = (ushort*)take((size_t)4096*1024*2);
  ushort* wt_ffn2 = (ushort*)take((size_t)1024*4096*2);
  float*  bufA    = (float*)take((size_t)2*1024*3072*4);  // qkv 2 partials ; later gelu bf16
  ushort* bufB    = (ushort*)take((size_t)1024*1024*2);   // x_tan ; later ao
  float*  bufC    = (float*)take((size_t)4*1024*1024*4);  // split-K partials (4x 4MB)
  float*  xatt    = (float*)take((size_t)1024*1024*4);
  ushort* tbuf    = (ushort*)take((size_t)1024*1024*2);

  k_pre<<<13312, 256, 0, stream>>>(qkv_w, out_w, ffn_w1, ffn_w2, x, cg, ln1s, ln1b,
                                   wt_qkv, wt_out, wt_ffn1, wt_ffn2, bufB);
  // qkv: split-K2, f32 partials (2 x 12MB)
  k_gemm<3><<<dim3(48,8,2), 256, 0, stream>>>(bufB, wt_qkv, qkv_b, (void*)bufA, 1024, 3072, 1024, 512);
  k_attn4<<<dim3(16,8,4), 128, 0, stream>>>(bufA, clog, geo, bufB);
  // out-proj: split-K4
  k_gemm<3><<<dim3(16,8,4), 256, 0, stream>>>(bufB, wt_out, out_b, (void*)bufC, 1024, 1024, 1024, 256);
  k_postattn<<<1024, 256, 0, stream>>>(x, bufC, cg, ln2s, ln2b, xatt, tbuf);
  // ffn1: gelu epilogue, full K
  k_gemm<2><<<dim3(64,8,1), 256, 0, stream>>>(tbuf, wt_ffn1, ffn_b1, (void*)bufA, 1024, 4096, 1024, 1024);
  // ffn2: split-K4
  k_gemm<3><<<dim3(16,8,4), 256, 0, stream>>>((const ushort*)bufA, wt_ffn2, ffn_b2, (void*)bufC, 1024, 1024, 4096, 1024);
  k_final<<<1024, 256, 0, stream>>>(xatt, bufC, cg, (float*)d_out);
}

// Round 7
// 116.628 us; speedup vs baseline: 4.6561x; 1.0579x over previous
//
#include <hip/hip_runtime.h>

typedef unsigned int uint;
typedef unsigned short ushort;
typedef __attribute__((ext_vector_type(8))) short bf16x8;
typedef __attribute__((ext_vector_type(4))) float f32x4;

#define EPSF 1e-7f
#define ONE_M_EPS 0.99999988079071044921875f /* f32 nearest to 1-1e-7 */
#define ATANH_1ME 8.4056213f                 /* atanh(1-1e-7), f64-accurate */
#define Y2_CLIP 0.99999982f                  /* (1-1e-7)^2 */

__device__ __forceinline__ ushort f2bf(float f){
  union{float f;uint u;}x; x.f=f; uint u=x.u;
  return (ushort)((u + 0x7fffu + ((u>>16)&1u)) >> 16);
}
__device__ __forceinline__ float bf2f(ushort u){
  union{uint u;float f;}x; x.u = ((uint)u)<<16; return x.f;
}
__device__ __forceinline__ float atanh_c(float a){
  a = fminf(a, ONE_M_EPS);
  return 0.5f*__logf((1.f+a)/(1.f-a));
}
__device__ __forceinline__ float gelu_t(float v){
  return 0.5f*v*(1.f + tanhf(0.7978845608f*(v + 0.044715f*v*v*v)));
}

__device__ __forceinline__ float expmap_factor(float n2, float sc, float& r2){
  float n = sqrtf(n2);
  if (n < EPSF) { r2 = 0.f; return 0.f; }
  float mag = tanhf(sc*n)/sc;
  float f = mag/n;
  if (mag >= 1.f) { f *= ONE_M_EPS/mag; r2 = Y2_CLIP; }
  else r2 = mag*mag;
  return f;
}
__device__ __forceinline__ float roundtrip_factor(float tn2, float sc){
  float tn = sqrtf(tn2);
  if (tn < EPSF) return 0.f;
  float mag = tanhf(sc*tn)/sc;
  if (mag >= 1.f) {
    return ATANH_1ME / (sc * tn);
  } else {
    if (mag < EPSF) return 0.f;
    return (mag/tn) * (atanh_c(mag) / (sc * mag));
  }
}

// freqs[i] = 10000^(-i/32) = 10^(-i/8), f64-derived literals
__device__ __constant__ float FREQS[32] = {
  1.0f, 0.7498942093324559f, 0.5623413251903491f, 0.4216965034285822f,
  0.31622776601683794f, 0.23713737056616552f, 0.1778279410038923f, 0.13335214321633242f,
  0.1f, 0.07498942093324558f, 0.05623413251903491f, 0.04216965034285822f,
  0.03162277660168379f, 0.023713737056616554f, 0.01778279410038923f, 0.013335214321633242f,
  0.01f, 0.007498942093324559f, 0.005623413251903491f, 0.004216965034285822f,
  0.0031622776601683794f, 0.0023713737056616554f, 0.0017782794100389228f, 0.0013335214321633241f,
  0.001f, 0.0007498942093324558f, 0.0005623413251903491f, 0.0004216965034285822f,
  0.00031622776601683794f, 0.00023713737056616553f, 0.00017782794100389227f, 0.00013335214321633243f
};

__device__ __forceinline__ void rope64(float* v, int row){
  #pragma unroll
  for (int i=0;i<32;i++){
    float sn, cn; __sincosf((float)row * FREQS[i], &sn, &cn);
    float a = v[i], b = v[i+32];
    v[i] = a*cn - b*sn;
    v[i+32] = a*sn + b*cn;
  }
}

// ---------------- block reductions (256 threads) ----------------
__device__ __forceinline__ float blkSum(float v, float* tmp){
  #pragma unroll
  for (int o=32;o>0;o>>=1) v += __shfl_xor(v, o, 64);
  int w = threadIdx.x >> 6;
  if ((threadIdx.x & 63) == 0) tmp[w] = v;
  __syncthreads();
  v = tmp[0]+tmp[1]+tmp[2]+tmp[3];
  __syncthreads();
  return v;
}
__device__ __forceinline__ float2 blkSum2(float a, float b, float* tmp){
  #pragma unroll
  for (int o=32;o>0;o>>=1){ a += __shfl_xor(a, o, 64); b += __shfl_xor(b, o, 64); }
  int w = threadIdx.x >> 6;
  if ((threadIdx.x & 63) == 0){ tmp[w] = a; tmp[4+w] = b; }
  __syncthreads();
  float2 r; r.x = tmp[0]+tmp[1]+tmp[2]+tmp[3]; r.y = tmp[4]+tmp[5]+tmp[6]+tmp[7];
  __syncthreads();
  return r;
}

// ---------------- fused front-end: 4 weight transposes + prep ----------------
__global__ __launch_bounds__(256) void k_pre(const float* __restrict__ qkv_w,
    const float* __restrict__ out_w, const float* __restrict__ ffn_w1,
    const float* __restrict__ ffn_w2, const float* __restrict__ x,
    const float* __restrict__ cg, const float* __restrict__ lns, const float* __restrict__ lnb,
    ushort* __restrict__ wq, ushort* __restrict__ wo,
    ushort* __restrict__ w1, ushort* __restrict__ w2, ushort* __restrict__ xtan){
  __shared__ float s[32][33];
  int b = blockIdx.x;
  if (b < 12288){
    const float* W; ushort* WT; int K, N;
    if (b < 3072){ W=qkv_w; WT=wq; K=1024; N=3072; }
    else if (b < 4096){ b-=3072; W=out_w; WT=wo; K=1024; N=1024; }
    else if (b < 8192){ b-=4096; W=ffn_w1; WT=w1; K=1024; N=4096; }
    else { b-=8192; W=ffn_w2; WT=w2; K=4096; N=1024; }
    int nbn = N >> 5;
    int n0 = (b % nbn)*32, k0 = (b / nbn)*32;
    int tx = threadIdx.x & 31, ty = threadIdx.x >> 5; // (32,8)
    #pragma unroll
    for (int i=0;i<4;i++)
      s[ty+8*i][tx] = W[(size_t)(k0+ty+8*i)*N + n0+tx];
    __syncthreads();
    #pragma unroll
    for (int i=0;i<4;i++)
      WT[(size_t)(n0+ty+8*i)*K + k0+tx] = f2bf(s[tx][ty+8*i]);
  } else {
    float* tmp = &s[0][0];
    int r = b - 12288, t = threadIdx.x;
    float c = cg[0];
    float sc = fmaxf(sqrtf(c), EPSF);
    float4 xv = ((const float4*)(x + (size_t)r*1024))[t];
    float n2 = blkSum(xv.x*xv.x + xv.y*xv.y + xv.z*xv.z + xv.w*xv.w, tmp);
    float n = sqrtf(n2);
    float f1 = (n < EPSF) ? 0.f : (atanh_c(n) / sc / n);
    float ux = xv.x*f1, uy = xv.y*f1, uz = xv.z*f1, uw = xv.w*f1;
    float2 s12 = blkSum2(ux+uy+uz+uw, ux*ux+uy*uy+uz*uz+uw*uw, tmp);
    float mu = s12.x*(1.f/1024.f);
    float var = s12.y*(1.f/1024.f) - mu*mu;
    float inv = rsqrtf(var + 1e-6f);
    float4 sv = ((const float4*)lns)[t];
    float4 bv = ((const float4*)lnb)[t];
    float ta = (ux-mu)*inv*sv.x + bv.x;
    float tb = (uy-mu)*inv*sv.y + bv.y;
    float tc = (uz-mu)*inv*sv.z + bv.z;
    float td = (uw-mu)*inv*sv.w + bv.w;
    float tn2 = blkSum(ta*ta+tb*tb+tc*tc+td*td, tmp);
    float f = roundtrip_factor(tn2, sc);
    ushort4 o; o.x=f2bf(ta*f); o.y=f2bf(tb*f); o.z=f2bf(tc*f); o.w=f2bf(td*f);
    ((ushort4*)(xtan + (size_t)r*1024))[t] = o;
  }
}

// ---------------- GEMM: C[M][N] = A[M][K](bf16) * Bt[N][K](bf16)^T + bias ----------------
// 2-phase pipelined global_load_lds double-buffer, XOR-swizzled LDS, bijective XCD remap.
// BM=128, BN=64, 4 waves (each 32x64).
// EPI: 2 = gelu + bf16 out (z==0), 3 = f32 split-K partial at z*M*N (bias only z==0)
template<int EPI>
__global__ __launch_bounds__(256) void k_gemm(const ushort* __restrict__ A,
    const ushort* __restrict__ Bt, const float* __restrict__ bias,
    void* __restrict__ C, int M, int N, int Kstride, int Kchunk){
  constexpr int MF = 2, NF = 4;
  __shared__ ushort As[2][128*64];
  __shared__ ushort Bs[2][64*64];
  const int tid = threadIdx.x;
  const int lane = tid & 63;
  const int wid = tid >> 6;
  const int ro = wid * 32, co = 0;
  const int l15 = lane & 15, hi = lane >> 4;
  const int nwg = gridDim.x * gridDim.y;
  const int lin = blockIdx.y * gridDim.x + blockIdx.x;
  const int qq = nwg >> 3, rr = nwg & 7;
  const int xcd = lin & 7, ii = lin >> 3;
  const int swz = (xcd < rr) ? (xcd*(qq+1) + ii) : (rr*(qq+1) + (xcd-rr)*qq + ii);
  const int m0 = (swz % gridDim.y) * 128;
  const int n0 = (swz / gridDim.y) * 64;
  const int z = blockIdx.z;
  const int kbase = z * Kchunk;
  const int swr = (l15 & 7) << 3;

  f32x4 acc[MF][NF];
  #pragma unroll
  for (int i=0;i<MF;i++)
    #pragma unroll
    for (int j=0;j<NF;j++) acc[i][j] = (f32x4){0.f,0.f,0.f,0.f};

  auto stage = [&](int buf, int koff){
    #pragma unroll
    for (int r2=0;r2<4;r2++){
      int idx = r2*256 + tid;
      int row = idx >> 3, cc = idx & 7;
      int off = koff + ((cc ^ (row & 7)) << 3);
      const ushort* ga = A + (size_t)(m0+row)*Kstride + off;
      int lo = (r2*256 + (tid & 192)) * 8;
      __builtin_amdgcn_global_load_lds((const __attribute__((address_space(1))) uint*)ga,
          (__attribute__((address_space(3))) uint*)&As[buf][lo], 16, 0, 0);
    }
    #pragma unroll
    for (int r2=0;r2<2;r2++){
      int idx = r2*256 + tid;
      int row = idx >> 3, cc = idx & 7;
      int off = koff + ((cc ^ (row & 7)) << 3);
      const ushort* gb = Bt + (size_t)(n0+row)*Kstride + off;
      int lo = (r2*256 + (tid & 192)) * 8;
      __builtin_amdgcn_global_load_lds((const __attribute__((address_space(1))) uint*)gb,
          (__attribute__((address_space(3))) uint*)&Bs[buf][lo], 16, 0, 0);
    }
  };
  auto compute = [&](int buf){
    #pragma unroll
    for (int ks=0;ks<2;ks++){
      bf16x8 af[MF], bfv[NF];
      int cb = (ks*32 + hi*8) ^ swr;
      #pragma unroll
      for (int m2=0;m2<MF;m2++) af[m2]  = *(const bf16x8*)&As[buf][(ro+m2*16+l15)*64 + cb];
      #pragma unroll
      for (int n2=0;n2<NF;n2++) bfv[n2] = *(const bf16x8*)&Bs[buf][(co+n2*16+l15)*64 + cb];
      #pragma unroll
      for (int m2=0;m2<MF;m2++)
        #pragma unroll
        for (int n2=0;n2<NF;n2++)
          acc[m2][n2] = __builtin_amdgcn_mfma_f32_16x16x32_bf16(af[m2], bfv[n2], acc[m2][n2], 0, 0, 0);
    }
  };

  const int nt = Kchunk >> 6;
  stage(0, kbase);
  __syncthreads();
  int cur = 0;
  for (int t = 1; t < nt; ++t){
    stage(cur ^ 1, kbase + t*64);
    compute(cur);
    __syncthreads();
    cur ^= 1;
  }
  compute(cur);

  #pragma unroll
  for (int m=0;m<MF;m++){
    #pragma unroll
    for (int n=0;n<NF;n++){
      int gc = n0 + co + n*16 + l15;
      float bb = (EPI == 3) ? (z == 0 ? bias[gc] : 0.f) : bias[gc];
      #pragma unroll
      for (int i=0;i<4;i++){
        int gr = m0 + ro + m*16 + hi*4 + i;
        float v = acc[m][n][i] + bb;
        if (EPI == 2) v = gelu_t(v);
        if (EPI == 2) ((ushort*)C)[(size_t)gr*N + gc] = f2bf(v);
        else ((float*)C)[(size_t)z*M*N + (size_t)gr*N + gc] = v;
      }
    }
  }
}

// ---------------- MFMA hyperbolic attention v5 ----------------
// grid (H=16, Be=8, qs=2), 256 threads (4 waves). Block: 64 q-rows x 128 kv.
// Disjoint staging roles: tid<128 K row; tid in [128,192) 2 V rows (hi only);
// tid in [192,256) 1 Q row. QK^T 3-pass hi/lo MFMA; PV 2-pass (Ph+Pl)*Vh.
__global__ __launch_bounds__(256) void k_attn5(const float* __restrict__ qkv,
    const float* __restrict__ c_logits, const float* __restrict__ geo,
    ushort* __restrict__ ao){
  constexpr size_t PSTRIDE = (size_t)1024*3072;
  __shared__ ushort Kh[128*64], Kl[128*64];   // after QK^T: Ph/Pl overlay [64][128]
  __shared__ ushort Vth[64*128];              // V^T [d][kv], hi only
  __shared__ ushort Qh[64*64], Ql[64*64];
  __shared__ float k2s[128], q2s[64];
  const int h = blockIdx.x, be = blockIdx.y, qs = blockIdx.z;
  const int tid = threadIdx.x;
  const float cl = c_logits[h];
  const float ch = (cl > 20.f) ? cl : log1pf(__expf(cl));
  const float sc = fmaxf(sqrtf(ch), EPSF);
  const float gs = geo[h];

  if (tid < 128){
    // ---- K row tid: rope + expmap + hi/lo, XOR-swizzled 16B chunks ----
    int kv = tid;
    const float4* pa = (const float4*)(qkv + (size_t)(be*128+kv)*3072 + 1024 + h*64);
    const float4* pb = (const float4*)(qkv + PSTRIDE + (size_t)(be*128+kv)*3072 + 1024 + h*64);
    float v[64];
    #pragma unroll
    for (int c=0;c<16;c++){
      float4 ta = pa[c], tb = pb[c];
      v[4*c]=ta.x+tb.x; v[4*c+1]=ta.y+tb.y; v[4*c+2]=ta.z+tb.z; v[4*c+3]=ta.w+tb.w;
    }
    rope64(v, kv);
    float n2 = 0.f;
    #pragma unroll
    for (int e=0;e<64;e++) n2 += v[e]*v[e];
    float r2; float f = expmap_factor(n2, sc, r2);
    k2s[kv] = r2;
    #pragma unroll
    for (int cch=0; cch<8; cch++){
      uint hw[4], lw[4];
      #pragma unroll
      for (int w2=0; w2<4; w2++){
        float a0 = v[cch*8 + w2*2] * f, a1 = v[cch*8 + w2*2 + 1] * f;
        ushort h0 = f2bf(a0); ushort l0 = f2bf(a0 - bf2f(h0));
        ushort h1 = f2bf(a1); ushort l1 = f2bf(a1 - bf2f(h1));
        hw[w2] = (uint)h0 | ((uint)h1<<16);
        lw[w2] = (uint)l0 | ((uint)l1<<16);
      }
      uint4 uh; uh.x=hw[0]; uh.y=hw[1]; uh.z=hw[2]; uh.w=hw[3];
      uint4 ul; ul.x=lw[0]; ul.y=lw[1]; ul.z=lw[2]; ul.w=lw[3];
      int idx = kv*64 + ((cch ^ (kv&7))<<3);
      *(uint4*)&Kh[idx] = uh;
      *(uint4*)&Kl[idx] = ul;
    }
  } else if (tid < 192){
    // ---- V rows tid-128 and tid-64: transpose into [d][kv], hi only ----
    #pragma unroll
    for (int rr2=0; rr2<2; rr2++){
      int kv = (tid - 128) + rr2*64;
      const float4* pa = (const float4*)(qkv + (size_t)(be*128+kv)*3072 + 2048 + h*64);
      const float4* pb = (const float4*)(qkv + PSTRIDE + (size_t)(be*128+kv)*3072 + 2048 + h*64);
      float v[64];
      #pragma unroll
      for (int c=0;c<16;c++){
        float4 ta = pa[c], tb = pb[c];
        v[4*c]=ta.x+tb.x; v[4*c+1]=ta.y+tb.y; v[4*c+2]=ta.z+tb.z; v[4*c+3]=ta.w+tb.w;
      }
      #pragma unroll
      for (int d=0; d<64; d++){
        int idx = d*128 + (((kv>>3) ^ (d&7))<<3) + (kv&7);
        Vth[idx] = f2bf(v[d]);
      }
    }
  } else {
    // ---- Q row qs*64 + (tid-192) ----
    int ql = tid - 192;
    int qrow = qs*64 + ql;
    const float4* pa = (const float4*)(qkv + (size_t)(be*128+qrow)*3072 + h*64);
    const float4* pb = (const float4*)(qkv + PSTRIDE + (size_t)(be*128+qrow)*3072 + h*64);
    float v[64];
    #pragma unroll
    for (int c=0;c<16;c++){
      float4 ta = pa[c], tb = pb[c];
      v[4*c]=ta.x+tb.x; v[4*c+1]=ta.y+tb.y; v[4*c+2]=ta.z+tb.z; v[4*c+3]=ta.w+tb.w;
    }
    rope64(v, qrow);
    float n2 = 0.f;
    #pragma unroll
    for (int e=0;e<64;e++) n2 += v[e]*v[e];
    float r2; float f = expmap_factor(n2, sc, r2);
    q2s[ql] = r2;
    #pragma unroll
    for (int cch=0; cch<8; cch++){
      uint hw[4], lw[4];
      #pragma unroll
      for (int w2=0; w2<4; w2++){
        float a0 = v[cch*8 + w2*2] * f, a1 = v[cch*8 + w2*2 + 1] * f;
        ushort h0 = f2bf(a0); ushort l0 = f2bf(a0 - bf2f(h0));
        ushort h1 = f2bf(a1); ushort l1 = f2bf(a1 - bf2f(h1));
        hw[w2] = (uint)h0 | ((uint)h1<<16);
        lw[w2] = (uint)l0 | ((uint)l1<<16);
      }
      uint4 uh; uh.x=hw[0]; uh.y=hw[1]; uh.z=hw[2]; uh.w=hw[3];
      uint4 ul; ul.x=lw[0]; ul.y=lw[1]; ul.z=lw[2]; ul.w=lw[3];
      int idx = ql*64 + ((cch ^ (ql&7))<<3);
      *(uint4*)&Qh[idx] = uh;
      *(uint4*)&Ql[idx] = ul;
    }
  }
  __syncthreads();

  // ---- QK^T: wave w handles q local rows [w*16, w*16+16) x 128 kv; 3-pass hi/lo ----
  const int lane = tid & 63, w = tid >> 6;
  const int l15 = lane & 15, hi4 = lane >> 4;
  f32x4 acc[8];
  #pragma unroll
  for (int nf=0;nf<8;nf++) acc[nf] = (f32x4){0.f,0.f,0.f,0.f};
  #pragma unroll
  for (int ks=0; ks<2; ks++){
    int qrowL = w*16 + l15;
    int qidx = qrowL*64 + (((ks*4 + hi4) ^ (qrowL&7))<<3);
    bf16x8 qh = *(const bf16x8*)&Qh[qidx];
    bf16x8 ql2 = *(const bf16x8*)&Ql[qidx];
    #pragma unroll
    for (int nf=0; nf<8; nf++){
      int krow = nf*16 + l15;
      int kidx = krow*64 + (((ks*4 + hi4) ^ (krow&7))<<3);
      bf16x8 kh = *(const bf16x8*)&Kh[kidx];
      bf16x8 kl2 = *(const bf16x8*)&Kl[kidx];
      acc[nf] = __builtin_amdgcn_mfma_f32_16x16x32_bf16(qh, kh, acc[nf], 0, 0, 0);
      acc[nf] = __builtin_amdgcn_mfma_f32_16x16x32_bf16(qh, kl2, acc[nf], 0, 0, 0);
      acc[nf] = __builtin_amdgcn_mfma_f32_16x16x32_bf16(ql2, kh, acc[nf], 0, 0, 0);
    }
  }
  __syncthreads();   // all K reads complete -> P may overlay Kh/Kl

  // ---- distance + softmax in registers (C-layout: row=(lane>>4)*4+i, col=lane&15) ----
  float q2v[4], Bfv[4];
  #pragma unroll
  for (int i=0;i<4;i++){ q2v[i] = q2s[w*16 + hi4*4 + i]; Bfv[i] = 1.f - ch*q2v[i]; }
  const float e2 = 2.f*ch;
  #pragma unroll
  for (int nf=0; nf<8; nf++){
    float k2 = k2s[nf*16 + l15];
    #pragma unroll
    for (int i=0;i<4;i++){
      float xy = acc[nf][i];
      float Af = 1.f + ch*k2 - e2*xy;
      float den = fmaxf(Af - ch*k2*Bfv[i], EPSF);
      float num2 = fmaxf(Af*(Af*q2v[i] - 2.f*Bfv[i]*xy) + Bfv[i]*Bfv[i]*k2, 0.f);
      float rn = sqrtf(num2)/den;
      rn = (rn >= 1.f) ? ONE_M_EPS : rn;
      float arg = fminf(sc*rn, ONE_M_EPS);
      float dd = __logf((1.f+arg)/(1.f-arg)) / sc;
      acc[nf][i] = -gs*dd;
    }
  }
  #pragma unroll
  for (int i=0;i<4;i++){
    float m = acc[0][i];
    #pragma unroll
    for (int nf=1;nf<8;nf++) m = fmaxf(m, acc[nf][i]);
    #pragma unroll
    for (int o=1;o<16;o<<=1) m = fmaxf(m, __shfl_xor(m, o));
    float l = 0.f;
    #pragma unroll
    for (int nf=0;nf<8;nf++){ float pp = __expf(acc[nf][i]-m); acc[nf][i] = pp; l += pp; }
    #pragma unroll
    for (int o=1;o<16;o<<=1) l += __shfl_xor(l, o);
    float inv = 1.f/l;
    #pragma unroll
    for (int nf=0;nf<8;nf++){
      float p = acc[nf][i]*inv;
      ushort ph = f2bf(p);
      ushort pl = f2bf(p - bf2f(ph));
      int row = w*16 + hi4*4 + i, col = nf*16 + l15;
      int idx = row*128 + (((col>>3) ^ (row&7))<<3) + (col&7);
      Kh[idx] = ph; Kl[idx] = pl;
    }
  }
  __syncthreads();

  // ---- PV: ao[64][64] via MFMA, 2-pass (Ph+Pl)*Vh ----
  f32x4 acc2[4];
  #pragma unroll
  for (int nf=0;nf<4;nf++) acc2[nf] = (f32x4){0.f,0.f,0.f,0.f};
  #pragma unroll
  for (int ks=0; ks<4; ks++){
    int prow = w*16 + l15;
    int pidx = prow*128 + (((ks*4 + hi4) ^ (prow&7))<<3);
    bf16x8 ph = *(const bf16x8*)&Kh[pidx];
    bf16x8 pl = *(const bf16x8*)&Kl[pidx];
    #pragma unroll
    for (int nf=0; nf<4; nf++){
      int vrow = nf*16 + l15;
      int vidx = vrow*128 + (((ks*4 + hi4) ^ (vrow&7))<<3);
      bf16x8 vh = *(const bf16x8*)&Vth[vidx];
      acc2[nf] = __builtin_amdgcn_mfma_f32_16x16x32_bf16(ph, vh, acc2[nf], 0, 0, 0);
      acc2[nf] = __builtin_amdgcn_mfma_f32_16x16x32_bf16(pl, vh, acc2[nf], 0, 0, 0);
    }
  }
  #pragma unroll
  for (int nf=0; nf<4; nf++)
    #pragma unroll
    for (int i=0;i<4;i++){
      int row = qs*64 + w*16 + hi4*4 + i;
      int col = nf*16 + l15;
      ao[(size_t)(be*128 + row)*1024 + h*64 + col] = f2bf(acc2[nf][i]);
    }
}

// ---------------- post-attention: mobius residual + LN2 roundtrip -> t (bf16) ----------------
__global__ __launch_bounds__(256) void k_postattn(const float* __restrict__ x,
    const float* __restrict__ proj, const float* __restrict__ cg,
    const float* __restrict__ lns, const float* __restrict__ lnb,
    float* __restrict__ xatt, ushort* __restrict__ tout){
  __shared__ float tmp[8];
  int r = blockIdx.x, t = threadIdx.x;
  float c = cg[0], sc = fmaxf(sqrtf(c), EPSF);
  float4 pa = ((const float4*)(proj + (size_t)r*1024))[t];
  float4 pb = ((const float4*)(proj + 1024*1024 + (size_t)r*1024))[t];
  float4 pc = ((const float4*)(proj + 2*1024*1024 + (size_t)r*1024))[t];
  float4 pd = ((const float4*)(proj + 3*1024*1024 + (size_t)r*1024))[t];
  float4 pv; pv.x=(pa.x+pb.x)+(pc.x+pd.x); pv.y=(pa.y+pb.y)+(pc.y+pd.y);
  pv.z=(pa.z+pb.z)+(pc.z+pd.z); pv.w=(pa.w+pb.w)+(pc.w+pd.w);
  float4 xv = ((const float4*)(x + (size_t)r*1024))[t];
  float pn2 = blkSum(pv.x*pv.x+pv.y*pv.y+pv.z*pv.z+pv.w*pv.w, tmp);
  float y2; float fy = expmap_factor(pn2, sc, y2);
  float ya = pv.x*fy, yb = pv.y*fy, yc = pv.z*fy, yd = pv.w*fy;
  float2 s = blkSum2(xv.x*xv.x+xv.y*xv.y+xv.z*xv.z+xv.w*xv.w,
                     xv.x*ya+xv.y*yb+xv.z*yc+xv.w*yd, tmp);
  float x2 = s.x, xy = s.y;
  float Af = 1.f + 2.f*c*xy + c*y2;
  float Bf = 1.f - c*x2;
  float den = fmaxf(1.f + 2.f*c*xy + c*c*x2*y2, EPSF);
  float num2 = fmaxf(Af*Af*x2 + 2.f*Af*Bf*xy + Bf*Bf*y2, 0.f);
  float rn = sqrtf(num2)/den;
  float fp = (rn >= 1.f) ? (ONE_M_EPS/fmaxf(rn,EPSF)) : 1.f;
  float xan = (rn >= 1.f) ? ONE_M_EPS : rn;
  float g = fp/den;
  float xa = (Af*xv.x + Bf*ya)*g;
  float xb = (Af*xv.y + Bf*yb)*g;
  float xc = (Af*xv.z + Bf*yc)*g;
  float xd = (Af*xv.w + Bf*yd)*g;
  float4 xo; xo.x=xa; xo.y=xb; xo.z=xc; xo.w=xd;
  ((float4*)(xatt + (size_t)r*1024))[t] = xo;
  float at = (rn >= 1.f) ? ATANH_1ME : atanh_c(xan);
  float fl = (xan < EPSF) ? 0.f : at / sc / fmaxf(xan, EPSF);
  float ux = xa*fl, uy = xb*fl, uz = xc*fl, uw = xd*fl;
  float2 s12 = blkSum2(ux+uy+uz+uw, ux*ux+uy*uy+uz*uz+uw*uw, tmp);
  float mu = s12.x*(1.f/1024.f);
  float var = s12.y*(1.f/1024.f) - mu*mu;
  float inv = rsqrtf(var + 1e-6f);
  float4 sv = ((const float4*)lns)[t];
  float4 bv = ((const float4*)lnb)[t];
  float ta = (ux-mu)*inv*sv.x + bv.x;
  float tb = (uy-mu)*inv*sv.y + bv.y;
  float tc = (uz-mu)*inv*sv.z + bv.z;
  float td = (uw-mu)*inv*sv.w + bv.w;
  float tn2 = blkSum(ta*ta+tb*tb+tc*tc+td*td, tmp);
  float f = roundtrip_factor(tn2, sc);
  ushort4 o; o.x=f2bf(ta*f); o.y=f2bf(tb*f); o.z=f2bf(tc*f); o.w=f2bf(td*f);
  ((ushort4*)(tout + (size_t)r*1024))[t] = o;
}

// ---------------- final: out = mobius_add(x_att, expmap0(tf)) ----------------
__global__ __launch_bounds__(256) void k_final(const float* __restrict__ xatt,
    const float* __restrict__ tf, const float* __restrict__ cg, float* __restrict__ out){
  __shared__ float tmp[8];
  int r = blockIdx.x, t = threadIdx.x;
  float c = cg[0], sc = fmaxf(sqrtf(c), EPSF);
  float4 fa = ((const float4*)(tf + (size_t)r*1024))[t];
  float4 fb = ((const float4*)(tf + 1024*1024 + (size_t)r*1024))[t];
  float4 fc = ((const float4*)(tf + 2*1024*1024 + (size_t)r*1024))[t];
  float4 fd = ((const float4*)(tf + 3*1024*1024 + (size_t)r*1024))[t];
  float4 fv; fv.x=(fa.x+fb.x)+(fc.x+fd.x); fv.y=(fa.y+fb.y)+(fc.y+fd.y);
  fv.z=(fa.z+fb.z)+(fc.z+fd.z); fv.w=(fa.w+fb.w)+(fc.w+fd.w);
  float4 xv = ((const float4*)(xatt + (size_t)r*1024))[t];
  float fn2 = blkSum(fv.x*fv.x+fv.y*fv.y+fv.z*fv.z+fv.w*fv.w, tmp);
  float y2; float fy = expmap_factor(fn2, sc, y2);
  float ya = fv.x*fy, yb = fv.y*fy, yc = fv.z*fy, yd = fv.w*fy;
  float2 s = blkSum2(xv.x*xv.x+xv.y*xv.y+xv.z*xv.z+xv.w*xv.w,
                     xv.x*ya+xv.y*yb+xv.z*yc+xv.w*yd, tmp);
  float x2 = s.x, xy = s.y;
  float Af = 1.f + 2.f*c*xy + c*y2;
  float Bf = 1.f - c*x2;
  float den = fmaxf(1.f + 2.f*c*xy + c*c*x2*y2, EPSF);
  float num2 = fmaxf(Af*Af*x2 + 2.f*Af*Bf*xy + Bf*Bf*y2, 0.f);
  float rn = sqrtf(num2)/den;
  float fp = (rn >= 1.f) ? (ONE_M_EPS/fmaxf(rn,EPSF)) : 1.f;
  float g = fp/den;
  float4 o;
  o.x = (Af*xv.x + Bf*ya)*g;
  o.y = (Af*xv.y + Bf*yb)*g;
  o.z = (Af*xv.z + Bf*yc)*g;
  o.w = (Af*xv.w + Bf*yd)*g;
  ((float4*)(out + (size_t)r*1024))[t] = o;
}

extern "C" void kernel_launch(void* const* d_in, const int* in_sizes, int n_in,
                              void* d_out, int out_size, void* d_ws, size_t ws_size,
                              hipStream_t stream){
  (void)in_sizes; (void)n_in; (void)out_size; (void)ws_size;
  const float* x     = (const float*)d_in[0];
  const float* cg    = (const float*)d_in[1];
  const float* qkv_w = (const float*)d_in[2];
  const float* qkv_b = (const float*)d_in[3];
  const float* out_w = (const float*)d_in[4];
  const float* out_b = (const float*)d_in[5];
  const float* ffn_w1= (const float*)d_in[6];
  const float* ffn_b1= (const float*)d_in[7];
  const float* ffn_w2= (const float*)d_in[8];
  const float* ffn_b2= (const float*)d_in[9];
  const float* ln1s  = (const float*)d_in[10];
  const float* ln1b  = (const float*)d_in[11];
  const float* ln2s  = (const float*)d_in[12];
  const float* ln2b  = (const float*)d_in[13];
  const float* clog  = (const float*)d_in[14];
  const float* geo   = (const float*)d_in[15];

  char* p = (char*)d_ws;
  auto take = [&](size_t n){ char* r = p; p += (n + 255) & ~(size_t)255; return r; };
  ushort* wt_qkv  = (ushort*)take((size_t)3072*1024*2);
  ushort* wt_out  = (ushort*)take((size_t)1024*1024*2);
  ushort* wt_ffn1 = (ushort*)take((size_t)4096*1024*2);
  ushort* wt_ffn2 = (ushort*)take((size_t)1024*4096*2);
  float*  bufA    = (float*)take((size_t)2*1024*3072*4);  // qkv 2 partials ; later gelu bf16
  ushort* bufB    = (ushort*)take((size_t)1024*1024*2);   // x_tan ; later ao
  float*  bufC    = (float*)take((size_t)4*1024*1024*4);  // split-K partials (4x 4MB)
  float*  xatt    = (float*)take((size_t)1024*1024*4);
  ushort* tbuf    = (ushort*)take((size_t)1024*1024*2);

  k_pre<<<13312, 256, 0, stream>>>(qkv_w, out_w, ffn_w1, ffn_w2, x, cg, ln1s, ln1b,
                                   wt_qkv, wt_out, wt_ffn1, wt_ffn2, bufB);
  // qkv: split-K2, f32 partials (2 x 12MB)
  k_gemm<3><<<dim3(48,8,2), 256, 0, stream>>>(bufB, wt_qkv, qkv_b, (void*)bufA, 1024, 3072, 1024, 512);
  k_attn5<<<dim3(16,8,2), 256, 0, stream>>>(bufA, clog, geo, bufB);
  // out-proj: split-K4
  k_gemm<3><<<dim3(16,8,4), 256, 0, stream>>>(bufB, wt_out, out_b, (void*)bufC, 1024, 1024, 1024, 256);
  k_postattn<<<1024, 256, 0, stream>>>(x, bufC, cg, ln2s, ln2b, xatt, tbuf);
  // ffn1: gelu epilogue, full K
  k_gemm<2><<<dim3(64,8,1), 256, 0, stream>>>(tbuf, wt_ffn1, ffn_b1, (void*)bufA, 1024, 4096, 1024, 1024);
  // ffn2: split-K4
  k_gemm<3><<<dim3(16,8,4), 256, 0, stream>>>((const ushort*)bufA, wt_ffn2, ffn_b2, (void*)bufC, 1024, 1024, 4096, 1024);
  k_final<<<1024, 256, 0, stream>>>(xatt, bufC, cg, (float*)d_out);
}